// Round 2
// baseline (5883.722 us; speedup 1.0000x reference)
//
#include <hip/hip_runtime.h>
#include <hip/hip_bf16.h>

#define DEVI __device__ __forceinline__

// Problem constants
static constexpr int BATCH = 8;
static constexpr int NPT   = 2048;   // points
static constexpr int DMID  = 64;     // conv1 out channels
static constexpr int DEMB  = 256;    // embedding channels
static constexpr int NSA   = 4;      // SA layers

DEVI float waveReduceSum(float v) {
#pragma unroll
  for (int o = 32; o > 0; o >>= 1) v += __shfl_down(v, o, 64);
  return v;
}
DEVI float waveReduceMax(float v) {
#pragma unroll
  for (int o = 32; o > 0; o >>= 1) v = fmaxf(v, __shfl_down(v, o, 64));
  return v;
}
// 256-thread block reductions (4 waves). Leading sync makes repeated calls safe.
DEVI float blockReduceSum(float v) {
  __shared__ float sm[4];
  int lane = threadIdx.x & 63, wid = threadIdx.x >> 6;
  __syncthreads();
  v = waveReduceSum(v);
  if (lane == 0) sm[wid] = v;
  __syncthreads();
  return sm[0] + sm[1] + sm[2] + sm[3];
}
DEVI float blockReduceMax(float v) {
  __shared__ float sm[4];
  int lane = threadIdx.x & 63, wid = threadIdx.x >> 6;
  __syncthreads();
  v = waveReduceMax(v);
  if (lane == 0) sm[wid] = v;
  __syncthreads();
  return fmaxf(fmaxf(sm[0], sm[1]), fmaxf(sm[2], sm[3]));
}

// ---- conv1 (1x1, C=3 -> 64): h1[b,o,n] = sum_c x[b,n,c]*w1[o,c] + b1[o] ----
__global__ void k_stage1(const float* __restrict__ x, const float* __restrict__ w1,
                         const float* __restrict__ b1, float* __restrict__ h1) {
  int idx = blockIdx.x * 256 + threadIdx.x;        // [B][64][N]
  if (idx >= BATCH * DMID * NPT) return;
  int n = idx & (NPT - 1);
  int o = (idx >> 11) & (DMID - 1);
  int b = idx >> 17;
  const float* xp = x + ((long)(b * NPT + n)) * 3;
  float acc = b1[o];
  acc += xp[0] * w1[o * 3 + 0];
  acc += xp[1] * w1[o * 3 + 1];
  acc += xp[2] * w1[o * 3 + 2];
  h1[idx] = acc;
}

// ---- BN stats (training mode, biased var) per channel over (B,N): emit affine a,b ----
__global__ __launch_bounds__(256) void k_bnstats(const float* __restrict__ h, int Cc,
                                                 const float* __restrict__ g, const float* __restrict__ be,
                                                 float* __restrict__ sa, float* __restrict__ sb) {
  int c = blockIdx.x;
  float s = 0.f, s2 = 0.f;
  for (int b = 0; b < BATCH; ++b) {
    const float* p = h + ((long)(b * Cc + c)) * NPT;
    for (int n = threadIdx.x; n < NPT; n += 256) {
      float v = p[n];
      s += v; s2 += v * v;
    }
  }
  s  = blockReduceSum(s);
  s2 = blockReduceSum(s2);
  if (threadIdx.x == 0) {
    const float inv_cnt = 1.0f / (BATCH * NPT);
    float m   = s * inv_cnt;
    float var = s2 * inv_cnt - m * m;
    float istd = rsqrtf(var + 1e-5f);
    float A = istd * g[c];
    sa[c] = A;
    sb[c] = be[c] - m * A;
  }
}

// ---- BN apply + ReLU (in place) ----
__global__ void k_bnapply(float* __restrict__ h, const float* __restrict__ sa,
                          const float* __restrict__ sb, int Cc, int total) {
  int i = blockIdx.x * 256 + threadIdx.x;
  if (i >= total) return;
  int c = (i >> 11) & (Cc - 1);
  float v = fmaf(h[i], sa[c], sb[c]);
  h[i] = v > 0.f ? v : 0.f;
}

// ---- generic tiled fp32 GEMM: C[M,N] = A.B (+bias[row]) (*colscale[col]) (+=) ----
// A: [M,K] row-major (ATRANS=false) or [K,M] row-major (ATRANS=true)
// B: [K,N] row-major. Requires M%64==0, N%64==0, K%16==0.
template <bool ATRANS>
__global__ __launch_bounds__(256) void k_gemm(
    const float* __restrict__ A, long aStride,
    const float* __restrict__ B, long bStride,
    float* __restrict__ C, long cStride,
    int M, int N, int K,
    const float* __restrict__ bias,
    const float* __restrict__ colscale,
    int accumulate) {
  __shared__ __align__(16) float As[16][68];
  __shared__ __align__(16) float Bs[16][68];
  A += aStride * blockIdx.z;
  B += bStride * blockIdx.z;
  C += cStride * blockIdx.z;
  const int bm = blockIdx.y * 64, bn = blockIdx.x * 64;
  const int tid = threadIdx.x;
  const int tx = tid & 15, ty = tid >> 4;
  float acc[4][4] = {};
  for (int k0 = 0; k0 < K; k0 += 16) {
    if (ATRANS) {
      int m = tid & 63, kk = tid >> 6;
#pragma unroll
      for (int p = 0; p < 4; ++p)
        As[kk + 4 * p][m] = A[(long)(k0 + kk + 4 * p) * M + bm + m];
    } else {
      int kk = tid & 15, m = tid >> 4;
#pragma unroll
      for (int p = 0; p < 4; ++p)
        As[kk][m + 16 * p] = A[(long)(bm + m + 16 * p) * K + k0 + kk];
    }
    {
      int n = tid & 63, kk = tid >> 6;
#pragma unroll
      for (int p = 0; p < 4; ++p)
        Bs[kk + 4 * p][n] = B[(long)(k0 + kk + 4 * p) * N + bn + n];
    }
    __syncthreads();
#pragma unroll
    for (int kk = 0; kk < 16; ++kk) {
      float4 av = *reinterpret_cast<const float4*>(&As[kk][ty * 4]);
      float4 bv = *reinterpret_cast<const float4*>(&Bs[kk][tx * 4]);
      float a[4] = {av.x, av.y, av.z, av.w};
      float bb[4] = {bv.x, bv.y, bv.z, bv.w};
#pragma unroll
      for (int i = 0; i < 4; ++i)
#pragma unroll
        for (int j = 0; j < 4; ++j) acc[i][j] += a[i] * bb[j];
    }
    __syncthreads();
  }
#pragma unroll
  for (int i = 0; i < 4; ++i) {
    int r = bm + ty * 4 + i;
    float badd = bias ? bias[r] : 0.0f;
#pragma unroll
    for (int j = 0; j < 4; ++j) {
      int c = bn + tx * 4 + j;
      float v = acc[i][j] + badd;
      if (colscale) v *= colscale[c];
      long off = (long)r * N + c;
      if (accumulate) C[off] += v;
      else C[off] = v;
    }
  }
}

// ---- row softmax in place over E[2048][2048] (one block per row) ----
__global__ __launch_bounds__(256) void k_softmax(float* __restrict__ E) {
  float* p = E + (long)blockIdx.x * NPT;
  float v[8];
  float mx = -3.0e38f;
#pragma unroll
  for (int i = 0; i < 8; ++i) {
    v[i] = p[threadIdx.x + 256 * i];
    mx = fmaxf(mx, v[i]);
  }
  mx = blockReduceMax(mx);
  float s = 0.f;
#pragma unroll
  for (int i = 0; i < 8; ++i) {
    v[i] = __expf(v[i] - mx);
    s += v[i];
  }
  s = blockReduceSum(s);
  float inv = 1.0f / s;
#pragma unroll
  for (int i = 0; i < 8; ++i) p[threadIdx.x + 256 * i] = v[i] * inv;
}

// ---- column sums of P' (two-phase, deterministic): part[y][m], then S[m]=1/(1e-9+sum) ----
__global__ void k_colsum_part(const float* __restrict__ E, float* __restrict__ part) {
  int m = blockIdx.x * 256 + threadIdx.x;  // grid.x = 8
  int y = blockIdx.y;                      // grid.y = 16 (128 rows each)
  const float* p = E + (long)y * 128 * NPT + m;
  float s = 0.f;
  for (int n = 0; n < 128; ++n) s += p[(long)n * NPT];
  part[y * NPT + m] = s;
}
__global__ void k_colsum_fin(const float* __restrict__ part, float* __restrict__ S) {
  int m = blockIdx.x * 256 + threadIdx.x;
  float s = 0.f;
#pragma unroll
  for (int y = 0; y < 16; ++y) s += part[y * NPT + m];
  S[m] = 1.0f / (1e-9f + s);
}

// ---- pooled[b,n] = mean over e of H[b,e,n] ----
__global__ void k_pool(const float* __restrict__ H, float* __restrict__ pooled) {
  int i = blockIdx.x * 256 + threadIdx.x;  // [B][N]
  if (i >= BATCH * NPT) return;
  int b = i >> 11, n = i & (NPT - 1);
  const float* p = H + (long)b * DEMB * NPT + n;
  float s = 0.f;
  for (int e = 0; e < DEMB; ++e) s += p[(long)e * NPT];
  pooled[i] = s * (1.0f / DEMB);
}

// ---- fc1: f[b,j] = relu(sum_n pooled[b,n]*fc1w[j,n] + fc1b[j]) ----
__global__ __launch_bounds__(256) void k_fc1(const float* __restrict__ pooled,
                                             const float* __restrict__ w, const float* __restrict__ bias,
                                             float* __restrict__ f) {
  int j = blockIdx.x, b = blockIdx.y;
  const float* pp = pooled + (long)b * NPT;
  const float* wr = w + (long)j * NPT;
  float s = 0.f;
  for (int n = threadIdx.x; n < NPT; n += 256) s += pp[n] * wr[n];
  s = blockReduceSum(s);
  if (threadIdx.x == 0) {
    s += bias[j];
    f[(long)b * NPT + j] = s > 0.f ? s : 0.f;
  }
}

// ---- fc2: out[b] = sum_j f[b,j]*fc2w[j] + fc2b ----
__global__ __launch_bounds__(256) void k_fc2(const float* __restrict__ f,
                                             const float* __restrict__ w, const float* __restrict__ bias,
                                             float* __restrict__ out) {
  int b = blockIdx.x;
  float s = 0.f;
  for (int j = threadIdx.x; j < NPT; j += 256) s += f[(long)b * NPT + j] * w[j];
  s = blockReduceSum(s);
  if (threadIdx.x == 0) out[b] = s + bias[0];
}

extern "C" void kernel_launch(void* const* d_in, const int* in_sizes, int n_in,
                              void* d_out, int out_size, void* d_ws, size_t ws_size,
                              hipStream_t stream) {
  const float* X    = (const float*)d_in[0];
  const float* W1   = (const float*)d_in[1];
  const float* B1   = (const float*)d_in[2];
  const float* G1   = (const float*)d_in[3];
  const float* BE1  = (const float*)d_in[4];
  const float* W2   = (const float*)d_in[5];
  const float* B2   = (const float*)d_in[6];
  const float* G2   = (const float*)d_in[7];
  const float* BE2  = (const float*)d_in[8];
  const float* WQ   = (const float*)d_in[9];
  const float* WK   = (const float*)d_in[10];
  const float* WV   = (const float*)d_in[11];
  const float* FC1W = (const float*)d_in[12];
  const float* FC1B = (const float*)d_in[13];
  const float* FC2W = (const float*)d_in[14];
  const float* FC2B = (const float*)d_in[15];
  float* OUT = (float*)d_out;

  // workspace layout (floats); total ~22.1M floats ~= 88 MB
  const long SZ_H1  = (long)BATCH * DMID * NPT;   // 1,048,576
  const long SZ_H   = (long)BATCH * DEMB * NPT;   // 4,194,304
  const long SZ_E   = (long)NPT * NPT;            // 4,194,304
  const long BS     = (long)DEMB * NPT;           // per-batch stride in H/Q/K/V

  float* ws  = (float*)d_ws;
  float* H1  = ws;
  float* H   = H1 + SZ_H1;
  float* Q   = H + SZ_H;
  float* Kb  = Q + SZ_H;
  float* V   = Kb + SZ_H;
  float* E   = V + SZ_H;
  float* SA1 = E + SZ_E;
  float* SB1 = SA1 + DMID;
  float* SA2 = SB1 + DMID;
  float* SB2 = SA2 + DEMB;
  float* S   = SB2 + DEMB;      // 2048
  float* SP  = S + NPT;         // 16*2048 colsum partials
  float* POOL = SP + 16 * NPT;  // 8*2048
  float* F    = POOL + BATCH * NPT;

  // conv1 + BN + ReLU
  k_stage1<<<(int)(SZ_H1 / 256), 256, 0, stream>>>(X, W1, B1, H1);
  k_bnstats<<<DMID, 256, 0, stream>>>(H1, DMID, G1, BE1, SA1, SB1);
  k_bnapply<<<(int)(SZ_H1 / 256), 256, 0, stream>>>(H1, SA1, SB1, DMID, (int)SZ_H1);

  // conv2 + BN + ReLU  (M=256, K=64, N=2048, batched over z)
  k_gemm<false><<<dim3(32, 4, 8), 256, 0, stream>>>(W2, 0, H1, (long)DMID * NPT, H, BS,
                                                    DEMB, NPT, DMID, B2, nullptr, 0);
  k_bnstats<<<DEMB, 256, 0, stream>>>(H, DEMB, G2, BE2, SA2, SB2);
  k_bnapply<<<(int)(SZ_H / 256), 256, 0, stream>>>(H, SA2, SB2, DEMB, (int)SZ_H);

  // SA layers
  for (int l = 0; l < NSA; ++l) {
    const long wo = (long)l * DEMB * DEMB;
    k_gemm<false><<<dim3(32, 4, 8), 256, 0, stream>>>(WQ + wo, 0, H, BS, Q, BS,
                                                      DEMB, NPT, DEMB, nullptr, nullptr, 0);
    k_gemm<false><<<dim3(32, 4, 8), 256, 0, stream>>>(WK + wo, 0, H, BS, Kb, BS,
                                                      DEMB, NPT, DEMB, nullptr, nullptr, 0);
    k_gemm<false><<<dim3(32, 4, 8), 256, 0, stream>>>(WV + wo, 0, H, BS, V, BS,
                                                      DEMB, NPT, DEMB, nullptr, nullptr, 0);
    for (int b = 0; b < BATCH; ++b) {
      // E[n,m] = sum_a Q[a,n] * K[a,m]   (A transposed layout)
      k_gemm<true><<<dim3(32, 32, 1), 256, 0, stream>>>(Q + b * BS, 0, Kb + b * BS, 0, E, 0,
                                                        NPT, NPT, DEMB, nullptr, nullptr, 0);
      k_softmax<<<NPT, 256, 0, stream>>>(E);
      k_colsum_part<<<dim3(8, 16), 256, 0, stream>>>(E, SP);
      k_colsum_fin<<<8, 256, 0, stream>>>(SP, S);
      // H[b] += (V[b] . P') * colscale
      k_gemm<false><<<dim3(32, 4, 1), 256, 0, stream>>>(V + b * BS, 0, E, 0, H + b * BS, 0,
                                                        DEMB, NPT, NPT, nullptr, S, 1);
    }
  }

  // head
  k_pool<<<(BATCH * NPT) / 256, 256, 0, stream>>>(H, POOL);
  k_fc1<<<dim3(NPT, BATCH), 256, 0, stream>>>(POOL, FC1W, FC1B, F);
  k_fc2<<<BATCH, 256, 0, stream>>>(F, FC2W, FC2B, OUT);
}

// Round 3
// 3122.332 us; speedup vs baseline: 1.8844x; 1.8844x over previous
//
#include <hip/hip_runtime.h>
#include <hip/hip_bf16.h>

typedef __hip_bfloat16 bf16;
#define DEVI __device__ __forceinline__

// Problem constants
static constexpr int BATCH = 8;
static constexpr int NPT   = 2048;
static constexpr int DMID  = 64;
static constexpr int DEMB  = 256;
static constexpr int NSA   = 4;
static constexpr long STRD = (long)DEMB * NPT;  // 524288, per-batch stride for H/Ht/Qt/Kt/V
static constexpr long NN   = (long)NPT * NPT;   // 4194304

typedef __attribute__((ext_vector_type(4))) float f32x4;
typedef __attribute__((ext_vector_type(8))) short bf16x8v;

DEVI f32x4 MFMA16(bf16x8v a, bf16x8v b, f32x4 c) {
  return __builtin_amdgcn_mfma_f32_16x16x32_bf16(a, b, c, 0, 0, 0);
}

DEVI void gload16(const bf16* g, bf16* l) {
  __builtin_amdgcn_global_load_lds(
      (const __attribute__((address_space(1))) void*)g,
      (__attribute__((address_space(3))) void*)l, 16, 0, 0);
}

DEVI float waveReduceSum(float v) {
#pragma unroll
  for (int o = 32; o > 0; o >>= 1) v += __shfl_down(v, o, 64);
  return v;
}
DEVI float blockReduceSum(float v) {
  __shared__ float sm[4];
  int lane = threadIdx.x & 63, wid = threadIdx.x >> 6;
  __syncthreads();
  v = waveReduceSum(v);
  if (lane == 0) sm[wid] = v;
  __syncthreads();
  return sm[0] + sm[1] + sm[2] + sm[3];
}

// ---- fp32 -> bf16 convert ----
__global__ void k_cvt(const float* __restrict__ in, bf16* __restrict__ out, int n) {
  int i = blockIdx.x * 256 + threadIdx.x;
  if (i < n) out[i] = __float2bfloat16(in[i]);
}

// ---- conv1: H1t[b][n][o] = sum_c x[b,n,c]*w1[o,c] + b1[o]  (fp32, transposed layout) ----
__global__ void k_conv1t(const float* __restrict__ x, const float* __restrict__ w1,
                         const float* __restrict__ b1, float* __restrict__ h1t) {
  long idx = (long)blockIdx.x * 256 + threadIdx.x;  // [b*n][o]
  int o = idx & 63;
  long bn = idx >> 6;
  const float* xp = x + bn * 3;
  h1t[idx] = b1[o] + xp[0] * w1[o * 3] + xp[1] * w1[o * 3 + 1] + xp[2] * w1[o * 3 + 2];
}

// ---- BN1 stats on H1t [16384][64]: two stage ----
__global__ __launch_bounds__(256) void k_bn1a(const float* __restrict__ h, float* __restrict__ pS,
                                              float* __restrict__ pS2) {
  int c = threadIdx.x & 63, rg = threadIdx.x >> 6;
  long r0 = (long)blockIdx.x * 128 + rg * 32;
  float s = 0.f, s2 = 0.f;
  for (int i = 0; i < 32; ++i) {
    float v = h[(r0 + i) * 64 + c];
    s += v; s2 += v * v;
  }
  __shared__ float smS[256], smS2[256];
  smS[threadIdx.x] = s; smS2[threadIdx.x] = s2;
  __syncthreads();
  if (threadIdx.x < 64) {
    float a = 0.f, b = 0.f;
#pragma unroll
    for (int g = 0; g < 4; ++g) { a += smS[g * 64 + c]; b += smS2[g * 64 + c]; }
    pS[blockIdx.x * 64 + c] = a;
    pS2[blockIdx.x * 64 + c] = b;
  }
}
__global__ void k_bn1b(const float* __restrict__ pS, const float* __restrict__ pS2,
                       const float* __restrict__ g, const float* __restrict__ be,
                       float* __restrict__ sa, float* __restrict__ sb) {
  int c = threadIdx.x;
  if (c >= 64) return;
  float s = 0.f, s2 = 0.f;
  for (int i = 0; i < 128; ++i) { s += pS[i * 64 + c]; s2 += pS2[i * 64 + c]; }
  const float inv = 1.0f / (BATCH * NPT);
  float m = s * inv, var = s2 * inv - m * m;
  float A = rsqrtf(var + 1e-5f) * g[c];
  sa[c] = A; sb[c] = be[c] - m * A;
}
__global__ void k_bn1apply(const float* __restrict__ h, const float* __restrict__ sa,
                           const float* __restrict__ sb, bf16* __restrict__ o) {
  long idx = (long)blockIdx.x * 256 + threadIdx.x;
  int c = idx & 63;
  float v = fmaf(h[idx], sa[c], sb[c]);
  o[idx] = __float2bfloat16(v > 0.f ? v : 0.f);
}

// ---- BN2 stats/apply on H [b][256][2048] fp32 ----
__global__ __launch_bounds__(256) void k_bnstats(const float* __restrict__ h, int Cc,
                                                 const float* __restrict__ g, const float* __restrict__ be,
                                                 float* __restrict__ sa, float* __restrict__ sb) {
  int c = blockIdx.x;
  float s = 0.f, s2 = 0.f;
  for (int b = 0; b < BATCH; ++b) {
    const float* p = h + ((long)(b * Cc + c)) * NPT;
    for (int n = threadIdx.x; n < NPT; n += 256) {
      float v = p[n];
      s += v; s2 += v * v;
    }
  }
  s = blockReduceSum(s);
  s2 = blockReduceSum(s2);
  if (threadIdx.x == 0) {
    const float inv = 1.0f / (BATCH * NPT);
    float m = s * inv, var = s2 * inv - m * m;
    float A = rsqrtf(var + 1e-5f) * g[c];
    sa[c] = A; sb[c] = be[c] - m * A;
  }
}
__global__ void k_bnapply(float* __restrict__ h, const float* __restrict__ sa,
                          const float* __restrict__ sb, int Cc, int total) {
  int i = blockIdx.x * 256 + threadIdx.x;
  if (i >= total) return;
  int c = (i >> 11) & (Cc - 1);
  float v = fmaf(h[i], sa[c], sb[c]);
  h[i] = v > 0.f ? v : 0.f;
}

// ---- tiled transpose+convert: H [b][256][2048] f32 -> Ht [b][2048][256] bf16 ----
__global__ __launch_bounds__(256) void k_tcvt(const float* __restrict__ H, bf16* __restrict__ Ht) {
  __shared__ float t[64][65];
  const float* h = H + (long)blockIdx.z * STRD;
  bf16* o = Ht + (long)blockIdx.z * STRD;
  int n0 = blockIdx.x * 64, c0 = blockIdx.y * 64;
#pragma unroll
  for (int ii = 0; ii < 16; ++ii) {
    int idx = ii * 256 + threadIdx.x;
    int i = idx >> 6, j = idx & 63;
    t[i][j] = h[(long)(c0 + i) * NPT + n0 + j];
  }
  __syncthreads();
#pragma unroll
  for (int ii = 0; ii < 16; ++ii) {
    int idx = ii * 256 + threadIdx.x;
    int i = idx >> 6, j = idx & 63;
    o[(long)(n0 + i) * DEMB + c0 + j] = __float2bfloat16(t[j][i]);
  }
}

// ---- MFMA GEMM, B^T form: C[M][N] = A[M][K] . B[N][K]^T ; 128x128 tile, BK=64 ----
// MODE 0: C f32 = acc            MODE 1: C bf16 = acc
// MODE 2: C f32 = acc + bias[r]  MODE 3: C f32 += acc * colscale[c]
template <int MODE>
__global__ __launch_bounds__(256) void k_mgemm(
    const bf16* __restrict__ A, long aStr, int ldA,
    const bf16* __restrict__ B, long bStr, int ldB,
    void* __restrict__ Cv, long cStr, int ldC,
    int K,
    const float* __restrict__ bias,
    const float* __restrict__ colscale, long csStr) {
  __shared__ __align__(16) bf16 sA[128 * 64];
  __shared__ __align__(16) bf16 sB[128 * 64];
  const int z = blockIdx.z;
  A += aStr * z;
  B += bStr * z;
  const int bm = blockIdx.y * 128, bn = blockIdx.x * 128;
  const int tid = threadIdx.x;
  const int lane = tid & 63, wv = tid >> 6;
  const int wr = (wv >> 1) * 64, wc = (wv & 1) * 64;
  f32x4 acc[4][4] = {};

  for (int k0 = 0; k0 < K; k0 += 64) {
#pragma unroll
    for (int i = 0; i < 4; ++i) {
      int c = i * 256 + tid;
      gload16(A + (long)(bm + (c >> 3)) * ldA + k0 + (c & 7) * 8, sA + c * 8);
      gload16(B + (long)(bn + (c >> 3)) * ldB + k0 + (c & 7) * 8, sB + c * 8);
    }
    __syncthreads();
    bf16x8v af[4][2], bfr[4][2];
#pragma unroll
    for (int mi = 0; mi < 4; ++mi)
#pragma unroll
      for (int ks = 0; ks < 2; ++ks) {
        af[mi][ks]  = *(const bf16x8v*)&sA[(wr + mi * 16 + (lane & 15)) * 64 + ks * 32 + (lane >> 4) * 8];
        bfr[mi][ks] = *(const bf16x8v*)&sB[(wc + mi * 16 + (lane & 15)) * 64 + ks * 32 + (lane >> 4) * 8];
      }
#pragma unroll
    for (int ks = 0; ks < 2; ++ks)
#pragma unroll
      for (int mi = 0; mi < 4; ++mi)
#pragma unroll
        for (int ni = 0; ni < 4; ++ni)
          acc[mi][ni] = MFMA16(af[mi][ks], bfr[ni][ks], acc[mi][ni]);
    __syncthreads();
  }

  const int rb = (lane >> 4) * 4, cb = lane & 15;
  if constexpr (MODE == 1) {
    bf16* C = (bf16*)Cv + cStr * z;
#pragma unroll
    for (int mi = 0; mi < 4; ++mi)
#pragma unroll
      for (int ni = 0; ni < 4; ++ni) {
        int r0 = bm + wr + mi * 16 + rb, c0 = bn + wc + ni * 16 + cb;
#pragma unroll
        for (int k = 0; k < 4; ++k)
          C[(long)(r0 + k) * ldC + c0] = __float2bfloat16(acc[mi][ni][k]);
      }
  } else {
    float* C = (float*)Cv + cStr * z;
    const float* cs = (MODE == 3) ? colscale + csStr * z : nullptr;
#pragma unroll
    for (int mi = 0; mi < 4; ++mi)
#pragma unroll
      for (int ni = 0; ni < 4; ++ni) {
        int r0 = bm + wr + mi * 16 + rb, c0 = bn + wc + ni * 16 + cb;
        float scl = (MODE == 3) ? cs[c0] : 1.0f;
#pragma unroll
        for (int k = 0; k < 4; ++k) {
          int r = r0 + k;
          float v = acc[mi][ni][k];
          if (MODE == 2) v += bias[r];
          long off = (long)r * ldC + c0;
          if (MODE == 3) C[off] += v * scl;
          else C[off] = v;
        }
      }
  }
}

// ---- column-wise online softmax stats over F [z][2048(m)][2048(n)] (reduce over m) ----
__global__ __launch_bounds__(256) void k_cms(const float* __restrict__ F,
                                             float* __restrict__ CM, float* __restrict__ CSi) {
  const float* f = F + (long)blockIdx.y * NN;
  int n = blockIdx.x * 256 + threadIdx.x;
  float m = -3.0e38f, s = 0.f;
  for (int r = 0; r < NPT; ++r) {
    float v = f[(long)r * NPT + n];
    if (v <= m) {
      s += __expf(v - m);
    } else {
      s = s * __expf(m - v) + 1.0f;
      m = v;
    }
  }
  CM[blockIdx.y * NPT + n] = m;
  CSi[blockIdx.y * NPT + n] = 1.0f / s;
}

// ---- PT[z][m][n] = exp(F - CM[n]) * CSi[n]  (bf16) ----
__global__ void k_pnorm(const float* __restrict__ F, const float* __restrict__ CM,
                        const float* __restrict__ CSi, bf16* __restrict__ PT) {
  long idx = (long)blockIdx.x * 256 + threadIdx.x;
  int n = idx & (NPT - 1);
  long zi = idx >> 22;
  long sn = zi * NPT + n;
  PT[idx] = __float2bfloat16(__expf(F[idx] - CM[sn]) * CSi[sn]);
}

// ---- S[z][m] = 1/(1e-9 + rowsum of PT row m) ----
__global__ __launch_bounds__(256) void k_rowsum(const bf16* __restrict__ PT, float* __restrict__ S) {
  const bf16* p = PT + (long)blockIdx.y * NN + (long)blockIdx.x * NPT;
  uint4 u = *(const uint4*)(p + threadIdx.x * 8);
  float s = 0.f;
  unsigned w[4] = {u.x, u.y, u.z, u.w};
#pragma unroll
  for (int i = 0; i < 4; ++i) {
    s += __uint_as_float(w[i] << 16);
    s += __uint_as_float(w[i] & 0xffff0000u);
  }
  s = blockReduceSum(s);
  if (threadIdx.x == 0) S[blockIdx.y * NPT + blockIdx.x] = 1.0f / (1e-9f + s);
}

// ---- pooled[b,n] = mean over e of H[b,e,n] ----
__global__ void k_pool(const float* __restrict__ H, float* __restrict__ pooled) {
  int i = blockIdx.x * 256 + threadIdx.x;
  if (i >= BATCH * NPT) return;
  int b = i >> 11, n = i & (NPT - 1);
  const float* p = H + (long)b * STRD + n;
  float s = 0.f;
  for (int e = 0; e < DEMB; ++e) s += p[(long)e * NPT];
  pooled[i] = s * (1.0f / DEMB);
}

// ---- fc1 ----
__global__ __launch_bounds__(256) void k_fc1(const float* __restrict__ pooled,
                                             const float* __restrict__ w, const float* __restrict__ bias,
                                             float* __restrict__ f) {
  int j = blockIdx.x, b = blockIdx.y;
  const float* pp = pooled + (long)b * NPT;
  const float* wr = w + (long)j * NPT;
  float s = 0.f;
  for (int n = threadIdx.x; n < NPT; n += 256) s += pp[n] * wr[n];
  s = blockReduceSum(s);
  if (threadIdx.x == 0) {
    s += bias[j];
    f[(long)b * NPT + j] = s > 0.f ? s : 0.f;
  }
}

// ---- fc2 ----
__global__ __launch_bounds__(256) void k_fc2(const float* __restrict__ f,
                                             const float* __restrict__ w, const float* __restrict__ bias,
                                             float* __restrict__ out) {
  int b = blockIdx.x;
  float s = 0.f;
  for (int j = threadIdx.x; j < NPT; j += 256) s += f[(long)b * NPT + j] * w[j];
  s = blockReduceSum(s);
  if (threadIdx.x == 0) out[b] = s + bias[0];
}

extern "C" void kernel_launch(void* const* d_in, const int* in_sizes, int n_in,
                              void* d_out, int out_size, void* d_ws, size_t ws_size,
                              hipStream_t stream) {
  const float* X    = (const float*)d_in[0];
  const float* W1   = (const float*)d_in[1];
  const float* B1   = (const float*)d_in[2];
  const float* G1   = (const float*)d_in[3];
  const float* BE1  = (const float*)d_in[4];
  const float* W2   = (const float*)d_in[5];
  const float* B2   = (const float*)d_in[6];
  const float* G2   = (const float*)d_in[7];
  const float* BE2  = (const float*)d_in[8];
  const float* WQ   = (const float*)d_in[9];
  const float* WK   = (const float*)d_in[10];
  const float* WV   = (const float*)d_in[11];
  const float* FC1W = (const float*)d_in[12];
  const float* FC1B = (const float*)d_in[13];
  const float* FC2W = (const float*)d_in[14];
  const float* FC2B = (const float*)d_in[15];
  float* OUT = (float*)d_out;

  // ---- workspace carve-out (256B-aligned blocks) ----
  char* p = (char*)d_ws;
  auto alloc = [&](size_t bytes) -> char* {
    char* r = p;
    p += (bytes + 255) & ~(size_t)255;
    return r;
  };
  float* H1t  = (float*)alloc((size_t)BATCH * NPT * DMID * 4);
  bf16*  H1tb = (bf16*)alloc((size_t)BATCH * NPT * DMID * 2);
  float* H    = (float*)alloc((size_t)BATCH * STRD * 4);
  bf16*  Ht   = (bf16*)alloc((size_t)BATCH * STRD * 2);
  bf16*  Qt   = (bf16*)alloc((size_t)BATCH * STRD * 2);
  bf16*  Kt   = (bf16*)alloc((size_t)BATCH * STRD * 2);
  bf16*  Vb   = (bf16*)alloc((size_t)BATCH * STRD * 2);
  bf16*  W2b  = (bf16*)alloc((size_t)DEMB * DMID * 2);
  bf16*  WQb  = (bf16*)alloc((size_t)NSA * DEMB * DEMB * 2);
  bf16*  WKb  = (bf16*)alloc((size_t)NSA * DEMB * DEMB * 2);
  bf16*  WVb  = (bf16*)alloc((size_t)NSA * DEMB * DEMB * 2);
  float* pS   = (float*)alloc(128 * 64 * 4);
  float* pS2  = (float*)alloc(128 * 64 * 4);
  float* sa1  = (float*)alloc(64 * 4);
  float* sb1  = (float*)alloc(64 * 4);
  float* sa2  = (float*)alloc(256 * 4);
  float* sb2  = (float*)alloc(256 * 4);
  float* CM   = (float*)alloc((size_t)BATCH * NPT * 4);
  float* CSi  = (float*)alloc((size_t)BATCH * NPT * 4);
  float* S    = (float*)alloc((size_t)BATCH * NPT * 4);
  float* POOL = (float*)alloc((size_t)BATCH * NPT * 4);
  float* FH   = (float*)alloc((size_t)BATCH * NPT * 4);
  size_t used = (size_t)(p - (char*)d_ws);
  const size_t per_g = (size_t)NN * 6;  // F f32 (16MB) + PT bf16 (8MB)
  int G = 8;
  while (G > 1 && used + (size_t)G * per_g + 1024 > ws_size) G >>= 1;
  float* F  = (float*)alloc((size_t)G * NN * 4);
  bf16*  PT = (bf16*)alloc((size_t)G * NN * 2);

  // ---- weight converts ----
  k_cvt<<<(DEMB * DMID + 255) / 256, 256, 0, stream>>>(W2, W2b, DEMB * DMID);
  int nw = NSA * DEMB * DEMB;
  k_cvt<<<(nw + 255) / 256, 256, 0, stream>>>(WQ, WQb, nw);
  k_cvt<<<(nw + 255) / 256, 256, 0, stream>>>(WK, WKb, nw);
  k_cvt<<<(nw + 255) / 256, 256, 0, stream>>>(WV, WVb, nw);

  // ---- conv1 + BN1 + ReLU (-> H1tb bf16 [b][n][64]) ----
  long szh1 = (long)BATCH * NPT * DMID;
  k_conv1t<<<(int)(szh1 / 256), 256, 0, stream>>>(X, W1, B1, H1t);
  k_bn1a<<<128, 256, 0, stream>>>(H1t, pS, pS2);
  k_bn1b<<<1, 64, 0, stream>>>(pS, pS2, G1, BE1, sa1, sb1);
  k_bn1apply<<<(int)(szh1 / 256), 256, 0, stream>>>(H1t, sa1, sb1, H1tb);

  // ---- conv2 (MFMA) + BN2 + ReLU -> H fp32 [b][256][2048] ----
  k_mgemm<2><<<dim3(16, 2, 8), 256, 0, stream>>>(W2b, 0, DMID, H1tb, (long)NPT * DMID, DMID,
                                                 H, STRD, NPT, DMID, B2, nullptr, 0);
  k_bnstats<<<DEMB, 256, 0, stream>>>(H, DEMB, G2, BE2, sa2, sb2);
  k_bnapply<<<(int)(BATCH * STRD / 256), 256, 0, stream>>>(H, sa2, sb2, DEMB, (int)(BATCH * STRD));

  // ---- SA layers ----
  for (int l = 0; l < NSA; ++l) {
    const long wo = (long)l * DEMB * DEMB;
    k_tcvt<<<dim3(32, 4, 8), 256, 0, stream>>>(H, Ht);
    // Qt[n][a], Kt[m][a] : A=Ht (M=2048), B=W (N=256)
    k_mgemm<1><<<dim3(2, 16, 8), 256, 0, stream>>>(Ht, STRD, DEMB, WQb + wo, 0, DEMB,
                                                   Qt, STRD, DEMB, DEMB, nullptr, nullptr, 0);
    k_mgemm<1><<<dim3(2, 16, 8), 256, 0, stream>>>(Ht, STRD, DEMB, WKb + wo, 0, DEMB,
                                                   Kt, STRD, DEMB, DEMB, nullptr, nullptr, 0);
    // V[e][n] : A=Wv (M=256), B=Ht (N=2048)
    k_mgemm<1><<<dim3(16, 2, 8), 256, 0, stream>>>(WVb + wo, 0, DEMB, Ht, STRD, DEMB,
                                                   Vb, STRD, NPT, DEMB, nullptr, nullptr, 0);
    for (int b0 = 0; b0 < BATCH; b0 += G) {
      // F[m][n] = sum_a Kt[m][a] Qt[n][a]  (= E^T), fp32
      k_mgemm<0><<<dim3(16, 16, G), 256, 0, stream>>>(Kt + b0 * STRD, STRD, DEMB,
                                                      Qt + b0 * STRD, STRD, DEMB,
                                                      F, NN, NPT, DEMB, nullptr, nullptr, 0);
      k_cms<<<dim3(8, G), 256, 0, stream>>>(F, CM, CSi);
      k_pnorm<<<(int)((long)G * NN / 256), 256, 0, stream>>>(F, CM, CSi, PT);
      k_rowsum<<<dim3(NPT, G), 256, 0, stream>>>(PT, S);
      // H[e][m] += S[m] * sum_n V[e][n] PT[m][n]
      k_mgemm<3><<<dim3(16, 2, G), 256, 0, stream>>>(Vb + b0 * STRD, STRD, NPT,
                                                     PT, NN, NPT,
                                                     H + b0 * STRD, STRD, NPT, NPT,
                                                     nullptr, S, NPT);
    }
  }

  // ---- head ----
  k_pool<<<(BATCH * NPT) / 256, 256, 0, stream>>>(H, POOL);
  k_fc1<<<dim3(NPT, BATCH), 256, 0, stream>>>(POOL, FC1W, FC1B, FH);
  k_fc2<<<BATCH, 256, 0, stream>>>(FH, FC2W, FC2B, OUT);
}

// Round 4
// 825.427 us; speedup vs baseline: 7.1281x; 3.7827x over previous
//
#include <hip/hip_runtime.h>
#include <hip/hip_bf16.h>

typedef __hip_bfloat16 bf16;
#define DEVI __device__ __forceinline__

// Problem constants
static constexpr int BATCH = 8;
static constexpr int NPT   = 2048;
static constexpr int DMID  = 64;
static constexpr int DEMB  = 256;
static constexpr int NSA   = 4;
static constexpr long STRD = (long)DEMB * NPT;  // 524288, per-batch stride for H/Ht/Qt/Kt/V
static constexpr long NN   = (long)NPT * NPT;   // 4194304

typedef __attribute__((ext_vector_type(4))) float f32x4;
typedef __attribute__((ext_vector_type(8))) short bf16x8v;

DEVI f32x4 MFMA16(bf16x8v a, bf16x8v b, f32x4 c) {
  return __builtin_amdgcn_mfma_f32_16x16x32_bf16(a, b, c, 0, 0, 0);
}

DEVI void gload16(const bf16* g, bf16* l) {
  __builtin_amdgcn_global_load_lds(
      (const __attribute__((address_space(1))) void*)g,
      (__attribute__((address_space(3))) void*)l, 16, 0, 0);
}

DEVI float waveReduceSum(float v) {
#pragma unroll
  for (int o = 32; o > 0; o >>= 1) v += __shfl_down(v, o, 64);
  return v;
}
DEVI float blockReduceSum(float v) {
  __shared__ float sm[4];
  int lane = threadIdx.x & 63, wid = threadIdx.x >> 6;
  __syncthreads();
  v = waveReduceSum(v);
  if (lane == 0) sm[wid] = v;
  __syncthreads();
  return sm[0] + sm[1] + sm[2] + sm[3];
}

// ---- fp32 -> bf16 convert ----
__global__ void k_cvt(const float* __restrict__ in, bf16* __restrict__ out, int n) {
  int i = blockIdx.x * 256 + threadIdx.x;
  if (i < n) out[i] = __float2bfloat16(in[i]);
}

// ---- conv1: H1t[b][n][o] = sum_c x[b,n,c]*w1[o,c] + b1[o]  (fp32, transposed layout) ----
__global__ void k_conv1t(const float* __restrict__ x, const float* __restrict__ w1,
                         const float* __restrict__ b1, float* __restrict__ h1t) {
  long idx = (long)blockIdx.x * 256 + threadIdx.x;  // [b*n][o]
  int o = idx & 63;
  long bn = idx >> 6;
  const float* xp = x + bn * 3;
  h1t[idx] = b1[o] + xp[0] * w1[o * 3] + xp[1] * w1[o * 3 + 1] + xp[2] * w1[o * 3 + 2];
}

// ---- BN1 stats on H1t [16384][64]: two stage ----
__global__ __launch_bounds__(256) void k_bn1a(const float* __restrict__ h, float* __restrict__ pS,
                                              float* __restrict__ pS2) {
  int c = threadIdx.x & 63, rg = threadIdx.x >> 6;
  long r0 = (long)blockIdx.x * 128 + rg * 32;
  float s = 0.f, s2 = 0.f;
  for (int i = 0; i < 32; ++i) {
    float v = h[(r0 + i) * 64 + c];
    s += v; s2 += v * v;
  }
  __shared__ float smS[256], smS2[256];
  smS[threadIdx.x] = s; smS2[threadIdx.x] = s2;
  __syncthreads();
  if (threadIdx.x < 64) {
    float a = 0.f, b = 0.f;
#pragma unroll
    for (int g = 0; g < 4; ++g) { a += smS[g * 64 + c]; b += smS2[g * 64 + c]; }
    pS[blockIdx.x * 64 + c] = a;
    pS2[blockIdx.x * 64 + c] = b;
  }
}
__global__ void k_bn1b(const float* __restrict__ pS, const float* __restrict__ pS2,
                       const float* __restrict__ g, const float* __restrict__ be,
                       float* __restrict__ sa, float* __restrict__ sb) {
  int c = threadIdx.x;
  if (c >= 64) return;
  float s = 0.f, s2 = 0.f;
  for (int i = 0; i < 128; ++i) { s += pS[i * 64 + c]; s2 += pS2[i * 64 + c]; }
  const float inv = 1.0f / (BATCH * NPT);
  float m = s * inv, var = s2 * inv - m * m;
  float A = rsqrtf(var + 1e-5f) * g[c];
  sa[c] = A; sb[c] = be[c] - m * A;
}
__global__ void k_bn1apply(const float* __restrict__ h, const float* __restrict__ sa,
                           const float* __restrict__ sb, bf16* __restrict__ o) {
  long idx = (long)blockIdx.x * 256 + threadIdx.x;
  int c = idx & 63;
  float v = fmaf(h[idx], sa[c], sb[c]);
  o[idx] = __float2bfloat16(v > 0.f ? v : 0.f);
}

// ---- BN2 stats/apply on H [b][256][2048] fp32 ----
__global__ __launch_bounds__(256) void k_bnstats(const float* __restrict__ h, int Cc,
                                                 const float* __restrict__ g, const float* __restrict__ be,
                                                 float* __restrict__ sa, float* __restrict__ sb) {
  int c = blockIdx.x;
  float s = 0.f, s2 = 0.f;
  for (int b = 0; b < BATCH; ++b) {
    const float* p = h + ((long)(b * Cc + c)) * NPT;
    for (int n = threadIdx.x; n < NPT; n += 256) {
      float v = p[n];
      s += v; s2 += v * v;
    }
  }
  s = blockReduceSum(s);
  s2 = blockReduceSum(s2);
  if (threadIdx.x == 0) {
    const float inv = 1.0f / (BATCH * NPT);
    float m = s * inv, var = s2 * inv - m * m;
    float A = rsqrtf(var + 1e-5f) * g[c];
    sa[c] = A; sb[c] = be[c] - m * A;
  }
}
__global__ void k_bnapply(float* __restrict__ h, const float* __restrict__ sa,
                          const float* __restrict__ sb, int Cc, int total) {
  int i = blockIdx.x * 256 + threadIdx.x;
  if (i >= total) return;
  int c = (i >> 11) & (Cc - 1);
  float v = fmaf(h[i], sa[c], sb[c]);
  h[i] = v > 0.f ? v : 0.f;
}

// ---- tiled transpose+convert: H [b][256][2048] f32 -> Ht [b][2048][256] bf16 ----
__global__ __launch_bounds__(256) void k_tcvt(const float* __restrict__ H, bf16* __restrict__ Ht) {
  __shared__ float t[64][65];
  const float* h = H + (long)blockIdx.z * STRD;
  bf16* o = Ht + (long)blockIdx.z * STRD;
  int n0 = blockIdx.x * 64, c0 = blockIdx.y * 64;
#pragma unroll
  for (int ii = 0; ii < 16; ++ii) {
    int idx = ii * 256 + threadIdx.x;
    int i = idx >> 6, j = idx & 63;
    t[i][j] = h[(long)(c0 + i) * NPT + n0 + j];
  }
  __syncthreads();
#pragma unroll
  for (int ii = 0; ii < 16; ++ii) {
    int idx = ii * 256 + threadIdx.x;
    int i = idx >> 6, j = idx & 63;
    o[(long)(n0 + i) * DEMB + c0 + j] = __float2bfloat16(t[j][i]);
  }
}

// ---- MFMA GEMM, B^T form: C[M][N] = A[M][K] . B[N][K]^T ; 128x128 tile, BK=64 ----
// MODE 0: C f32 = acc            MODE 1: C bf16 = acc
// MODE 2: C f32 = acc + bias[r]  MODE 3: C f32 += acc * colscale[c]
template <int MODE>
__global__ __launch_bounds__(256) void k_mgemm(
    const bf16* __restrict__ A, long aStr, int ldA,
    const bf16* __restrict__ B, long bStr, int ldB,
    void* __restrict__ Cv, long cStr, int ldC,
    int K,
    const float* __restrict__ bias,
    const float* __restrict__ colscale, long csStr) {
  __shared__ __align__(16) bf16 sA[128 * 64];
  __shared__ __align__(16) bf16 sB[128 * 64];
  const int z = blockIdx.z;
  A += aStr * z;
  B += bStr * z;
  const int bm = blockIdx.y * 128, bn = blockIdx.x * 128;
  const int tid = threadIdx.x;
  const int lane = tid & 63, wv = tid >> 6;
  const int wr = (wv >> 1) * 64, wc = (wv & 1) * 64;
  f32x4 acc[4][4] = {};

  for (int k0 = 0; k0 < K; k0 += 64) {
#pragma unroll
    for (int i = 0; i < 4; ++i) {
      int c = i * 256 + tid;
      gload16(A + (long)(bm + (c >> 3)) * ldA + k0 + (c & 7) * 8, sA + c * 8);
      gload16(B + (long)(bn + (c >> 3)) * ldB + k0 + (c & 7) * 8, sB + c * 8);
    }
    __syncthreads();
    bf16x8v af[4][2], bfr[4][2];
#pragma unroll
    for (int mi = 0; mi < 4; ++mi)
#pragma unroll
      for (int ks = 0; ks < 2; ++ks) {
        af[mi][ks]  = *(const bf16x8v*)&sA[(wr + mi * 16 + (lane & 15)) * 64 + ks * 32 + (lane >> 4) * 8];
        bfr[mi][ks] = *(const bf16x8v*)&sB[(wc + mi * 16 + (lane & 15)) * 64 + ks * 32 + (lane >> 4) * 8];
      }
#pragma unroll
    for (int ks = 0; ks < 2; ++ks)
#pragma unroll
      for (int mi = 0; mi < 4; ++mi)
#pragma unroll
        for (int ni = 0; ni < 4; ++ni)
          acc[mi][ni] = MFMA16(af[mi][ks], bfr[ni][ks], acc[mi][ni]);
    __syncthreads();
  }

  const int rb = (lane >> 4) * 4, cb = lane & 15;
  if constexpr (MODE == 1) {
    bf16* C = (bf16*)Cv + cStr * z;
#pragma unroll
    for (int mi = 0; mi < 4; ++mi)
#pragma unroll
      for (int ni = 0; ni < 4; ++ni) {
        int r0 = bm + wr + mi * 16 + rb, c0 = bn + wc + ni * 16 + cb;
#pragma unroll
        for (int k = 0; k < 4; ++k)
          C[(long)(r0 + k) * ldC + c0] = __float2bfloat16(acc[mi][ni][k]);
      }
  } else {
    float* C = (float*)Cv + cStr * z;
    const float* cs = (MODE == 3) ? colscale + csStr * z : nullptr;
#pragma unroll
    for (int mi = 0; mi < 4; ++mi)
#pragma unroll
      for (int ni = 0; ni < 4; ++ni) {
        int r0 = bm + wr + mi * 16 + rb, c0 = bn + wc + ni * 16 + cb;
        float scl = (MODE == 3) ? cs[c0] : 1.0f;
#pragma unroll
        for (int k = 0; k < 4; ++k) {
          int r = r0 + k;
          float v = acc[mi][ni][k];
          if (MODE == 2) v += bias[r];
          long off = (long)r * ldC + c0;
          if (MODE == 3) C[off] += v * scl;
          else C[off] = v;
        }
      }
  }
}

// ---- partial column softmax stats: grid (8, 16, G); each block 256 cols x 128 rows ----
__global__ __launch_bounds__(256) void k_cms_part(const float* __restrict__ F,
                                                  float* __restrict__ PM, float* __restrict__ PS) {
  const float* f = F + (long)blockIdx.z * NN + (long)blockIdx.y * 128 * NPT +
                   blockIdx.x * 256 + threadIdx.x;
  float m = -3.0e38f, s = 0.f;
#pragma unroll 8
  for (int r = 0; r < 128; ++r) {
    float v = f[(long)r * NPT];
    float nm = fmaxf(m, v);
    s = s * __expf(m - nm) + __expf(v - nm);
    m = nm;
  }
  long o = ((long)blockIdx.z * 16 + blockIdx.y) * NPT + blockIdx.x * 256 + threadIdx.x;
  PM[o] = m;
  PS[o] = s;
}

// ---- combine 16 partials per column -> CM, CSi ----
__global__ void k_cms_fin(const float* __restrict__ PM, const float* __restrict__ PS,
                          float* __restrict__ CM, float* __restrict__ CSi) {
  long idx = (long)blockIdx.x * 256 + threadIdx.x;  // [G*NPT]
  long z = idx >> 11;
  int n = idx & (NPT - 1);
  const float* pm = PM + z * 16 * NPT + n;
  const float* ps = PS + z * 16 * NPT + n;
  float m = -3.0e38f;
#pragma unroll
  for (int y = 0; y < 16; ++y) m = fmaxf(m, pm[(long)y * NPT]);
  float s = 0.f;
#pragma unroll
  for (int y = 0; y < 16; ++y) s += ps[(long)y * NPT] * __expf(pm[(long)y * NPT] - m);
  CM[idx] = m;
  CSi[idx] = 1.0f / s;
}

// ---- fused normalize + bf16 pack + row-sum: one block per F-row m ----
// PT[m][n] = exp(F[m][n]-CM[n])*CSi[n];  S[m] = 1/(1e-9 + sum_n PT_f32[m][n])
__global__ __launch_bounds__(256) void k_pnr(const float* __restrict__ F,
                                             const float* __restrict__ CM,
                                             const float* __restrict__ CSi,
                                             bf16* __restrict__ PT, float* __restrict__ S) {
  const long zo = (long)blockIdx.y * NN;
  const long ro = (long)blockIdx.x * NPT;
  const float* f = F + zo + ro;
  bf16* pt = PT + zo + ro;
  const float* cm = CM + (long)blockIdx.y * NPT;
  const float* csi = CSi + (long)blockIdx.y * NPT;
  const int n0 = threadIdx.x * 8;
  float fv[8], mv[8], cv[8];
  *(float4*)&fv[0] = *(const float4*)(f + n0);
  *(float4*)&fv[4] = *(const float4*)(f + n0 + 4);
  *(float4*)&mv[0] = *(const float4*)(cm + n0);
  *(float4*)&mv[4] = *(const float4*)(cm + n0 + 4);
  *(float4*)&cv[0] = *(const float4*)(csi + n0);
  *(float4*)&cv[4] = *(const float4*)(csi + n0 + 4);
  float s = 0.f;
  bf16 tb[8];
#pragma unroll
  for (int i = 0; i < 8; ++i) {
    float pv = __expf(fv[i] - mv[i]) * cv[i];
    s += pv;
    tb[i] = __float2bfloat16(pv);
  }
  *(uint4*)(pt + n0) = *(uint4*)tb;
  s = blockReduceSum(s);
  if (threadIdx.x == 0) S[(long)blockIdx.y * NPT + blockIdx.x] = 1.0f / (1e-9f + s);
}

// ---- pooled[b,n] = mean over e of H[b,e,n] ----
__global__ void k_pool(const float* __restrict__ H, float* __restrict__ pooled) {
  int i = blockIdx.x * 256 + threadIdx.x;
  if (i >= BATCH * NPT) return;
  int b = i >> 11, n = i & (NPT - 1);
  const float* p = H + (long)b * STRD + n;
  float s = 0.f;
  for (int e = 0; e < DEMB; ++e) s += p[(long)e * NPT];
  pooled[i] = s * (1.0f / DEMB);
}

// ---- fc1 ----
__global__ __launch_bounds__(256) void k_fc1(const float* __restrict__ pooled,
                                             const float* __restrict__ w, const float* __restrict__ bias,
                                             float* __restrict__ f) {
  int j = blockIdx.x, b = blockIdx.y;
  const float* pp = pooled + (long)b * NPT;
  const float* wr = w + (long)j * NPT;
  float s = 0.f;
  for (int n = threadIdx.x; n < NPT; n += 256) s += pp[n] * wr[n];
  s = blockReduceSum(s);
  if (threadIdx.x == 0) {
    s += bias[j];
    f[(long)b * NPT + j] = s > 0.f ? s : 0.f;
  }
}

// ---- fc2 ----
__global__ __launch_bounds__(256) void k_fc2(const float* __restrict__ f,
                                             const float* __restrict__ w, const float* __restrict__ bias,
                                             float* __restrict__ out) {
  int b = blockIdx.x;
  float s = 0.f;
  for (int j = threadIdx.x; j < NPT; j += 256) s += f[(long)b * NPT + j] * w[j];
  s = blockReduceSum(s);
  if (threadIdx.x == 0) out[b] = s + bias[0];
}

extern "C" void kernel_launch(void* const* d_in, const int* in_sizes, int n_in,
                              void* d_out, int out_size, void* d_ws, size_t ws_size,
                              hipStream_t stream) {
  const float* X    = (const float*)d_in[0];
  const float* W1   = (const float*)d_in[1];
  const float* B1   = (const float*)d_in[2];
  const float* G1   = (const float*)d_in[3];
  const float* BE1  = (const float*)d_in[4];
  const float* W2   = (const float*)d_in[5];
  const float* B2   = (const float*)d_in[6];
  const float* G2   = (const float*)d_in[7];
  const float* BE2  = (const float*)d_in[8];
  const float* WQ   = (const float*)d_in[9];
  const float* WK   = (const float*)d_in[10];
  const float* WV   = (const float*)d_in[11];
  const float* FC1W = (const float*)d_in[12];
  const float* FC1B = (const float*)d_in[13];
  const float* FC2W = (const float*)d_in[14];
  const float* FC2B = (const float*)d_in[15];
  float* OUT = (float*)d_out;

  // ---- workspace carve-out (256B-aligned blocks) ----
  char* p = (char*)d_ws;
  auto alloc = [&](size_t bytes) -> char* {
    char* r = p;
    p += (bytes + 255) & ~(size_t)255;
    return r;
  };
  float* H1t  = (float*)alloc((size_t)BATCH * NPT * DMID * 4);
  bf16*  H1tb = (bf16*)alloc((size_t)BATCH * NPT * DMID * 2);
  float* H    = (float*)alloc((size_t)BATCH * STRD * 4);
  bf16*  Ht   = (bf16*)alloc((size_t)BATCH * STRD * 2);
  bf16*  Qt   = (bf16*)alloc((size_t)BATCH * STRD * 2);
  bf16*  Kt   = (bf16*)alloc((size_t)BATCH * STRD * 2);
  bf16*  Vb   = (bf16*)alloc((size_t)BATCH * STRD * 2);
  bf16*  W2b  = (bf16*)alloc((size_t)DEMB * DMID * 2);
  bf16*  WQb  = (bf16*)alloc((size_t)NSA * DEMB * DEMB * 2);
  bf16*  WKb  = (bf16*)alloc((size_t)NSA * DEMB * DEMB * 2);
  bf16*  WVb  = (bf16*)alloc((size_t)NSA * DEMB * DEMB * 2);
  float* pS   = (float*)alloc(128 * 64 * 4);
  float* pS2  = (float*)alloc(128 * 64 * 4);
  float* sa1  = (float*)alloc(64 * 4);
  float* sb1  = (float*)alloc(64 * 4);
  float* sa2  = (float*)alloc(256 * 4);
  float* sb2  = (float*)alloc(256 * 4);
  float* CM   = (float*)alloc((size_t)BATCH * NPT * 4);
  float* CSi  = (float*)alloc((size_t)BATCH * NPT * 4);
  float* S    = (float*)alloc((size_t)BATCH * NPT * 4);
  float* PM   = (float*)alloc((size_t)BATCH * 16 * NPT * 4);
  float* PSm  = (float*)alloc((size_t)BATCH * 16 * NPT * 4);
  float* POOL = (float*)alloc((size_t)BATCH * NPT * 4);
  float* FH   = (float*)alloc((size_t)BATCH * NPT * 4);
  size_t used = (size_t)(p - (char*)d_ws);
  const size_t per_g = (size_t)NN * 6;  // F f32 (16MB) + PT bf16 (8MB)
  int G = 8;
  while (G > 1 && used + (size_t)G * per_g + 1024 > ws_size) G >>= 1;
  float* F  = (float*)alloc((size_t)G * NN * 4);
  bf16*  PT = (bf16*)alloc((size_t)G * NN * 2);

  // ---- weight converts ----
  k_cvt<<<(DEMB * DMID + 255) / 256, 256, 0, stream>>>(W2, W2b, DEMB * DMID);
  int nw = NSA * DEMB * DEMB;
  k_cvt<<<(nw + 255) / 256, 256, 0, stream>>>(WQ, WQb, nw);
  k_cvt<<<(nw + 255) / 256, 256, 0, stream>>>(WK, WKb, nw);
  k_cvt<<<(nw + 255) / 256, 256, 0, stream>>>(WV, WVb, nw);

  // ---- conv1 + BN1 + ReLU (-> H1tb bf16 [b][n][64]) ----
  long szh1 = (long)BATCH * NPT * DMID;
  k_conv1t<<<(int)(szh1 / 256), 256, 0, stream>>>(X, W1, B1, H1t);
  k_bn1a<<<128, 256, 0, stream>>>(H1t, pS, pS2);
  k_bn1b<<<1, 64, 0, stream>>>(pS, pS2, G1, BE1, sa1, sb1);
  k_bn1apply<<<(int)(szh1 / 256), 256, 0, stream>>>(H1t, sa1, sb1, H1tb);

  // ---- conv2 (MFMA) + BN2 + ReLU -> H fp32 [b][256][2048] ----
  k_mgemm<2><<<dim3(16, 2, 8), 256, 0, stream>>>(W2b, 0, DMID, H1tb, (long)NPT * DMID, DMID,
                                                 H, STRD, NPT, DMID, B2, nullptr, 0);
  k_bnstats<<<DEMB, 256, 0, stream>>>(H, DEMB, G2, BE2, sa2, sb2);
  k_bnapply<<<(int)(BATCH * STRD / 256), 256, 0, stream>>>(H, sa2, sb2, DEMB, (int)(BATCH * STRD));

  // ---- SA layers ----
  for (int l = 0; l < NSA; ++l) {
    const long wo = (long)l * DEMB * DEMB;
    k_tcvt<<<dim3(32, 4, 8), 256, 0, stream>>>(H, Ht);
    // Qt[n][a], Kt[m][a] : A=Ht (M=2048), B=W (N=256)
    k_mgemm<1><<<dim3(2, 16, 8), 256, 0, stream>>>(Ht, STRD, DEMB, WQb + wo, 0, DEMB,
                                                   Qt, STRD, DEMB, DEMB, nullptr, nullptr, 0);
    k_mgemm<1><<<dim3(2, 16, 8), 256, 0, stream>>>(Ht, STRD, DEMB, WKb + wo, 0, DEMB,
                                                   Kt, STRD, DEMB, DEMB, nullptr, nullptr, 0);
    // V[e][n] : A=Wv (M=256), B=Ht (N=2048)
    k_mgemm<1><<<dim3(16, 2, 8), 256, 0, stream>>>(WVb + wo, 0, DEMB, Ht, STRD, DEMB,
                                                   Vb, STRD, NPT, DEMB, nullptr, nullptr, 0);
    for (int b0 = 0; b0 < BATCH; b0 += G) {
      // F[m][n] = sum_a Kt[m][a] Qt[n][a]  (= E^T), fp32
      k_mgemm<0><<<dim3(16, 16, G), 256, 0, stream>>>(Kt + b0 * STRD, STRD, DEMB,
                                                      Qt + b0 * STRD, STRD, DEMB,
                                                      F, NN, NPT, DEMB, nullptr, nullptr, 0);
      k_cms_part<<<dim3(8, 16, G), 256, 0, stream>>>(F, PM, PSm);
      k_cms_fin<<<G * NPT / 256, 256, 0, stream>>>(PM, PSm, CM, CSi);
      k_pnr<<<dim3(NPT, G), 256, 0, stream>>>(F, CM, CSi, PT, S);
      // H[e][m] += S[m] * sum_n V[e][n] PT[m][n]
      k_mgemm<3><<<dim3(16, 2, G), 256, 0, stream>>>(Vb + b0 * STRD, STRD, NPT,
                                                     PT, NN, NPT,
                                                     H + b0 * STRD, STRD, NPT, NPT,
                                                     nullptr, S, NPT);
    }
  }

  // ---- head ----
  k_pool<<<(BATCH * NPT) / 256, 256, 0, stream>>>(H, POOL);
  k_fc1<<<dim3(NPT, BATCH), 256, 0, stream>>>(POOL, FC1W, FC1B, FH);
  k_fc2<<<BATCH, 256, 0, stream>>>(FH, FC2W, FC2B, OUT);
}

// Round 5
// 676.067 us; speedup vs baseline: 8.7029x; 1.2209x over previous
//
#include <hip/hip_runtime.h>
#include <hip/hip_bf16.h>

typedef __hip_bfloat16 bf16;
#define DEVI __device__ __forceinline__

// Problem constants
static constexpr int BATCH = 8;
static constexpr int NPT   = 2048;
static constexpr int DMID  = 64;
static constexpr int DEMB  = 256;
static constexpr int NSA   = 4;
static constexpr long STRD = (long)DEMB * NPT;  // 524288
static constexpr long NN   = (long)NPT * NPT;   // 4194304

typedef __attribute__((ext_vector_type(4))) float f32x4;
typedef __attribute__((ext_vector_type(8))) short bf16x8v;

DEVI f32x4 MFMA16(bf16x8v a, bf16x8v b, f32x4 c) {
  return __builtin_amdgcn_mfma_f32_16x16x32_bf16(a, b, c, 0, 0, 0);
}

DEVI void gload16(const bf16* g, bf16* l) {
  __builtin_amdgcn_global_load_lds(
      (const __attribute__((address_space(1))) void*)g,
      (__attribute__((address_space(3))) void*)l, 16, 0, 0);
}

DEVI float waveReduceSum(float v) {
#pragma unroll
  for (int o = 32; o > 0; o >>= 1) v += __shfl_down(v, o, 64);
  return v;
}
DEVI float blockReduceSum(float v) {
  __shared__ float sm[4];
  int lane = threadIdx.x & 63, wid = threadIdx.x >> 6;
  __syncthreads();
  v = waveReduceSum(v);
  if (lane == 0) sm[wid] = v;
  __syncthreads();
  return sm[0] + sm[1] + sm[2] + sm[3];
}

// ---- fp32 -> bf16 convert ----
__global__ void k_cvt(const float* __restrict__ in, bf16* __restrict__ out, int n) {
  int i = blockIdx.x * 256 + threadIdx.x;
  if (i < n) out[i] = __float2bfloat16(in[i]);
}

// ---- conv1: H1t[b][n][o] = sum_c x[b,n,c]*w1[o,c] + b1[o] ----
__global__ void k_conv1t(const float* __restrict__ x, const float* __restrict__ w1,
                         const float* __restrict__ b1, float* __restrict__ h1t) {
  long idx = (long)blockIdx.x * 256 + threadIdx.x;  // [b*n][o]
  int o = idx & 63;
  long bn = idx >> 6;
  const float* xp = x + bn * 3;
  h1t[idx] = b1[o] + xp[0] * w1[o * 3] + xp[1] * w1[o * 3 + 1] + xp[2] * w1[o * 3 + 2];
}

// ---- BN1 stats on H1t [16384][64] ----
__global__ __launch_bounds__(256) void k_bn1a(const float* __restrict__ h, float* __restrict__ pS,
                                              float* __restrict__ pS2) {
  int c = threadIdx.x & 63, rg = threadIdx.x >> 6;
  long r0 = (long)blockIdx.x * 128 + rg * 32;
  float s = 0.f, s2 = 0.f;
  for (int i = 0; i < 32; ++i) {
    float v = h[(r0 + i) * 64 + c];
    s += v; s2 += v * v;
  }
  __shared__ float smS[256], smS2[256];
  smS[threadIdx.x] = s; smS2[threadIdx.x] = s2;
  __syncthreads();
  if (threadIdx.x < 64) {
    float a = 0.f, b = 0.f;
#pragma unroll
    for (int g = 0; g < 4; ++g) { a += smS[g * 64 + c]; b += smS2[g * 64 + c]; }
    pS[blockIdx.x * 64 + c] = a;
    pS2[blockIdx.x * 64 + c] = b;
  }
}
__global__ void k_bn1b(const float* __restrict__ pS, const float* __restrict__ pS2,
                       const float* __restrict__ g, const float* __restrict__ be,
                       float* __restrict__ sa, float* __restrict__ sb) {
  int c = threadIdx.x;
  if (c >= 64) return;
  float s = 0.f, s2 = 0.f;
  for (int i = 0; i < 128; ++i) { s += pS[i * 64 + c]; s2 += pS2[i * 64 + c]; }
  const float inv = 1.0f / (BATCH * NPT);
  float m = s * inv, var = s2 * inv - m * m;
  float A = rsqrtf(var + 1e-5f) * g[c];
  sa[c] = A; sb[c] = be[c] - m * A;
}
__global__ void k_bn1apply(const float* __restrict__ h, const float* __restrict__ sa,
                           const float* __restrict__ sb, bf16* __restrict__ o) {
  long idx = (long)blockIdx.x * 256 + threadIdx.x;
  int c = idx & 63;
  float v = fmaf(h[idx], sa[c], sb[c]);
  o[idx] = __float2bfloat16(v > 0.f ? v : 0.f);
}

// ---- BN2 stats/apply on H [b][256][2048] fp32 ----
__global__ __launch_bounds__(256) void k_bnstats(const float* __restrict__ h, int Cc,
                                                 const float* __restrict__ g, const float* __restrict__ be,
                                                 float* __restrict__ sa, float* __restrict__ sb) {
  int c = blockIdx.x;
  float s = 0.f, s2 = 0.f;
  for (int b = 0; b < BATCH; ++b) {
    const float* p = h + ((long)(b * Cc + c)) * NPT;
    for (int n = threadIdx.x; n < NPT; n += 256) {
      float v = p[n];
      s += v; s2 += v * v;
    }
  }
  s = blockReduceSum(s);
  s2 = blockReduceSum(s2);
  if (threadIdx.x == 0) {
    const float inv = 1.0f / (BATCH * NPT);
    float m = s * inv, var = s2 * inv - m * m;
    float A = rsqrtf(var + 1e-5f) * g[c];
    sa[c] = A; sb[c] = be[c] - m * A;
  }
}
__global__ void k_bnapply(float* __restrict__ h, const float* __restrict__ sa,
                          const float* __restrict__ sb, int Cc, int total) {
  int i = blockIdx.x * 256 + threadIdx.x;
  if (i >= total) return;
  int c = (i >> 11) & (Cc - 1);
  float v = fmaf(h[i], sa[c], sb[c]);
  h[i] = v > 0.f ? v : 0.f;
}

// ---- tiled transpose+convert: H [b][256][2048] f32 -> Ht [b][2048][256] bf16 ----
__global__ __launch_bounds__(256) void k_tcvt(const float* __restrict__ H, bf16* __restrict__ Ht) {
  __shared__ float t[64][65];
  const float* h = H + (long)blockIdx.z * STRD;
  bf16* o = Ht + (long)blockIdx.z * STRD;
  int n0 = blockIdx.x * 64, c0 = blockIdx.y * 64;
#pragma unroll
  for (int ii = 0; ii < 16; ++ii) {
    int idx = ii * 256 + threadIdx.x;
    int i = idx >> 6, j = idx & 63;
    t[i][j] = h[(long)(c0 + i) * NPT + n0 + j];
  }
  __syncthreads();
#pragma unroll
  for (int ii = 0; ii < 16; ++ii) {
    int idx = ii * 256 + threadIdx.x;
    int i = idx >> 6, j = idx & 63;
    o[(long)(n0 + i) * DEMB + c0 + j] = __float2bfloat16(t[j][i]);
  }
}

// ---- MFMA GEMM, B^T form: C[M][N] = A[M][K] . B[N][K]^T ; 128x128 tile, BK=64 ----
// XOR-swizzled LDS (granule ^= row&7) on both staging-source and read.
// MODE 0: C f32 = acc, PLUS column-softmax partial stats (PM/PS[z][gridY][col])
// MODE 1: C bf16 = acc
// MODE 2: C f32 = acc + bias[r]
template <int MODE>
__global__ __launch_bounds__(256) void k_mgemm(
    const bf16* __restrict__ A, long aStr, int ldA,
    const bf16* __restrict__ B, long bStr, int ldB,
    void* __restrict__ Cv, long cStr, int ldC,
    int K,
    const float* __restrict__ bias,
    float* __restrict__ PMo, float* __restrict__ PSo) {
  __shared__ __align__(16) bf16 sA[128 * 64];
  __shared__ __align__(16) bf16 sB[128 * 64];
  __shared__ float smx[4][64], ssx[4][64];
  const int z = blockIdx.z;
  A += aStr * z;
  B += bStr * z;
  const int bm = blockIdx.y * 128, bn = blockIdx.x * 128;
  const int tid = threadIdx.x;
  const int lane = tid & 63, wv = tid >> 6;
  const int wr = (wv >> 1) * 64, wc = (wv & 1) * 64;
  f32x4 acc[4][4] = {};

  for (int k0 = 0; k0 < K; k0 += 64) {
#pragma unroll
    for (int i = 0; i < 4; ++i) {
      int c = i * 256 + tid;
      int row = c >> 3, g = c & 7;
      int gs = (g ^ (row & 7)) * 8;
      gload16(A + (long)(bm + row) * ldA + k0 + gs, sA + c * 8);
      gload16(B + (long)(bn + row) * ldB + k0 + gs, sB + c * 8);
    }
    __syncthreads();
    bf16x8v af[4][2], bfr[4][2];
#pragma unroll
    for (int mi = 0; mi < 4; ++mi)
#pragma unroll
      for (int ks = 0; ks < 2; ++ks) {
        int rA = wr + mi * 16 + (lane & 15);
        int rB = wc + mi * 16 + (lane & 15);
        int g = ks * 4 + (lane >> 4);
        af[mi][ks]  = *(const bf16x8v*)&sA[rA * 64 + ((g ^ (rA & 7)) * 8)];
        bfr[mi][ks] = *(const bf16x8v*)&sB[rB * 64 + ((g ^ (rB & 7)) * 8)];
      }
#pragma unroll
    for (int ks = 0; ks < 2; ++ks)
#pragma unroll
      for (int mi = 0; mi < 4; ++mi)
#pragma unroll
        for (int ni = 0; ni < 4; ++ni)
          acc[mi][ni] = MFMA16(af[mi][ks], bfr[ni][ks], acc[mi][ni]);
    __syncthreads();
  }

  const int rb = (lane >> 4) * 4, cb = lane & 15;
  if constexpr (MODE == 1) {
    bf16* C = (bf16*)Cv + cStr * z;
#pragma unroll
    for (int mi = 0; mi < 4; ++mi)
#pragma unroll
      for (int ni = 0; ni < 4; ++ni) {
        int r0 = bm + wr + mi * 16 + rb, c0 = bn + wc + ni * 16 + cb;
#pragma unroll
        for (int k = 0; k < 4; ++k)
          C[(long)(r0 + k) * ldC + c0] = __float2bfloat16(acc[mi][ni][k]);
      }
  } else {
    float* C = (float*)Cv + cStr * z;
#pragma unroll
    for (int mi = 0; mi < 4; ++mi)
#pragma unroll
      for (int ni = 0; ni < 4; ++ni) {
        int r0 = bm + wr + mi * 16 + rb, c0 = bn + wc + ni * 16 + cb;
#pragma unroll
        for (int k = 0; k < 4; ++k) {
          int r = r0 + k;
          float v = acc[mi][ni][k];
          if (MODE == 2) v += bias[r];
          C[(long)r * ldC + c0] = v;
        }
      }
  }

  if constexpr (MODE == 0) {
    // per-column (over this block's 128 rows) online-softmax partials
    float cm[4], cs[4];
#pragma unroll
    for (int ni = 0; ni < 4; ++ni) {
      float m = -3.0e38f;
#pragma unroll
      for (int mi = 0; mi < 4; ++mi)
#pragma unroll
        for (int k = 0; k < 4; ++k) m = fmaxf(m, acc[mi][ni][k]);
      float s = 0.f;
#pragma unroll
      for (int mi = 0; mi < 4; ++mi)
#pragma unroll
        for (int k = 0; k < 4; ++k) s += __expf(acc[mi][ni][k] - m);
#pragma unroll
      for (int off = 16; off <= 32; off <<= 1) {
        float mo = __shfl_xor(m, off, 64);
        float so = __shfl_xor(s, off, 64);
        float M = fmaxf(m, mo);
        s = s * __expf(m - M) + so * __expf(mo - M);
        m = M;
      }
      cm[ni] = m; cs[ni] = s;
    }
    __syncthreads();  // LDS reads of K-loop complete; reuse smx/ssx safely
    if (lane < 16) {
#pragma unroll
      for (int ni = 0; ni < 4; ++ni) {
        smx[wv][ni * 16 + lane] = cm[ni];
        ssx[wv][ni * 16 + lane] = cs[ni];
      }
    }
    __syncthreads();
    if (tid < 128) {
      int half = tid >> 6, c64 = tid & 63;
      float m1 = smx[half][c64], s1 = ssx[half][c64];
      float m2 = smx[half + 2][c64], s2 = ssx[half + 2][c64];
      float M = fmaxf(m1, m2);
      float S = s1 * __expf(m1 - M) + s2 * __expf(m2 - M);
      long o = ((long)z * 16 + blockIdx.y) * NPT + bn + half * 64 + c64;
      PMo[o] = M;
      PSo[o] = S;
    }
  }
}

// ---- combine 16 partials per column -> CM, CSi ----
__global__ void k_cms_fin(const float* __restrict__ PM, const float* __restrict__ PS,
                          float* __restrict__ CM, float* __restrict__ CSi) {
  long idx = (long)blockIdx.x * 256 + threadIdx.x;  // [G*NPT]
  long z = idx >> 11;
  int n = idx & (NPT - 1);
  const float* pm = PM + z * 16 * NPT + n;
  const float* ps = PS + z * 16 * NPT + n;
  float m = -3.0e38f;
#pragma unroll
  for (int y = 0; y < 16; ++y) m = fmaxf(m, pm[(long)y * NPT]);
  float s = 0.f;
#pragma unroll
  for (int y = 0; y < 16; ++y) s += ps[(long)y * NPT] * __expf(pm[(long)y * NPT] - m);
  CM[idx] = m;
  CSi[idx] = 1.0f / s;
}

// ---- fused normalize + rowsum + V.P GEMM ----
// Per block: e = 0..255 (M), m in [m0, m0+64) (N), K = n = 0..2047.
// PT[m][n] = exp(F[m][n]-CM[n])*CSi[n] computed on the fly (bf16 into swizzled LDS);
// R[m] accumulated fp32 pre-round; epilogue H[e][m] += acc * 1/(1e-9+R[m]).
__global__ __launch_bounds__(256) void k_vp(const float* __restrict__ F,
                                            const float* __restrict__ CM,
                                            const float* __restrict__ CSi,
                                            const bf16* __restrict__ V,
                                            float* __restrict__ H) {
  __shared__ __align__(16) bf16 sA[256 * 64];  // V tile [e][n]
  __shared__ __align__(16) bf16 sB[64 * 64];   // PT tile [m][n]
  __shared__ float rsLds[4][64];
  __shared__ float Sv[64];
  const int z = blockIdx.y;
  const int m0 = blockIdx.x * 64;
  const int tid = threadIdx.x;
  const int lane = tid & 63, wv = tid >> 6;
  const bf16* Vz = V + (long)z * STRD;
  const float* Fr = F + (long)z * NN + (long)(m0 + lane) * NPT + wv * 16;
  const float* CMz = CM + (long)z * NPT + wv * 16;
  const float* CSz = CSi + (long)z * NPT + wv * 16;
  f32x4 acc[4][4] = {};
  float rs = 0.f;

  for (int step = 0; step < 32; ++step) {
    const int n0 = step * 64;
    // compute PT chunk in registers (16 n-values for row m0+lane, quarter wv)
    float fv[16], mv[16], cv[16];
#pragma unroll
    for (int q = 0; q < 4; ++q) {
      *(float4*)&fv[q * 4] = *(const float4*)(Fr + n0 + q * 4);
      *(float4*)&mv[q * 4] = *(const float4*)(CMz + n0 + q * 4);
      *(float4*)&cv[q * 4] = *(const float4*)(CSz + n0 + q * 4);
    }
    bf16 tb[16];
#pragma unroll
    for (int i = 0; i < 16; ++i) {
      float pv = __expf(fv[i] - mv[i]) * cv[i];
      rs += pv;
      tb[i] = __float2bfloat16(pv);
    }
    __syncthreads();  // previous tile's LDS reads complete
    // stage PT (ds_write, swizzled) + V (global_load_lds, pre-swizzled source)
    *(bf16x8v*)&sB[lane * 64 + (((2 * wv + 0) ^ (lane & 7)) * 8)] = *(bf16x8v*)&tb[0];
    *(bf16x8v*)&sB[lane * 64 + (((2 * wv + 1) ^ (lane & 7)) * 8)] = *(bf16x8v*)&tb[8];
#pragma unroll
    for (int i = 0; i < 8; ++i) {
      int c = i * 256 + tid;
      int row = c >> 3, g = c & 7;
      gload16(Vz + (long)row * NPT + n0 + ((g ^ (row & 7)) * 8), sA + c * 8);
    }
    __syncthreads();  // staging complete (vmcnt+lgkm drained by compiler)
    bf16x8v af[4][2], bfr[4][2];
#pragma unroll
    for (int mi = 0; mi < 4; ++mi)
#pragma unroll
      for (int ks = 0; ks < 2; ++ks) {
        int rA = wv * 64 + mi * 16 + (lane & 15);
        int rB = mi * 16 + (lane & 15);
        int g = ks * 4 + (lane >> 4);
        af[mi][ks]  = *(const bf16x8v*)&sA[rA * 64 + ((g ^ (rA & 7)) * 8)];
        bfr[mi][ks] = *(const bf16x8v*)&sB[rB * 64 + ((g ^ (rB & 7)) * 8)];
      }
#pragma unroll
    for (int ks = 0; ks < 2; ++ks)
#pragma unroll
      for (int mi = 0; mi < 4; ++mi)
#pragma unroll
        for (int ni = 0; ni < 4; ++ni)
          acc[mi][ni] = MFMA16(af[mi][ks], bfr[ni][ks], acc[mi][ni]);
  }

  __syncthreads();
  rsLds[wv][lane] = rs;
  __syncthreads();
  if (tid < 64) {
    float R = rsLds[0][tid] + rsLds[1][tid] + rsLds[2][tid] + rsLds[3][tid];
    Sv[tid] = 1.0f / (1e-9f + R);
  }
  __syncthreads();

  float* Hz = H + (long)z * STRD;
  const int rb = (lane >> 4) * 4, cb = lane & 15;
#pragma unroll
  for (int mi = 0; mi < 4; ++mi)
#pragma unroll
    for (int ni = 0; ni < 4; ++ni) {
      int r0 = wv * 64 + mi * 16 + rb;
      int c = ni * 16 + cb;
      float scl = Sv[c];
#pragma unroll
      for (int k = 0; k < 4; ++k)
        Hz[(long)(r0 + k) * NPT + m0 + c] += acc[mi][ni][k] * scl;
    }
}

// ---- pooled[b,n] = mean over e of H[b,e,n] ----
__global__ void k_pool(const float* __restrict__ H, float* __restrict__ pooled) {
  int i = blockIdx.x * 256 + threadIdx.x;
  if (i >= BATCH * NPT) return;
  int b = i >> 11, n = i & (NPT - 1);
  const float* p = H + (long)b * STRD + n;
  float s = 0.f;
  for (int e = 0; e < DEMB; ++e) s += p[(long)e * NPT];
  pooled[i] = s * (1.0f / DEMB);
}

// ---- fc1 ----
__global__ __launch_bounds__(256) void k_fc1(const float* __restrict__ pooled,
                                             const float* __restrict__ w, const float* __restrict__ bias,
                                             float* __restrict__ f) {
  int j = blockIdx.x, b = blockIdx.y;
  const float* pp = pooled + (long)b * NPT;
  const float* wr = w + (long)j * NPT;
  float s = 0.f;
  for (int n = threadIdx.x; n < NPT; n += 256) s += pp[n] * wr[n];
  s = blockReduceSum(s);
  if (threadIdx.x == 0) {
    s += bias[j];
    f[(long)b * NPT + j] = s > 0.f ? s : 0.f;
  }
}

// ---- fc2 ----
__global__ __launch_bounds__(256) void k_fc2(const float* __restrict__ f,
                                             const float* __restrict__ w, const float* __restrict__ bias,
                                             float* __restrict__ out) {
  int b = blockIdx.x;
  float s = 0.f;
  for (int j = threadIdx.x; j < NPT; j += 256) s += f[(long)b * NPT + j] * w[j];
  s = blockReduceSum(s);
  if (threadIdx.x == 0) out[b] = s + bias[0];
}

extern "C" void kernel_launch(void* const* d_in, const int* in_sizes, int n_in,
                              void* d_out, int out_size, void* d_ws, size_t ws_size,
                              hipStream_t stream) {
  const float* X    = (const float*)d_in[0];
  const float* W1   = (const float*)d_in[1];
  const float* B1   = (const float*)d_in[2];
  const float* G1   = (const float*)d_in[3];
  const float* BE1  = (const float*)d_in[4];
  const float* W2   = (const float*)d_in[5];
  const float* B2   = (const float*)d_in[6];
  const float* G2   = (const float*)d_in[7];
  const float* BE2  = (const float*)d_in[8];
  const float* WQ   = (const float*)d_in[9];
  const float* WK   = (const float*)d_in[10];
  const float* WV   = (const float*)d_in[11];
  const float* FC1W = (const float*)d_in[12];
  const float* FC1B = (const float*)d_in[13];
  const float* FC2W = (const float*)d_in[14];
  const float* FC2B = (const float*)d_in[15];
  float* OUT = (float*)d_out;

  // ---- workspace carve-out ----
  char* p = (char*)d_ws;
  auto alloc = [&](size_t bytes) -> char* {
    char* r = p;
    p += (bytes + 255) & ~(size_t)255;
    return r;
  };
  float* H1t  = (float*)alloc((size_t)BATCH * NPT * DMID * 4);
  bf16*  H1tb = (bf16*)alloc((size_t)BATCH * NPT * DMID * 2);
  float* H    = (float*)alloc((size_t)BATCH * STRD * 4);
  bf16*  Ht   = (bf16*)alloc((size_t)BATCH * STRD * 2);
  bf16*  Qt   = (bf16*)alloc((size_t)BATCH * STRD * 2);
  bf16*  Kt   = (bf16*)alloc((size_t)BATCH * STRD * 2);
  bf16*  Vb   = (bf16*)alloc((size_t)BATCH * STRD * 2);
  bf16*  W2b  = (bf16*)alloc((size_t)DEMB * DMID * 2);
  bf16*  WQb  = (bf16*)alloc((size_t)NSA * DEMB * DEMB * 2);
  bf16*  WKb  = (bf16*)alloc((size_t)NSA * DEMB * DEMB * 2);
  bf16*  WVb  = (bf16*)alloc((size_t)NSA * DEMB * DEMB * 2);
  float* pS   = (float*)alloc(128 * 64 * 4);
  float* pS2  = (float*)alloc(128 * 64 * 4);
  float* sa1  = (float*)alloc(64 * 4);
  float* sb1  = (float*)alloc(64 * 4);
  float* sa2  = (float*)alloc(256 * 4);
  float* sb2  = (float*)alloc(256 * 4);
  float* CM   = (float*)alloc((size_t)BATCH * NPT * 4);
  float* CSi  = (float*)alloc((size_t)BATCH * NPT * 4);
  float* PM   = (float*)alloc((size_t)BATCH * 16 * NPT * 4);
  float* PSm  = (float*)alloc((size_t)BATCH * 16 * NPT * 4);
  float* POOL = (float*)alloc((size_t)BATCH * NPT * 4);
  float* FH   = (float*)alloc((size_t)BATCH * NPT * 4);
  size_t used = (size_t)(p - (char*)d_ws);
  const size_t per_g = (size_t)NN * 4;  // F f32 (16MB per batch)
  int G = 8;
  while (G > 1 && used + (size_t)G * per_g + 1024 > ws_size) G >>= 1;
  float* F = (float*)alloc((size_t)G * NN * 4);

  // ---- weight converts ----
  k_cvt<<<(DEMB * DMID + 255) / 256, 256, 0, stream>>>(W2, W2b, DEMB * DMID);
  int nw = NSA * DEMB * DEMB;
  k_cvt<<<(nw + 255) / 256, 256, 0, stream>>>(WQ, WQb, nw);
  k_cvt<<<(nw + 255) / 256, 256, 0, stream>>>(WK, WKb, nw);
  k_cvt<<<(nw + 255) / 256, 256, 0, stream>>>(WV, WVb, nw);

  // ---- conv1 + BN1 + ReLU (-> H1tb bf16 [b][n][64]) ----
  long szh1 = (long)BATCH * NPT * DMID;
  k_conv1t<<<(int)(szh1 / 256), 256, 0, stream>>>(X, W1, B1, H1t);
  k_bn1a<<<128, 256, 0, stream>>>(H1t, pS, pS2);
  k_bn1b<<<1, 64, 0, stream>>>(pS, pS2, G1, BE1, sa1, sb1);
  k_bn1apply<<<(int)(szh1 / 256), 256, 0, stream>>>(H1t, sa1, sb1, H1tb);

  // ---- conv2 (MFMA) + BN2 + ReLU -> H fp32 [b][256][2048] ----
  k_mgemm<2><<<dim3(16, 2, 8), 256, 0, stream>>>(W2b, 0, DMID, H1tb, (long)NPT * DMID, DMID,
                                                 H, STRD, NPT, DMID, B2, nullptr, nullptr);
  k_bnstats<<<DEMB, 256, 0, stream>>>(H, DEMB, G2, BE2, sa2, sb2);
  k_bnapply<<<(int)(BATCH * STRD / 256), 256, 0, stream>>>(H, sa2, sb2, DEMB, (int)(BATCH * STRD));

  // ---- SA layers ----
  for (int l = 0; l < NSA; ++l) {
    const long wo = (long)l * DEMB * DEMB;
    k_tcvt<<<dim3(32, 4, 8), 256, 0, stream>>>(H, Ht);
    // Qt[n][a], Kt[m][a] : A=Ht (M=2048), B=W (N=256)
    k_mgemm<1><<<dim3(2, 16, 8), 256, 0, stream>>>(Ht, STRD, DEMB, WQb + wo, 0, DEMB,
                                                   Qt, STRD, DEMB, DEMB, nullptr, nullptr, nullptr);
    k_mgemm<1><<<dim3(2, 16, 8), 256, 0, stream>>>(Ht, STRD, DEMB, WKb + wo, 0, DEMB,
                                                   Kt, STRD, DEMB, DEMB, nullptr, nullptr, nullptr);
    // V[e][n] : A=Wv (M=256), B=Ht (N=2048)
    k_mgemm<1><<<dim3(16, 2, 8), 256, 0, stream>>>(WVb + wo, 0, DEMB, Ht, STRD, DEMB,
                                                   Vb, STRD, NPT, DEMB, nullptr, nullptr, nullptr);
    for (int b0 = 0; b0 < BATCH; b0 += G) {
      // F[m][n] = sum_a Kt[m][a] Qt[n][a] (= E^T), fp32 + fused column stats
      k_mgemm<0><<<dim3(16, 16, G), 256, 0, stream>>>(Kt + b0 * STRD, STRD, DEMB,
                                                      Qt + b0 * STRD, STRD, DEMB,
                                                      F, NN, NPT, DEMB, nullptr, PM, PSm);
      k_cms_fin<<<G * NPT / 256, 256, 0, stream>>>(PM, PSm, CM, CSi);
      // H[e][m] += S[m] * sum_n V[e][n] PT[m][n]  (PT from F on the fly)
      k_vp<<<dim3(32, G), 256, 0, stream>>>(F, CM, CSi, Vb + b0 * STRD, H + b0 * STRD);
    }
  }

  // ---- head ----
  k_pool<<<(BATCH * NPT) / 256, 256, 0, stream>>>(H, POOL);
  k_fc1<<<dim3(NPT, BATCH), 256, 0, stream>>>(POOL, FC1W, FC1B, FH);
  k_fc2<<<BATCH, 256, 0, stream>>>(FH, FC2W, FC2B, OUT);
}

// Round 6
// 578.175 us; speedup vs baseline: 10.1764x; 1.1693x over previous
//
#include <hip/hip_runtime.h>
#include <hip/hip_bf16.h>

typedef __hip_bfloat16 bf16;
#define DEVI __device__ __forceinline__

// Problem constants
static constexpr int BATCH = 8;
static constexpr int NPT   = 2048;
static constexpr int DMID  = 64;
static constexpr int DEMB  = 256;
static constexpr int NSA   = 4;
static constexpr long STRD = (long)DEMB * NPT;  // 524288
static constexpr long QKS  = (long)NPT * 512;   // per-batch stride of QKt
static constexpr long NN   = (long)NPT * NPT;   // 4194304

typedef __attribute__((ext_vector_type(4))) float f32x4;
typedef __attribute__((ext_vector_type(8))) short bf16x8v;

DEVI f32x4 MFMA16(bf16x8v a, bf16x8v b, f32x4 c) {
  return __builtin_amdgcn_mfma_f32_16x16x32_bf16(a, b, c, 0, 0, 0);
}

DEVI void gload16(const bf16* g, bf16* l) {
  __builtin_amdgcn_global_load_lds(
      (const __attribute__((address_space(1))) void*)g,
      (__attribute__((address_space(3))) void*)l, 16, 0, 0);
}

DEVI float waveReduceSum(float v) {
#pragma unroll
  for (int o = 32; o > 0; o >>= 1) v += __shfl_down(v, o, 64);
  return v;
}
DEVI float blockReduceSum(float v) {
  __shared__ float sm[4];
  int lane = threadIdx.x & 63, wid = threadIdx.x >> 6;
  __syncthreads();
  v = waveReduceSum(v);
  if (lane == 0) sm[wid] = v;
  __syncthreads();
  return sm[0] + sm[1] + sm[2] + sm[3];
}

// ---- fp32 -> bf16 convert ----
__global__ void k_cvt(const float* __restrict__ in, bf16* __restrict__ out, int n) {
  int i = blockIdx.x * 256 + threadIdx.x;
  if (i < n) out[i] = __float2bfloat16(in[i]);
}

// ---- concat-convert Wq,Wk -> WQKb [l][512][256] bf16 ----
__global__ void k_cvtqk(const float* __restrict__ wq, const float* __restrict__ wk,
                        bf16* __restrict__ o) {
  int idx = blockIdx.x * 256 + threadIdx.x;  // NSA*512*256
  int c = idx & 255;
  int r = (idx >> 8) & 511;
  int l = idx >> 17;
  float v = (r < 256) ? wq[((l << 8) + r) * 256 + c] : wk[((l << 8) + (r - 256)) * 256 + c];
  o[idx] = __float2bfloat16(v);
}

// ---- conv1: H1t[b][n][o] = sum_c x[b,n,c]*w1[o,c] + b1[o] ----
__global__ void k_conv1t(const float* __restrict__ x, const float* __restrict__ w1,
                         const float* __restrict__ b1, float* __restrict__ h1t) {
  long idx = (long)blockIdx.x * 256 + threadIdx.x;  // [b*n][o]
  int o = idx & 63;
  long bn = idx >> 6;
  const float* xp = x + bn * 3;
  h1t[idx] = b1[o] + xp[0] * w1[o * 3] + xp[1] * w1[o * 3 + 1] + xp[2] * w1[o * 3 + 2];
}

// ---- BN1 stats on H1t [16384][64] ----
__global__ __launch_bounds__(256) void k_bn1a(const float* __restrict__ h, float* __restrict__ pS,
                                              float* __restrict__ pS2) {
  int c = threadIdx.x & 63, rg = threadIdx.x >> 6;
  long r0 = (long)blockIdx.x * 128 + rg * 32;
  float s = 0.f, s2 = 0.f;
  for (int i = 0; i < 32; ++i) {
    float v = h[(r0 + i) * 64 + c];
    s += v; s2 += v * v;
  }
  __shared__ float smS[256], smS2[256];
  smS[threadIdx.x] = s; smS2[threadIdx.x] = s2;
  __syncthreads();
  if (threadIdx.x < 64) {
    float a = 0.f, b = 0.f;
#pragma unroll
    for (int g = 0; g < 4; ++g) { a += smS[g * 64 + c]; b += smS2[g * 64 + c]; }
    pS[blockIdx.x * 64 + c] = a;
    pS2[blockIdx.x * 64 + c] = b;
  }
}
__global__ void k_bn1b(const float* __restrict__ pS, const float* __restrict__ pS2,
                       const float* __restrict__ g, const float* __restrict__ be,
                       float* __restrict__ sa, float* __restrict__ sb) {
  int c = threadIdx.x;
  if (c >= 64) return;
  float s = 0.f, s2 = 0.f;
  for (int i = 0; i < 128; ++i) { s += pS[i * 64 + c]; s2 += pS2[i * 64 + c]; }
  const float inv = 1.0f / (BATCH * NPT);
  float m = s * inv, var = s2 * inv - m * m;
  float A = rsqrtf(var + 1e-5f) * g[c];
  sa[c] = A; sb[c] = be[c] - m * A;
}
__global__ void k_bn1apply(const float* __restrict__ h, const float* __restrict__ sa,
                           const float* __restrict__ sb, bf16* __restrict__ o) {
  long idx = (long)blockIdx.x * 256 + threadIdx.x;
  int c = idx & 63;
  float v = fmaf(h[idx], sa[c], sb[c]);
  o[idx] = __float2bfloat16(v > 0.f ? v : 0.f);
}

// ---- BN2 stats/apply on H [b][256][2048] fp32 ----
__global__ __launch_bounds__(256) void k_bnstats(const float* __restrict__ h, int Cc,
                                                 const float* __restrict__ g, const float* __restrict__ be,
                                                 float* __restrict__ sa, float* __restrict__ sb) {
  int c = blockIdx.x;
  float s = 0.f, s2 = 0.f;
  for (int b = 0; b < BATCH; ++b) {
    const float* p = h + ((long)(b * Cc + c)) * NPT;
    for (int n = threadIdx.x; n < NPT; n += 256) {
      float v = p[n];
      s += v; s2 += v * v;
    }
  }
  s = blockReduceSum(s);
  s2 = blockReduceSum(s2);
  if (threadIdx.x == 0) {
    const float inv = 1.0f / (BATCH * NPT);
    float m = s * inv, var = s2 * inv - m * m;
    float A = rsqrtf(var + 1e-5f) * g[c];
    sa[c] = A; sb[c] = be[c] - m * A;
  }
}
__global__ void k_bnapply(float* __restrict__ h, const float* __restrict__ sa,
                          const float* __restrict__ sb, int Cc, int total) {
  int i = blockIdx.x * 256 + threadIdx.x;
  if (i >= total) return;
  int c = (i >> 11) & (Cc - 1);
  float v = fmaf(h[i], sa[c], sb[c]);
  h[i] = v > 0.f ? v : 0.f;
}

// ---- tiled transpose+convert: H [b][256][2048] f32 -> Ht [b][2048][256] bf16 ----
__global__ __launch_bounds__(256) void k_tcvt(const float* __restrict__ H, bf16* __restrict__ Ht) {
  __shared__ float t[64][65];
  const float* h = H + (long)blockIdx.z * STRD;
  bf16* o = Ht + (long)blockIdx.z * STRD;
  int n0 = blockIdx.x * 64, c0 = blockIdx.y * 64;
#pragma unroll
  for (int ii = 0; ii < 16; ++ii) {
    int idx = ii * 256 + threadIdx.x;
    int i = idx >> 6, j = idx & 63;
    t[i][j] = h[(long)(c0 + i) * NPT + n0 + j];
  }
  __syncthreads();
#pragma unroll
  for (int ii = 0; ii < 16; ++ii) {
    int idx = ii * 256 + threadIdx.x;
    int i = idx >> 6, j = idx & 63;
    o[(long)(n0 + i) * DEMB + c0 + j] = __float2bfloat16(t[j][i]);
  }
}

// ---- MFMA GEMM, B^T form: C[M][N] = A[M][K] . B[N][K]^T ; 128x128 tile, BK=64 ----
// XOR-swizzled LDS (granule ^= row&7) on both staging-source and read.
// MODE 0: C f32 = acc, PLUS column-softmax partial stats (PM/PS[z][gridY][col])
// MODE 1: C bf16 = acc
// MODE 2: C f32 = acc + bias[r]
template <int MODE>
__global__ __launch_bounds__(256) void k_mgemm(
    const bf16* __restrict__ A, long aStr, int ldA,
    const bf16* __restrict__ B, long bStr, int ldB,
    void* __restrict__ Cv, long cStr, int ldC,
    int K,
    const float* __restrict__ bias,
    float* __restrict__ PMo, float* __restrict__ PSo) {
  __shared__ __align__(16) bf16 sA[128 * 64];
  __shared__ __align__(16) bf16 sB[128 * 64];
  __shared__ float smx[4][64], ssx[4][64];
  const int z = blockIdx.z;
  A += aStr * z;
  B += bStr * z;
  const int bm = blockIdx.y * 128, bn = blockIdx.x * 128;
  const int tid = threadIdx.x;
  const int lane = tid & 63, wv = tid >> 6;
  const int wr = (wv >> 1) * 64, wc = (wv & 1) * 64;
  f32x4 acc[4][4] = {};

  for (int k0 = 0; k0 < K; k0 += 64) {
#pragma unroll
    for (int i = 0; i < 4; ++i) {
      int c = i * 256 + tid;
      int row = c >> 3, g = c & 7;
      int gs = (g ^ (row & 7)) * 8;
      gload16(A + (long)(bm + row) * ldA + k0 + gs, sA + c * 8);
      gload16(B + (long)(bn + row) * ldB + k0 + gs, sB + c * 8);
    }
    __syncthreads();
    bf16x8v af[4][2], bfr[4][2];
#pragma unroll
    for (int mi = 0; mi < 4; ++mi)
#pragma unroll
      for (int ks = 0; ks < 2; ++ks) {
        int rA = wr + mi * 16 + (lane & 15);
        int rB = wc + mi * 16 + (lane & 15);
        int g = ks * 4 + (lane >> 4);
        af[mi][ks]  = *(const bf16x8v*)&sA[rA * 64 + ((g ^ (rA & 7)) * 8)];
        bfr[mi][ks] = *(const bf16x8v*)&sB[rB * 64 + ((g ^ (rB & 7)) * 8)];
      }
#pragma unroll
    for (int ks = 0; ks < 2; ++ks)
#pragma unroll
      for (int mi = 0; mi < 4; ++mi)
#pragma unroll
        for (int ni = 0; ni < 4; ++ni)
          acc[mi][ni] = MFMA16(af[mi][ks], bfr[ni][ks], acc[mi][ni]);
    __syncthreads();
  }

  const int rb = (lane >> 4) * 4, cb = lane & 15;
  if constexpr (MODE == 1) {
    bf16* C = (bf16*)Cv + cStr * z;
#pragma unroll
    for (int mi = 0; mi < 4; ++mi)
#pragma unroll
      for (int ni = 0; ni < 4; ++ni) {
        int r0 = bm + wr + mi * 16 + rb, c0 = bn + wc + ni * 16 + cb;
#pragma unroll
        for (int k = 0; k < 4; ++k)
          C[(long)(r0 + k) * ldC + c0] = __float2bfloat16(acc[mi][ni][k]);
      }
  } else {
    float* C = (float*)Cv + cStr * z;
#pragma unroll
    for (int mi = 0; mi < 4; ++mi)
#pragma unroll
      for (int ni = 0; ni < 4; ++ni) {
        int r0 = bm + wr + mi * 16 + rb, c0 = bn + wc + ni * 16 + cb;
#pragma unroll
        for (int k = 0; k < 4; ++k) {
          int r = r0 + k;
          float v = acc[mi][ni][k];
          if (MODE == 2) v += bias[r];
          C[(long)r * ldC + c0] = v;
        }
      }
  }

  if constexpr (MODE == 0) {
    // per-column (over this block's 128 rows) online-softmax partials
    float cm[4], cs[4];
#pragma unroll
    for (int ni = 0; ni < 4; ++ni) {
      float m = -3.0e38f;
#pragma unroll
      for (int mi = 0; mi < 4; ++mi)
#pragma unroll
        for (int k = 0; k < 4; ++k) m = fmaxf(m, acc[mi][ni][k]);
      float s = 0.f;
#pragma unroll
      for (int mi = 0; mi < 4; ++mi)
#pragma unroll
        for (int k = 0; k < 4; ++k) s += __expf(acc[mi][ni][k] - m);
#pragma unroll
      for (int off = 16; off <= 32; off <<= 1) {
        float mo = __shfl_xor(m, off, 64);
        float so = __shfl_xor(s, off, 64);
        float M = fmaxf(m, mo);
        s = s * __expf(m - M) + so * __expf(mo - M);
        m = M;
      }
      cm[ni] = m; cs[ni] = s;
    }
    __syncthreads();  // LDS reads of K-loop complete; reuse smx/ssx safely
    if (lane < 16) {
#pragma unroll
      for (int ni = 0; ni < 4; ++ni) {
        smx[wv][ni * 16 + lane] = cm[ni];
        ssx[wv][ni * 16 + lane] = cs[ni];
      }
    }
    __syncthreads();
    if (tid < 128) {
      int half = tid >> 6, c64 = tid & 63;
      float m1 = smx[half][c64], s1 = ssx[half][c64];
      float m2 = smx[half + 2][c64], s2 = ssx[half + 2][c64];
      float M = fmaxf(m1, m2);
      float S = s1 * __expf(m1 - M) + s2 * __expf(m2 - M);
      long o = ((long)z * 16 + blockIdx.y) * NPT + bn + half * 64 + c64;
      PMo[o] = M;
      PSo[o] = S;
    }
  }
}

// ---- combine 16 partials per column -> CM, CSi ----
__global__ void k_cms_fin(const float* __restrict__ PM, const float* __restrict__ PS,
                          float* __restrict__ CM, float* __restrict__ CSi) {
  long idx = (long)blockIdx.x * 256 + threadIdx.x;  // [G*NPT]
  long z = idx >> 11;
  int n = idx & (NPT - 1);
  const float* pm = PM + z * 16 * NPT + n;
  const float* ps = PS + z * 16 * NPT + n;
  float m = -3.0e38f;
#pragma unroll
  for (int y = 0; y < 16; ++y) m = fmaxf(m, pm[(long)y * NPT]);
  float s = 0.f;
#pragma unroll
  for (int y = 0; y < 16; ++y) s += ps[(long)y * NPT] * __expf(pm[(long)y * NPT] - m);
  CM[idx] = m;
  CSi[idx] = 1.0f / s;
}

// ---- fused normalize + rowsum + V.P GEMM ----
// Per block: e = 0..255 (M), m in [m0, m0+32) (N), K = n = 0..2047.
// PT[m][n] = exp(F[m][n]-CM[n])*CSi[n] on the fly (bf16 into swizzled LDS);
// F chunk reads are register double-buffered (issue-early). grid (64, G).
__global__ __launch_bounds__(256) void k_vp(const float* __restrict__ F,
                                            const float* __restrict__ CM,
                                            const float* __restrict__ CSi,
                                            const bf16* __restrict__ V,
                                            float* __restrict__ H) {
  __shared__ __align__(16) bf16 sA[256 * 64];  // V tile [e][n]
  __shared__ __align__(16) bf16 sB[32 * 64];   // PT tile [m][n]
  __shared__ float rsLds[8][32];
  __shared__ float Sv[32];
  const int z = blockIdx.y;
  const int m0 = blockIdx.x * 32;
  const int tid = threadIdx.x;
  const int lane = tid & 63, wv = tid >> 6;
  const int mloc = tid & 31, seg = tid >> 5;
  const bf16* Vz = V + (long)z * STRD;
  const float* Fr = F + (long)z * NN + (long)(m0 + mloc) * NPT + seg * 8;
  const float* CMz = CM + (long)z * NPT + seg * 8;
  const float* CSz = CSi + (long)z * NPT + seg * 8;
  f32x4 acc[4][2] = {};
  float rs = 0.f;
  float fvA[8], fvB[8];
  *(float4*)&fvA[0] = *(const float4*)(Fr);
  *(float4*)&fvA[4] = *(const float4*)(Fr + 4);

#define VP_STEP(CUR, NXT, STEPI)                                               \
  {                                                                            \
    const int n0 = (STEPI) * 64;                                               \
    float mv[8], cv[8];                                                        \
    *(float4*)&mv[0] = *(const float4*)(CMz + n0);                             \
    *(float4*)&mv[4] = *(const float4*)(CMz + n0 + 4);                         \
    *(float4*)&cv[0] = *(const float4*)(CSz + n0);                             \
    *(float4*)&cv[4] = *(const float4*)(CSz + n0 + 4);                         \
    bf16 tb[8];                                                                \
    _Pragma("unroll") for (int i = 0; i < 8; ++i) {                            \
      float pv = __expf(CUR[i] - mv[i]) * cv[i];                               \
      rs += pv;                                                                \
      tb[i] = __float2bfloat16(pv);                                            \
    }                                                                          \
    __syncthreads();                                                           \
    *(bf16x8v*)&sB[mloc * 64 + ((seg ^ (mloc & 7)) * 8)] = *(bf16x8v*)tb;      \
    _Pragma("unroll") for (int i = 0; i < 8; ++i) {                            \
      int c = i * 256 + tid;                                                   \
      int row = c >> 3, g = c & 7;                                             \
      gload16(Vz + (long)row * NPT + n0 + ((g ^ (row & 7)) * 8), sA + c * 8);  \
    }                                                                          \
    if ((STEPI) + 1 < 32) {                                                    \
      *(float4*)&NXT[0] = *(const float4*)(Fr + n0 + 64);                      \
      *(float4*)&NXT[4] = *(const float4*)(Fr + n0 + 68);                      \
    }                                                                          \
    __syncthreads();                                                           \
    bf16x8v bfr[2][2];                                                         \
    _Pragma("unroll") for (int ni = 0; ni < 2; ++ni)                           \
      _Pragma("unroll") for (int ks = 0; ks < 2; ++ks) {                       \
        int rB = ni * 16 + (lane & 15);                                        \
        int g = ks * 4 + (lane >> 4);                                          \
        bfr[ni][ks] = *(const bf16x8v*)&sB[rB * 64 + ((g ^ (rB & 7)) * 8)];    \
      }                                                                        \
    _Pragma("unroll") for (int mi = 0; mi < 4; ++mi)                           \
      _Pragma("unroll") for (int ks = 0; ks < 2; ++ks) {                       \
        int rA = (wv * 4 + mi) * 16 + (lane & 15);                             \
        int g = ks * 4 + (lane >> 4);                                          \
        bf16x8v af = *(const bf16x8v*)&sA[rA * 64 + ((g ^ (rA & 7)) * 8)];     \
        _Pragma("unroll") for (int ni = 0; ni < 2; ++ni)                       \
          acc[mi][ni] = MFMA16(af, bfr[ni][ks], acc[mi][ni]);                  \
      }                                                                        \
  }

  for (int it = 0; it < 16; ++it) {
    VP_STEP(fvA, fvB, 2 * it);
    VP_STEP(fvB, fvA, 2 * it + 1);
  }
#undef VP_STEP

  __syncthreads();
  rsLds[seg][mloc] = rs;
  __syncthreads();
  if (tid < 32) {
    float R = 0.f;
#pragma unroll
    for (int s = 0; s < 8; ++s) R += rsLds[s][tid];
    Sv[tid] = 1.0f / (1e-9f + R);
  }
  __syncthreads();

  float* Hz = H + (long)z * STRD;
  const int rb = (lane >> 4) * 4, cb = lane & 15;
#pragma unroll
  for (int mi = 0; mi < 4; ++mi) {
    int e0 = (wv * 4 + mi) * 16 + rb;
#pragma unroll
    for (int ni = 0; ni < 2; ++ni) {
      int c = ni * 16 + cb;
      float scl = Sv[c];
#pragma unroll
      for (int k = 0; k < 4; ++k)
        Hz[(long)(e0 + k) * NPT + m0 + c] += acc[mi][ni][k] * scl;
    }
  }
}

// ---- pooled[b,n] = mean over e of H[b,e,n] ----
__global__ void k_pool(const float* __restrict__ H, float* __restrict__ pooled) {
  int i = blockIdx.x * 256 + threadIdx.x;
  if (i >= BATCH * NPT) return;
  int b = i >> 11, n = i & (NPT - 1);
  const float* p = H + (long)b * STRD + n;
  float s = 0.f;
  for (int e = 0; e < DEMB; ++e) s += p[(long)e * NPT];
  pooled[i] = s * (1.0f / DEMB);
}

// ---- fc1 ----
__global__ __launch_bounds__(256) void k_fc1(const float* __restrict__ pooled,
                                             const float* __restrict__ w, const float* __restrict__ bias,
                                             float* __restrict__ f) {
  int j = blockIdx.x, b = blockIdx.y;
  const float* pp = pooled + (long)b * NPT;
  const float* wr = w + (long)j * NPT;
  float s = 0.f;
  for (int n = threadIdx.x; n < NPT; n += 256) s += pp[n] * wr[n];
  s = blockReduceSum(s);
  if (threadIdx.x == 0) {
    s += bias[j];
    f[(long)b * NPT + j] = s > 0.f ? s : 0.f;
  }
}

// ---- fc2 ----
__global__ __launch_bounds__(256) void k_fc2(const float* __restrict__ f,
                                             const float* __restrict__ w, const float* __restrict__ bias,
                                             float* __restrict__ out) {
  int b = blockIdx.x;
  float s = 0.f;
  for (int j = threadIdx.x; j < NPT; j += 256) s += f[(long)b * NPT + j] * w[j];
  s = blockReduceSum(s);
  if (threadIdx.x == 0) out[b] = s + bias[0];
}

extern "C" void kernel_launch(void* const* d_in, const int* in_sizes, int n_in,
                              void* d_out, int out_size, void* d_ws, size_t ws_size,
                              hipStream_t stream) {
  const float* X    = (const float*)d_in[0];
  const float* W1   = (const float*)d_in[1];
  const float* B1   = (const float*)d_in[2];
  const float* G1   = (const float*)d_in[3];
  const float* BE1  = (const float*)d_in[4];
  const float* W2   = (const float*)d_in[5];
  const float* B2   = (const float*)d_in[6];
  const float* G2   = (const float*)d_in[7];
  const float* BE2  = (const float*)d_in[8];
  const float* WQ   = (const float*)d_in[9];
  const float* WK   = (const float*)d_in[10];
  const float* WV   = (const float*)d_in[11];
  const float* FC1W = (const float*)d_in[12];
  const float* FC1B = (const float*)d_in[13];
  const float* FC2W = (const float*)d_in[14];
  const float* FC2B = (const float*)d_in[15];
  float* OUT = (float*)d_out;

  // ---- workspace carve-out ----
  char* p = (char*)d_ws;
  auto alloc = [&](size_t bytes) -> char* {
    char* r = p;
    p += (bytes + 255) & ~(size_t)255;
    return r;
  };
  float* H1t  = (float*)alloc((size_t)BATCH * NPT * DMID * 4);
  bf16*  H1tb = (bf16*)alloc((size_t)BATCH * NPT * DMID * 2);
  float* H    = (float*)alloc((size_t)BATCH * STRD * 4);
  bf16*  Ht   = (bf16*)alloc((size_t)BATCH * STRD * 2);
  bf16*  QKt  = (bf16*)alloc((size_t)BATCH * QKS * 2);   // [b][n][512] = Q(0..255) | K(256..511)
  bf16*  Vb   = (bf16*)alloc((size_t)BATCH * STRD * 2);
  bf16*  W2b  = (bf16*)alloc((size_t)DEMB * DMID * 2);
  bf16*  WQKb = (bf16*)alloc((size_t)NSA * 512 * DEMB * 2);
  bf16*  WVb  = (bf16*)alloc((size_t)NSA * DEMB * DEMB * 2);
  float* pS   = (float*)alloc(128 * 64 * 4);
  float* pS2  = (float*)alloc(128 * 64 * 4);
  float* sa1  = (float*)alloc(64 * 4);
  float* sb1  = (float*)alloc(64 * 4);
  float* sa2  = (float*)alloc(256 * 4);
  float* sb2  = (float*)alloc(256 * 4);
  float* CM   = (float*)alloc((size_t)BATCH * NPT * 4);
  float* CSi  = (float*)alloc((size_t)BATCH * NPT * 4);
  float* PM   = (float*)alloc((size_t)BATCH * 16 * NPT * 4);
  float* PSm  = (float*)alloc((size_t)BATCH * 16 * NPT * 4);
  float* POOL = (float*)alloc((size_t)BATCH * NPT * 4);
  float* FH   = (float*)alloc((size_t)BATCH * NPT * 4);
  size_t used = (size_t)(p - (char*)d_ws);
  const size_t per_g = (size_t)NN * 4;  // F f32 (16MB per batch)
  int G = 8;
  while (G > 1 && used + (size_t)G * per_g + 1024 > ws_size) G >>= 1;
  float* F = (float*)alloc((size_t)G * NN * 4);

  // ---- weight converts ----
  k_cvt<<<(DEMB * DMID + 255) / 256, 256, 0, stream>>>(W2, W2b, DEMB * DMID);
  int nqk = NSA * 512 * DEMB;
  k_cvtqk<<<nqk / 256, 256, 0, stream>>>(WQ, WK, WQKb);
  int nw = NSA * DEMB * DEMB;
  k_cvt<<<(nw + 255) / 256, 256, 0, stream>>>(WV, WVb, nw);

  // ---- conv1 + BN1 + ReLU (-> H1tb bf16 [b][n][64]) ----
  long szh1 = (long)BATCH * NPT * DMID;
  k_conv1t<<<(int)(szh1 / 256), 256, 0, stream>>>(X, W1, B1, H1t);
  k_bn1a<<<128, 256, 0, stream>>>(H1t, pS, pS2);
  k_bn1b<<<1, 64, 0, stream>>>(pS, pS2, G1, BE1, sa1, sb1);
  k_bn1apply<<<(int)(szh1 / 256), 256, 0, stream>>>(H1t, sa1, sb1, H1tb);

  // ---- conv2 (MFMA) + BN2 + ReLU -> H fp32 [b][256][2048] ----
  k_mgemm<2><<<dim3(16, 2, 8), 256, 0, stream>>>(W2b, 0, DMID, H1tb, (long)NPT * DMID, DMID,
                                                 H, STRD, NPT, DMID, B2, nullptr, nullptr);
  k_bnstats<<<DEMB, 256, 0, stream>>>(H, DEMB, G2, BE2, sa2, sb2);
  k_bnapply<<<(int)(BATCH * STRD / 256), 256, 0, stream>>>(H, sa2, sb2, DEMB, (int)(BATCH * STRD));

  // ---- SA layers ----
  for (int l = 0; l < NSA; ++l) {
    k_tcvt<<<dim3(32, 4, 8), 256, 0, stream>>>(H, Ht);
    // QKt[n][0..511] = Ht . [Wq;Wk]^T  : A=Ht (M=2048), B=WQK (N=512)
    k_mgemm<1><<<dim3(4, 16, 8), 256, 0, stream>>>(Ht, STRD, DEMB, WQKb + (long)l * 512 * DEMB, 0, DEMB,
                                                   QKt, QKS, 512, DEMB, nullptr, nullptr, nullptr);
    // V[e][n] : A=Wv (M=256), B=Ht (N=2048)
    k_mgemm<1><<<dim3(16, 2, 8), 256, 0, stream>>>(WVb + (long)l * DEMB * DEMB, 0, DEMB, Ht, STRD, DEMB,
                                                   Vb, STRD, NPT, DEMB, nullptr, nullptr, nullptr);
    for (int b0 = 0; b0 < BATCH; b0 += G) {
      // F[m][n] = sum_a Kt[m][a] Qt[n][a] (= E^T), fp32 + fused column stats
      k_mgemm<0><<<dim3(16, 16, G), 256, 0, stream>>>(QKt + 256 + b0 * QKS, QKS, 512,
                                                      QKt + b0 * QKS, QKS, 512,
                                                      F, NN, NPT, DEMB, nullptr, PM, PSm);
      k_cms_fin<<<G * NPT / 256, 256, 0, stream>>>(PM, PSm, CM, CSi);
      // H[e][m] += S[m] * sum_n V[e][n] PT[m][n]  (PT from F on the fly)
      k_vp<<<dim3(64, G), 256, 0, stream>>>(F, CM, CSi, Vb + b0 * STRD, H + b0 * STRD);
    }
  }

  // ---- head ----
  k_pool<<<(BATCH * NPT) / 256, 256, 0, stream>>>(H, POOL);
  k_fc1<<<dim3(NPT, BATCH), 256, 0, stream>>>(POOL, FC1W, FC1B, FH);
  k_fc2<<<BATCH, 256, 0, stream>>>(FH, FC2W, FC2B, OUT);
}

// Round 7
// 547.121 us; speedup vs baseline: 10.7540x; 1.0568x over previous
//
#include <hip/hip_runtime.h>
#include <hip/hip_bf16.h>

typedef __hip_bfloat16 bf16;
#define DEVI __device__ __forceinline__

// Problem constants
static constexpr int BATCH = 8;
static constexpr int NPT   = 2048;
static constexpr int DMID  = 64;
static constexpr int DEMB  = 256;
static constexpr int NSA   = 4;
static constexpr long STRD = (long)DEMB * NPT;  // 524288
static constexpr long QKS  = (long)NPT * 512;   // per-batch stride of QKt
static constexpr long NN   = (long)NPT * NPT;   // 4194304

typedef __attribute__((ext_vector_type(4))) float f32x4;
typedef __attribute__((ext_vector_type(8))) short bf16x8v;

DEVI f32x4 MFMA16(bf16x8v a, bf16x8v b, f32x4 c) {
  return __builtin_amdgcn_mfma_f32_16x16x32_bf16(a, b, c, 0, 0, 0);
}

DEVI void gload16(const bf16* g, bf16* l) {
  __builtin_amdgcn_global_load_lds(
      (const __attribute__((address_space(1))) void*)g,
      (__attribute__((address_space(3))) void*)l, 16, 0, 0);
}

DEVI float waveReduceSum(float v) {
#pragma unroll
  for (int o = 32; o > 0; o >>= 1) v += __shfl_down(v, o, 64);
  return v;
}
DEVI float blockReduceSum(float v) {
  __shared__ float sm[4];
  int lane = threadIdx.x & 63, wid = threadIdx.x >> 6;
  __syncthreads();
  v = waveReduceSum(v);
  if (lane == 0) sm[wid] = v;
  __syncthreads();
  return sm[0] + sm[1] + sm[2] + sm[3];
}

// ---- fp32 -> bf16 convert ----
__global__ void k_cvt(const float* __restrict__ in, bf16* __restrict__ out, int n) {
  int i = blockIdx.x * 256 + threadIdx.x;
  if (i < n) out[i] = __float2bfloat16(in[i]);
}

// ---- concat-convert Wq,Wk -> WQKb [l][512][256] bf16 ----
__global__ void k_cvtqk(const float* __restrict__ wq, const float* __restrict__ wk,
                        bf16* __restrict__ o) {
  int idx = blockIdx.x * 256 + threadIdx.x;  // NSA*512*256
  int c = idx & 255;
  int r = (idx >> 8) & 511;
  int l = idx >> 17;
  float v = (r < 256) ? wq[((l << 8) + r) * 256 + c] : wk[((l << 8) + (r - 256)) * 256 + c];
  o[idx] = __float2bfloat16(v);
}

// ---- conv1: H1t[b][n][o] = sum_c x[b,n,c]*w1[o,c] + b1[o] ----
__global__ void k_conv1t(const float* __restrict__ x, const float* __restrict__ w1,
                         const float* __restrict__ b1, float* __restrict__ h1t) {
  long idx = (long)blockIdx.x * 256 + threadIdx.x;  // [b*n][o]
  int o = idx & 63;
  long bn = idx >> 6;
  const float* xp = x + bn * 3;
  h1t[idx] = b1[o] + xp[0] * w1[o * 3] + xp[1] * w1[o * 3 + 1] + xp[2] * w1[o * 3 + 2];
}

// ---- BN1 stats on H1t [16384][64] ----
__global__ __launch_bounds__(256) void k_bn1a(const float* __restrict__ h, float* __restrict__ pS,
                                              float* __restrict__ pS2) {
  int c = threadIdx.x & 63, rg = threadIdx.x >> 6;
  long r0 = (long)blockIdx.x * 128 + rg * 32;
  float s = 0.f, s2 = 0.f;
  for (int i = 0; i < 32; ++i) {
    float v = h[(r0 + i) * 64 + c];
    s += v; s2 += v * v;
  }
  __shared__ float smS[256], smS2[256];
  smS[threadIdx.x] = s; smS2[threadIdx.x] = s2;
  __syncthreads();
  if (threadIdx.x < 64) {
    float a = 0.f, b = 0.f;
#pragma unroll
    for (int g = 0; g < 4; ++g) { a += smS[g * 64 + c]; b += smS2[g * 64 + c]; }
    pS[blockIdx.x * 64 + c] = a;
    pS2[blockIdx.x * 64 + c] = b;
  }
}
__global__ void k_bn1b(const float* __restrict__ pS, const float* __restrict__ pS2,
                       const float* __restrict__ g, const float* __restrict__ be,
                       float* __restrict__ sa, float* __restrict__ sb) {
  int c = threadIdx.x;
  if (c >= 64) return;
  float s = 0.f, s2 = 0.f;
  for (int i = 0; i < 128; ++i) { s += pS[i * 64 + c]; s2 += pS2[i * 64 + c]; }
  const float inv = 1.0f / (BATCH * NPT);
  float m = s * inv, var = s2 * inv - m * m;
  float A = rsqrtf(var + 1e-5f) * g[c];
  sa[c] = A; sb[c] = be[c] - m * A;
}
__global__ void k_bn1apply(const float* __restrict__ h, const float* __restrict__ sa,
                           const float* __restrict__ sb, bf16* __restrict__ o) {
  long idx = (long)blockIdx.x * 256 + threadIdx.x;
  int c = idx & 63;
  float v = fmaf(h[idx], sa[c], sb[c]);
  o[idx] = __float2bfloat16(v > 0.f ? v : 0.f);
}

// ---- BN2 stats/apply on H [b][256][2048] fp32 ----
__global__ __launch_bounds__(256) void k_bnstats(const float* __restrict__ h, int Cc,
                                                 const float* __restrict__ g, const float* __restrict__ be,
                                                 float* __restrict__ sa, float* __restrict__ sb) {
  int c = blockIdx.x;
  float s = 0.f, s2 = 0.f;
  for (int b = 0; b < BATCH; ++b) {
    const float* p = h + ((long)(b * Cc + c)) * NPT;
    for (int n = threadIdx.x; n < NPT; n += 256) {
      float v = p[n];
      s += v; s2 += v * v;
    }
  }
  s = blockReduceSum(s);
  s2 = blockReduceSum(s2);
  if (threadIdx.x == 0) {
    const float inv = 1.0f / (BATCH * NPT);
    float m = s * inv, var = s2 * inv - m * m;
    float A = rsqrtf(var + 1e-5f) * g[c];
    sa[c] = A; sb[c] = be[c] - m * A;
  }
}
__global__ void k_bnapply(float* __restrict__ h, const float* __restrict__ sa,
                          const float* __restrict__ sb, int Cc, int total) {
  int i = blockIdx.x * 256 + threadIdx.x;
  if (i >= total) return;
  int c = (i >> 11) & (Cc - 1);
  float v = fmaf(h[i], sa[c], sb[c]);
  h[i] = v > 0.f ? v : 0.f;
}

// ---- tiled transpose+convert: H [b][256][2048] f32 -> Ht [b][2048][256] bf16 ----
__global__ __launch_bounds__(256) void k_tcvt(const float* __restrict__ H, bf16* __restrict__ Ht) {
  __shared__ float t[64][65];
  const float* h = H + (long)blockIdx.z * STRD;
  bf16* o = Ht + (long)blockIdx.z * STRD;
  int n0 = blockIdx.x * 64, c0 = blockIdx.y * 64;
#pragma unroll
  for (int ii = 0; ii < 16; ++ii) {
    int idx = ii * 256 + threadIdx.x;
    int i = idx >> 6, j = idx & 63;
    t[i][j] = h[(long)(c0 + i) * NPT + n0 + j];
  }
  __syncthreads();
#pragma unroll
  for (int ii = 0; ii < 16; ++ii) {
    int idx = ii * 256 + threadIdx.x;
    int i = idx >> 6, j = idx & 63;
    o[(long)(n0 + i) * DEMB + c0 + j] = __float2bfloat16(t[j][i]);
  }
}

// ---- MFMA GEMM, B^T form: C[M][N] = A[M][K] . B[N][K]^T ; 128x128 tile, BK=64 ----
// XOR-swizzled LDS (granule ^= row&7) on both staging-source and read.
// MODE 0: C bf16 = acc, PLUS column-softmax partial stats from fp32 acc (PM/PS)
// MODE 1: C bf16 = acc
// MODE 2: C f32 = acc + bias[r]
template <int MODE>
__global__ __launch_bounds__(256) void k_mgemm(
    const bf16* __restrict__ A, long aStr, int ldA,
    const bf16* __restrict__ B, long bStr, int ldB,
    void* __restrict__ Cv, long cStr, int ldC,
    int K,
    const float* __restrict__ bias,
    float* __restrict__ PMo, float* __restrict__ PSo) {
  __shared__ __align__(16) bf16 sA[128 * 64];
  __shared__ __align__(16) bf16 sB[128 * 64];
  __shared__ float smx[4][64], ssx[4][64];
  const int z = blockIdx.z;
  A += aStr * z;
  B += bStr * z;
  const int bm = blockIdx.y * 128, bn = blockIdx.x * 128;
  const int tid = threadIdx.x;
  const int lane = tid & 63, wv = tid >> 6;
  const int wr = (wv >> 1) * 64, wc = (wv & 1) * 64;
  f32x4 acc[4][4] = {};

  for (int k0 = 0; k0 < K; k0 += 64) {
#pragma unroll
    for (int i = 0; i < 4; ++i) {
      int c = i * 256 + tid;
      int row = c >> 3, g = c & 7;
      int gs = (g ^ (row & 7)) * 8;
      gload16(A + (long)(bm + row) * ldA + k0 + gs, sA + c * 8);
      gload16(B + (long)(bn + row) * ldB + k0 + gs, sB + c * 8);
    }
    __syncthreads();
    bf16x8v af[4][2], bfr[4][2];
#pragma unroll
    for (int mi = 0; mi < 4; ++mi)
#pragma unroll
      for (int ks = 0; ks < 2; ++ks) {
        int rA = wr + mi * 16 + (lane & 15);
        int rB = wc + mi * 16 + (lane & 15);
        int g = ks * 4 + (lane >> 4);
        af[mi][ks]  = *(const bf16x8v*)&sA[rA * 64 + ((g ^ (rA & 7)) * 8)];
        bfr[mi][ks] = *(const bf16x8v*)&sB[rB * 64 + ((g ^ (rB & 7)) * 8)];
      }
#pragma unroll
    for (int ks = 0; ks < 2; ++ks)
#pragma unroll
      for (int mi = 0; mi < 4; ++mi)
#pragma unroll
        for (int ni = 0; ni < 4; ++ni)
          acc[mi][ni] = MFMA16(af[mi][ks], bfr[ni][ks], acc[mi][ni]);
    __syncthreads();
  }

  const int rb = (lane >> 4) * 4, cb = lane & 15;
  if constexpr (MODE == 0 || MODE == 1) {
    bf16* C = (bf16*)Cv + cStr * z;
#pragma unroll
    for (int mi = 0; mi < 4; ++mi)
#pragma unroll
      for (int ni = 0; ni < 4; ++ni) {
        int r0 = bm + wr + mi * 16 + rb, c0 = bn + wc + ni * 16 + cb;
#pragma unroll
        for (int k = 0; k < 4; ++k)
          C[(long)(r0 + k) * ldC + c0] = __float2bfloat16(acc[mi][ni][k]);
      }
  } else {
    float* C = (float*)Cv + cStr * z;
#pragma unroll
    for (int mi = 0; mi < 4; ++mi)
#pragma unroll
      for (int ni = 0; ni < 4; ++ni) {
        int r0 = bm + wr + mi * 16 + rb, c0 = bn + wc + ni * 16 + cb;
#pragma unroll
        for (int k = 0; k < 4; ++k) {
          int r = r0 + k;
          C[(long)r * ldC + c0] = acc[mi][ni][k] + bias[r];
        }
      }
  }

  if constexpr (MODE == 0) {
    // per-column (over this block's 128 rows) online-softmax partials (exact fp32)
    float cm[4], cs[4];
#pragma unroll
    for (int ni = 0; ni < 4; ++ni) {
      float m = -3.0e38f;
#pragma unroll
      for (int mi = 0; mi < 4; ++mi)
#pragma unroll
        for (int k = 0; k < 4; ++k) m = fmaxf(m, acc[mi][ni][k]);
      float s = 0.f;
#pragma unroll
      for (int mi = 0; mi < 4; ++mi)
#pragma unroll
        for (int k = 0; k < 4; ++k) s += __expf(acc[mi][ni][k] - m);
#pragma unroll
      for (int off = 16; off <= 32; off <<= 1) {
        float mo = __shfl_xor(m, off, 64);
        float so = __shfl_xor(s, off, 64);
        float M = fmaxf(m, mo);
        s = s * __expf(m - M) + so * __expf(mo - M);
        m = M;
      }
      cm[ni] = m; cs[ni] = s;
    }
    __syncthreads();  // LDS reads of K-loop complete; reuse smx/ssx safely
    if (lane < 16) {
#pragma unroll
      for (int ni = 0; ni < 4; ++ni) {
        smx[wv][ni * 16 + lane] = cm[ni];
        ssx[wv][ni * 16 + lane] = cs[ni];
      }
    }
    __syncthreads();
    if (tid < 128) {
      int half = tid >> 6, c64 = tid & 63;
      float m1 = smx[half][c64], s1 = ssx[half][c64];
      float m2 = smx[half + 2][c64], s2 = ssx[half + 2][c64];
      float M = fmaxf(m1, m2);
      float S = s1 * __expf(m1 - M) + s2 * __expf(m2 - M);
      long o = ((long)z * 16 + blockIdx.y) * NPT + bn + half * 64 + c64;
      PMo[o] = M;
      PSo[o] = S;
    }
  }
}

// ---- combine 16 partials per column -> CM, CSi ----
__global__ void k_cms_fin(const float* __restrict__ PM, const float* __restrict__ PS,
                          float* __restrict__ CM, float* __restrict__ CSi) {
  long idx = (long)blockIdx.x * 256 + threadIdx.x;  // [G*NPT]
  long z = idx >> 11;
  int n = idx & (NPT - 1);
  const float* pm = PM + z * 16 * NPT + n;
  const float* ps = PS + z * 16 * NPT + n;
  float m = -3.0e38f;
#pragma unroll
  for (int y = 0; y < 16; ++y) m = fmaxf(m, pm[(long)y * NPT]);
  float s = 0.f;
#pragma unroll
  for (int y = 0; y < 16; ++y) s += ps[(long)y * NPT] * __expf(pm[(long)y * NPT] - m);
  CM[idx] = m;
  CSi[idx] = 1.0f / s;
}

// ---- fused normalize + rowsum + V.P GEMM (F in bf16) ----
// Per block: e = 0..255 (M), m in [m0, m0+32) (N), K = n = 0..2047. grid (64, G).
__global__ __launch_bounds__(256) void k_vp(const bf16* __restrict__ F,
                                            const float* __restrict__ CM,
                                            const float* __restrict__ CSi,
                                            const bf16* __restrict__ V,
                                            float* __restrict__ H) {
  __shared__ __align__(16) bf16 sA[256 * 64];  // V tile [e][n]
  __shared__ __align__(16) bf16 sB[32 * 64];   // PT tile [m][n]
  __shared__ float rsLds[8][32];
  __shared__ float Sv[32];
  const int z = blockIdx.y;
  const int m0 = blockIdx.x * 32;
  const int tid = threadIdx.x;
  const int lane = tid & 63, wv = tid >> 6;
  const int mloc = tid & 31, seg = tid >> 5;
  const bf16* Vz = V + (long)z * STRD;
  const bf16* Fr = F + (long)z * NN + (long)(m0 + mloc) * NPT + seg * 8;
  const float* CMz = CM + (long)z * NPT + seg * 8;
  const float* CSz = CSi + (long)z * NPT + seg * 8;
  f32x4 acc[4][2] = {};
  float rs = 0.f;
  bf16x8v fvA, fvB;
  fvA = *(const bf16x8v*)(Fr);

#define VP_STEP(CUR, NXT, STEPI)                                               \
  {                                                                            \
    const int n0 = (STEPI) * 64;                                               \
    float mv[8], cv[8];                                                        \
    *(float4*)&mv[0] = *(const float4*)(CMz + n0);                             \
    *(float4*)&mv[4] = *(const float4*)(CMz + n0 + 4);                         \
    *(float4*)&cv[0] = *(const float4*)(CSz + n0);                             \
    *(float4*)&cv[4] = *(const float4*)(CSz + n0 + 4);                         \
    bf16 tb[8];                                                                \
    _Pragma("unroll") for (int i = 0; i < 8; ++i) {                            \
      float fvi = __uint_as_float((unsigned)(unsigned short)CUR[i] << 16);     \
      float pv = __expf(fvi - mv[i]) * cv[i];                                  \
      rs += pv;                                                                \
      tb[i] = __float2bfloat16(pv);                                            \
    }                                                                          \
    __syncthreads();                                                           \
    *(bf16x8v*)&sB[mloc * 64 + ((seg ^ (mloc & 7)) * 8)] = *(bf16x8v*)tb;      \
    _Pragma("unroll") for (int i = 0; i < 8; ++i) {                            \
      int c = i * 256 + tid;                                                   \
      int row = c >> 3, g = c & 7;                                             \
      gload16(Vz + (long)row * NPT + n0 + ((g ^ (row & 7)) * 8), sA + c * 8);  \
    }                                                                          \
    if ((STEPI) + 1 < 32) {                                                    \
      NXT = *(const bf16x8v*)(Fr + n0 + 64);                                   \
    }                                                                          \
    __syncthreads();                                                           \
    bf16x8v bfr[2][2];                                                         \
    _Pragma("unroll") for (int ni = 0; ni < 2; ++ni)                           \
      _Pragma("unroll") for (int ks = 0; ks < 2; ++ks) {                       \
        int rB = ni * 16 + (lane & 15);                                        \
        int g = ks * 4 + (lane >> 4);                                          \
        bfr[ni][ks] = *(const bf16x8v*)&sB[rB * 64 + ((g ^ (rB & 7)) * 8)];    \
      }                                                                        \
    _Pragma("unroll") for (int mi = 0; mi < 4; ++mi)                           \
      _Pragma("unroll") for (int ks = 0; ks < 2; ++ks) {                       \
        int rA = (wv * 4 + mi) * 16 + (lane & 15);                             \
        int g = ks * 4 + (lane >> 4);                                          \
        bf16x8v af = *(const bf16x8v*)&sA[rA * 64 + ((g ^ (rA & 7)) * 8)];     \
        _Pragma("unroll") for (int ni = 0; ni < 2; ++ni)                       \
          acc[mi][ni] = MFMA16(af, bfr[ni][ks], acc[mi][ni]);                  \
      }                                                                        \
  }

  for (int it = 0; it < 16; ++it) {
    VP_STEP(fvA, fvB, 2 * it);
    VP_STEP(fvB, fvA, 2 * it + 1);
  }
#undef VP_STEP

  __syncthreads();
  rsLds[seg][mloc] = rs;
  __syncthreads();
  if (tid < 32) {
    float R = 0.f;
#pragma unroll
    for (int s = 0; s < 8; ++s) R += rsLds[s][tid];
    Sv[tid] = 1.0f / (1e-9f + R);
  }
  __syncthreads();

  float* Hz = H + (long)z * STRD;
  const int rb = (lane >> 4) * 4, cb = lane & 15;
#pragma unroll
  for (int mi = 0; mi < 4; ++mi) {
    int e0 = (wv * 4 + mi) * 16 + rb;
#pragma unroll
    for (int ni = 0; ni < 2; ++ni) {
      int c = ni * 16 + cb;
      float scl = Sv[c];
#pragma unroll
      for (int k = 0; k < 4; ++k)
        Hz[(long)(e0 + k) * NPT + m0 + c] += acc[mi][ni][k] * scl;
    }
  }
}

// ---- pooled[b,n] = mean over e of H[b,e,n] ----
__global__ void k_pool(const float* __restrict__ H, float* __restrict__ pooled) {
  int i = blockIdx.x * 256 + threadIdx.x;
  if (i >= BATCH * NPT) return;
  int b = i >> 11, n = i & (NPT - 1);
  const float* p = H + (long)b * STRD + n;
  float s = 0.f;
  for (int e = 0; e < DEMB; ++e) s += p[(long)e * NPT];
  pooled[i] = s * (1.0f / DEMB);
}

// ---- fc1 ----
__global__ __launch_bounds__(256) void k_fc1(const float* __restrict__ pooled,
                                             const float* __restrict__ w, const float* __restrict__ bias,
                                             float* __restrict__ f) {
  int j = blockIdx.x, b = blockIdx.y;
  const float* pp = pooled + (long)b * NPT;
  const float* wr = w + (long)j * NPT;
  float s = 0.f;
  for (int n = threadIdx.x; n < NPT; n += 256) s += pp[n] * wr[n];
  s = blockReduceSum(s);
  if (threadIdx.x == 0) {
    s += bias[j];
    f[(long)b * NPT + j] = s > 0.f ? s : 0.f;
  }
}

// ---- fc2 ----
__global__ __launch_bounds__(256) void k_fc2(const float* __restrict__ f,
                                             const float* __restrict__ w, const float* __restrict__ bias,
                                             float* __restrict__ out) {
  int b = blockIdx.x;
  float s = 0.f;
  for (int j = threadIdx.x; j < NPT; j += 256) s += f[(long)b * NPT + j] * w[j];
  s = blockReduceSum(s);
  if (threadIdx.x == 0) out[b] = s + bias[0];
}

extern "C" void kernel_launch(void* const* d_in, const int* in_sizes, int n_in,
                              void* d_out, int out_size, void* d_ws, size_t ws_size,
                              hipStream_t stream) {
  const float* X    = (const float*)d_in[0];
  const float* W1   = (const float*)d_in[1];
  const float* B1   = (const float*)d_in[2];
  const float* G1   = (const float*)d_in[3];
  const float* BE1  = (const float*)d_in[4];
  const float* W2   = (const float*)d_in[5];
  const float* B2   = (const float*)d_in[6];
  const float* G2   = (const float*)d_in[7];
  const float* BE2  = (const float*)d_in[8];
  const float* WQ   = (const float*)d_in[9];
  const float* WK   = (const float*)d_in[10];
  const float* WV   = (const float*)d_in[11];
  const float* FC1W = (const float*)d_in[12];
  const float* FC1B = (const float*)d_in[13];
  const float* FC2W = (const float*)d_in[14];
  const float* FC2B = (const float*)d_in[15];
  float* OUT = (float*)d_out;

  // ---- workspace carve-out ----
  char* p = (char*)d_ws;
  auto alloc = [&](size_t bytes) -> char* {
    char* r = p;
    p += (bytes + 255) & ~(size_t)255;
    return r;
  };
  float* H1t  = (float*)alloc((size_t)BATCH * NPT * DMID * 4);
  bf16*  H1tb = (bf16*)alloc((size_t)BATCH * NPT * DMID * 2);
  float* H    = (float*)alloc((size_t)BATCH * STRD * 4);
  bf16*  Ht   = (bf16*)alloc((size_t)BATCH * STRD * 2);
  bf16*  QKt  = (bf16*)alloc((size_t)BATCH * QKS * 2);   // [b][n][512] = Q(0..255) | K(256..511)
  bf16*  Vb   = (bf16*)alloc((size_t)BATCH * STRD * 2);
  bf16*  W2b  = (bf16*)alloc((size_t)DEMB * DMID * 2);
  bf16*  WQKb = (bf16*)alloc((size_t)NSA * 512 * DEMB * 2);
  bf16*  WVb  = (bf16*)alloc((size_t)NSA * DEMB * DEMB * 2);
  float* pS   = (float*)alloc(128 * 64 * 4);
  float* pS2  = (float*)alloc(128 * 64 * 4);
  float* sa1  = (float*)alloc(64 * 4);
  float* sb1  = (float*)alloc(64 * 4);
  float* sa2  = (float*)alloc(256 * 4);
  float* sb2  = (float*)alloc(256 * 4);
  float* CM   = (float*)alloc((size_t)BATCH * NPT * 4);
  float* CSi  = (float*)alloc((size_t)BATCH * NPT * 4);
  float* PM   = (float*)alloc((size_t)BATCH * 16 * NPT * 4);
  float* PSm  = (float*)alloc((size_t)BATCH * 16 * NPT * 4);
  float* POOL = (float*)alloc((size_t)BATCH * NPT * 4);
  float* FH   = (float*)alloc((size_t)BATCH * NPT * 4);
  size_t used = (size_t)(p - (char*)d_ws);
  const size_t per_g = (size_t)NN * 2;  // F bf16 (8MB per batch)
  int G = 8;
  while (G > 1 && used + (size_t)G * per_g + 1024 > ws_size) G >>= 1;
  bf16* F = (bf16*)alloc((size_t)G * NN * 2);

  // ---- weight converts ----
  k_cvt<<<(DEMB * DMID + 255) / 256, 256, 0, stream>>>(W2, W2b, DEMB * DMID);
  int nqk = NSA * 512 * DEMB;
  k_cvtqk<<<nqk / 256, 256, 0, stream>>>(WQ, WK, WQKb);
  int nw = NSA * DEMB * DEMB;
  k_cvt<<<(nw + 255) / 256, 256, 0, stream>>>(WV, WVb, nw);

  // ---- conv1 + BN1 + ReLU (-> H1tb bf16 [b][n][64]) ----
  long szh1 = (long)BATCH * NPT * DMID;
  k_conv1t<<<(int)(szh1 / 256), 256, 0, stream>>>(X, W1, B1, H1t);
  k_bn1a<<<128, 256, 0, stream>>>(H1t, pS, pS2);
  k_bn1b<<<1, 64, 0, stream>>>(pS, pS2, G1, BE1, sa1, sb1);
  k_bn1apply<<<(int)(szh1 / 256), 256, 0, stream>>>(H1t, sa1, sb1, H1tb);

  // ---- conv2 (MFMA) + BN2 + ReLU -> H fp32 [b][256][2048] ----
  k_mgemm<2><<<dim3(16, 2, 8), 256, 0, stream>>>(W2b, 0, DMID, H1tb, (long)NPT * DMID, DMID,
                                                 H, STRD, NPT, DMID, B2, nullptr, nullptr);
  k_bnstats<<<DEMB, 256, 0, stream>>>(H, DEMB, G2, BE2, sa2, sb2);
  k_bnapply<<<(int)(BATCH * STRD / 256), 256, 0, stream>>>(H, sa2, sb2, DEMB, (int)(BATCH * STRD));

  // ---- SA layers ----
  for (int l = 0; l < NSA; ++l) {
    k_tcvt<<<dim3(32, 4, 8), 256, 0, stream>>>(H, Ht);
    // QKt[n][0..511] = Ht . [Wq;Wk]^T  : A=Ht (M=2048), B=WQK (N=512)
    k_mgemm<1><<<dim3(4, 16, 8), 256, 0, stream>>>(Ht, STRD, DEMB, WQKb + (long)l * 512 * DEMB, 0, DEMB,
                                                   QKt, QKS, 512, DEMB, nullptr, nullptr, nullptr);
    // V[e][n] : A=Wv (M=256), B=Ht (N=2048)
    k_mgemm<1><<<dim3(16, 2, 8), 256, 0, stream>>>(WVb + (long)l * DEMB * DEMB, 0, DEMB, Ht, STRD, DEMB,
                                                   Vb, STRD, NPT, DEMB, nullptr, nullptr, nullptr);
    for (int b0 = 0; b0 < BATCH; b0 += G) {
      // F[m][n] = sum_a Kt[m][a] Qt[n][a] (= E^T), bf16 + fused exact column stats
      k_mgemm<0><<<dim3(16, 16, G), 256, 0, stream>>>(QKt + 256 + b0 * QKS, QKS, 512,
                                                      QKt + b0 * QKS, QKS, 512,
                                                      F, NN, NPT, DEMB, nullptr, PM, PSm);
      k_cms_fin<<<G * NPT / 256, 256, 0, stream>>>(PM, PSm, CM, CSi);
      // H[e][m] += S[m] * sum_n V[e][n] PT[m][n]  (PT from bf16 F on the fly)
      k_vp<<<dim3(64, G), 256, 0, stream>>>(F, CM, CSi, Vb + b0 * STRD, H + b0 * STRD);
    }
  }

  // ---- head ----
  k_pool<<<(BATCH * NPT) / 256, 256, 0, stream>>>(H, POOL);
  k_fc1<<<dim3(NPT, BATCH), 256, 0, stream>>>(POOL, FC1W, FC1B, FH);
  k_fc2<<<BATCH, 256, 0, stream>>>(FH, FC2W, FC2B, OUT);
}

// Round 8
// 535.339 us; speedup vs baseline: 10.9907x; 1.0220x over previous
//
#include <hip/hip_runtime.h>
#include <hip/hip_bf16.h>

typedef __hip_bfloat16 bf16;
#define DEVI __device__ __forceinline__

// Problem constants
static constexpr int BATCH = 8;
static constexpr int NPT   = 2048;
static constexpr int DMID  = 64;
static constexpr int DEMB  = 256;
static constexpr int NSA   = 4;
static constexpr long STRD = (long)DEMB * NPT;  // 524288
static constexpr long QKS  = (long)NPT * 512;   // per-batch stride of QKt
static constexpr long NN   = (long)NPT * NPT;   // 4194304

typedef __attribute__((ext_vector_type(4))) float f32x4;
typedef __attribute__((ext_vector_type(8))) short bf16x8v;

DEVI f32x4 MFMA16(bf16x8v a, bf16x8v b, f32x4 c) {
  return __builtin_amdgcn_mfma_f32_16x16x32_bf16(a, b, c, 0, 0, 0);
}

DEVI void gload16(const bf16* g, bf16* l) {
  __builtin_amdgcn_global_load_lds(
      (const __attribute__((address_space(1))) void*)g,
      (__attribute__((address_space(3))) void*)l, 16, 0, 0);
}

DEVI float waveReduceSum(float v) {
#pragma unroll
  for (int o = 32; o > 0; o >>= 1) v += __shfl_down(v, o, 64);
  return v;
}
DEVI float blockReduceSum(float v) {
  __shared__ float sm[4];
  int lane = threadIdx.x & 63, wid = threadIdx.x >> 6;
  __syncthreads();
  v = waveReduceSum(v);
  if (lane == 0) sm[wid] = v;
  __syncthreads();
  return sm[0] + sm[1] + sm[2] + sm[3];
}

// ---- fp32 -> bf16 convert ----
__global__ void k_cvt(const float* __restrict__ in, bf16* __restrict__ out, int n) {
  int i = blockIdx.x * 256 + threadIdx.x;
  if (i < n) out[i] = __float2bfloat16(in[i]);
}

// ---- concat-convert Wq,Wk -> WQKb [l][512][256] bf16 ----
__global__ void k_cvtqk(const float* __restrict__ wq, const float* __restrict__ wk,
                        bf16* __restrict__ o) {
  int idx = blockIdx.x * 256 + threadIdx.x;  // NSA*512*256
  int c = idx & 255;
  int r = (idx >> 8) & 511;
  int l = idx >> 17;
  float v = (r < 256) ? wq[((l << 8) + r) * 256 + c] : wk[((l << 8) + (r - 256)) * 256 + c];
  o[idx] = __float2bfloat16(v);
}

// ---- conv1: H1t[b][n][o] = sum_c x[b,n,c]*w1[o,c] + b1[o] ----
__global__ void k_conv1t(const float* __restrict__ x, const float* __restrict__ w1,
                         const float* __restrict__ b1, float* __restrict__ h1t) {
  long idx = (long)blockIdx.x * 256 + threadIdx.x;  // [b*n][o]
  int o = idx & 63;
  long bn = idx >> 6;
  const float* xp = x + bn * 3;
  h1t[idx] = b1[o] + xp[0] * w1[o * 3] + xp[1] * w1[o * 3 + 1] + xp[2] * w1[o * 3 + 2];
}

// ---- BN1 stats on H1t [16384][64] ----
__global__ __launch_bounds__(256) void k_bn1a(const float* __restrict__ h, float* __restrict__ pS,
                                              float* __restrict__ pS2) {
  int c = threadIdx.x & 63, rg = threadIdx.x >> 6;
  long r0 = (long)blockIdx.x * 128 + rg * 32;
  float s = 0.f, s2 = 0.f;
  for (int i = 0; i < 32; ++i) {
    float v = h[(r0 + i) * 64 + c];
    s += v; s2 += v * v;
  }
  __shared__ float smS[256], smS2[256];
  smS[threadIdx.x] = s; smS2[threadIdx.x] = s2;
  __syncthreads();
  if (threadIdx.x < 64) {
    float a = 0.f, b = 0.f;
#pragma unroll
    for (int g = 0; g < 4; ++g) { a += smS[g * 64 + c]; b += smS2[g * 64 + c]; }
    pS[blockIdx.x * 64 + c] = a;
    pS2[blockIdx.x * 64 + c] = b;
  }
}
__global__ void k_bn1b(const float* __restrict__ pS, const float* __restrict__ pS2,
                       const float* __restrict__ g, const float* __restrict__ be,
                       float* __restrict__ sa, float* __restrict__ sb) {
  int c = threadIdx.x;
  if (c >= 64) return;
  float s = 0.f, s2 = 0.f;
  for (int i = 0; i < 128; ++i) { s += pS[i * 64 + c]; s2 += pS2[i * 64 + c]; }
  const float inv = 1.0f / (BATCH * NPT);
  float m = s * inv, var = s2 * inv - m * m;
  float A = rsqrtf(var + 1e-5f) * g[c];
  sa[c] = A; sb[c] = be[c] - m * A;
}
__global__ void k_bn1apply(const float* __restrict__ h, const float* __restrict__ sa,
                           const float* __restrict__ sb, bf16* __restrict__ o) {
  long idx = (long)blockIdx.x * 256 + threadIdx.x;
  int c = idx & 63;
  float v = fmaf(h[idx], sa[c], sb[c]);
  o[idx] = __float2bfloat16(v > 0.f ? v : 0.f);
}

// ---- BN2 stats/apply on H [b][256][2048] fp32 ----
__global__ __launch_bounds__(256) void k_bnstats(const float* __restrict__ h, int Cc,
                                                 const float* __restrict__ g, const float* __restrict__ be,
                                                 float* __restrict__ sa, float* __restrict__ sb) {
  int c = blockIdx.x;
  float s = 0.f, s2 = 0.f;
  for (int b = 0; b < BATCH; ++b) {
    const float* p = h + ((long)(b * Cc + c)) * NPT;
    for (int n = threadIdx.x; n < NPT; n += 256) {
      float v = p[n];
      s += v; s2 += v * v;
    }
  }
  s = blockReduceSum(s);
  s2 = blockReduceSum(s2);
  if (threadIdx.x == 0) {
    const float inv = 1.0f / (BATCH * NPT);
    float m = s * inv, var = s2 * inv - m * m;
    float A = rsqrtf(var + 1e-5f) * g[c];
    sa[c] = A; sb[c] = be[c] - m * A;
  }
}
__global__ void k_bnapply(float* __restrict__ h, const float* __restrict__ sa,
                          const float* __restrict__ sb, int Cc, int total) {
  int i = blockIdx.x * 256 + threadIdx.x;
  if (i >= total) return;
  int c = (i >> 11) & (Cc - 1);
  float v = fmaf(h[i], sa[c], sb[c]);
  h[i] = v > 0.f ? v : 0.f;
}

// ---- tiled transpose+convert: H [b][256][2048] f32 -> Ht [b][2048][256] bf16 ----
__global__ __launch_bounds__(256) void k_tcvt(const float* __restrict__ H, bf16* __restrict__ Ht) {
  __shared__ float t[64][65];
  const float* h = H + (long)blockIdx.z * STRD;
  bf16* o = Ht + (long)blockIdx.z * STRD;
  int n0 = blockIdx.x * 64, c0 = blockIdx.y * 64;
#pragma unroll
  for (int ii = 0; ii < 16; ++ii) {
    int idx = ii * 256 + threadIdx.x;
    int i = idx >> 6, j = idx & 63;
    t[i][j] = h[(long)(c0 + i) * NPT + n0 + j];
  }
  __syncthreads();
#pragma unroll
  for (int ii = 0; ii < 16; ++ii) {
    int idx = ii * 256 + threadIdx.x;
    int i = idx >> 6, j = idx & 63;
    o[(long)(n0 + i) * DEMB + c0 + j] = __float2bfloat16(t[j][i]);
  }
}

// ---- MFMA GEMM, B^T form: C[M][N] = A[M][K] . B[N][K]^T ; 128x128 tile, BK=64 ----
// XOR-swizzled LDS (granule ^= row&7) on both staging-source and read.
// MODE 0: C bf16 = acc, PLUS column-softmax partial stats from fp32 acc (PM/PS)
// MODE 1: C bf16 = acc
// MODE 2: C f32 = acc + bias[r]
template <int MODE>
__global__ __launch_bounds__(256) void k_mgemm(
    const bf16* __restrict__ A, long aStr, int ldA,
    const bf16* __restrict__ B, long bStr, int ldB,
    void* __restrict__ Cv, long cStr, int ldC,
    int K,
    const float* __restrict__ bias,
    float* __restrict__ PMo, float* __restrict__ PSo) {
  __shared__ __align__(16) bf16 sA[128 * 64];
  __shared__ __align__(16) bf16 sB[128 * 64];
  __shared__ float smx[4][64], ssx[4][64];
  const int z = blockIdx.z;
  A += aStr * z;
  B += bStr * z;
  const int bm = blockIdx.y * 128, bn = blockIdx.x * 128;
  const int tid = threadIdx.x;
  const int lane = tid & 63, wv = tid >> 6;
  const int wr = (wv >> 1) * 64, wc = (wv & 1) * 64;
  f32x4 acc[4][4] = {};

  for (int k0 = 0; k0 < K; k0 += 64) {
#pragma unroll
    for (int i = 0; i < 4; ++i) {
      int c = i * 256 + tid;
      int row = c >> 3, g = c & 7;
      int gs = (g ^ (row & 7)) * 8;
      gload16(A + (long)(bm + row) * ldA + k0 + gs, sA + c * 8);
      gload16(B + (long)(bn + row) * ldB + k0 + gs, sB + c * 8);
    }
    __syncthreads();
    bf16x8v af[4][2], bfr[4][2];
#pragma unroll
    for (int mi = 0; mi < 4; ++mi)
#pragma unroll
      for (int ks = 0; ks < 2; ++ks) {
        int rA = wr + mi * 16 + (lane & 15);
        int rB = wc + mi * 16 + (lane & 15);
        int g = ks * 4 + (lane >> 4);
        af[mi][ks]  = *(const bf16x8v*)&sA[rA * 64 + ((g ^ (rA & 7)) * 8)];
        bfr[mi][ks] = *(const bf16x8v*)&sB[rB * 64 + ((g ^ (rB & 7)) * 8)];
      }
#pragma unroll
    for (int ks = 0; ks < 2; ++ks)
#pragma unroll
      for (int mi = 0; mi < 4; ++mi)
#pragma unroll
        for (int ni = 0; ni < 4; ++ni)
          acc[mi][ni] = MFMA16(af[mi][ks], bfr[ni][ks], acc[mi][ni]);
    __syncthreads();
  }

  const int rb = (lane >> 4) * 4, cb = lane & 15;
  if constexpr (MODE == 0 || MODE == 1) {
    bf16* C = (bf16*)Cv + cStr * z;
#pragma unroll
    for (int mi = 0; mi < 4; ++mi)
#pragma unroll
      for (int ni = 0; ni < 4; ++ni) {
        int r0 = bm + wr + mi * 16 + rb, c0 = bn + wc + ni * 16 + cb;
#pragma unroll
        for (int k = 0; k < 4; ++k)
          C[(long)(r0 + k) * ldC + c0] = __float2bfloat16(acc[mi][ni][k]);
      }
  } else {
    float* C = (float*)Cv + cStr * z;
#pragma unroll
    for (int mi = 0; mi < 4; ++mi)
#pragma unroll
      for (int ni = 0; ni < 4; ++ni) {
        int r0 = bm + wr + mi * 16 + rb, c0 = bn + wc + ni * 16 + cb;
#pragma unroll
        for (int k = 0; k < 4; ++k) {
          int r = r0 + k;
          C[(long)r * ldC + c0] = acc[mi][ni][k] + bias[r];
        }
      }
  }

  if constexpr (MODE == 0) {
    // per-column (over this block's 128 rows) online-softmax partials (exact fp32)
    float cm[4], cs[4];
#pragma unroll
    for (int ni = 0; ni < 4; ++ni) {
      float m = -3.0e38f;
#pragma unroll
      for (int mi = 0; mi < 4; ++mi)
#pragma unroll
        for (int k = 0; k < 4; ++k) m = fmaxf(m, acc[mi][ni][k]);
      float s = 0.f;
#pragma unroll
      for (int mi = 0; mi < 4; ++mi)
#pragma unroll
        for (int k = 0; k < 4; ++k) s += __expf(acc[mi][ni][k] - m);
#pragma unroll
      for (int off = 16; off <= 32; off <<= 1) {
        float mo = __shfl_xor(m, off, 64);
        float so = __shfl_xor(s, off, 64);
        float M = fmaxf(m, mo);
        s = s * __expf(m - M) + so * __expf(mo - M);
        m = M;
      }
      cm[ni] = m; cs[ni] = s;
    }
    __syncthreads();  // LDS reads of K-loop complete; reuse smx/ssx safely
    if (lane < 16) {
#pragma unroll
      for (int ni = 0; ni < 4; ++ni) {
        smx[wv][ni * 16 + lane] = cm[ni];
        ssx[wv][ni * 16 + lane] = cs[ni];
      }
    }
    __syncthreads();
    if (tid < 128) {
      int half = tid >> 6, c64 = tid & 63;
      float m1 = smx[half][c64], s1 = ssx[half][c64];
      float m2 = smx[half + 2][c64], s2 = ssx[half + 2][c64];
      float M = fmaxf(m1, m2);
      float S = s1 * __expf(m1 - M) + s2 * __expf(m2 - M);
      long o = ((long)z * 16 + blockIdx.y) * NPT + bn + half * 64 + c64;
      PMo[o] = M;
      PSo[o] = S;
    }
  }
}

// ---- combine 16 partials per column -> CM, CSi ----
__global__ void k_cms_fin(const float* __restrict__ PM, const float* __restrict__ PS,
                          float* __restrict__ CM, float* __restrict__ CSi) {
  long idx = (long)blockIdx.x * 256 + threadIdx.x;  // [G*NPT]
  long z = idx >> 11;
  int n = idx & (NPT - 1);
  const float* pm = PM + z * 16 * NPT + n;
  const float* ps = PS + z * 16 * NPT + n;
  float m = -3.0e38f;
#pragma unroll
  for (int y = 0; y < 16; ++y) m = fmaxf(m, pm[(long)y * NPT]);
  float s = 0.f;
#pragma unroll
  for (int y = 0; y < 16; ++y) s += ps[(long)y * NPT] * __expf(pm[(long)y * NPT] - m);
  CM[idx] = m;
  CSi[idx] = 1.0f / s;
}

// ---- fused normalize + rowsum + V.P GEMM (F bf16, 2-phase double-buffered) ----
// Per block: e = 0..255 (M), m in [m0, m0+32) (N), K = n = 0..2047.
// 1-D grid 64*nz; z = bid % nz pins each batch's V to one XCD's L2.
__global__ __launch_bounds__(256) void k_vp(const bf16* __restrict__ F,
                                            const float* __restrict__ CM,
                                            const float* __restrict__ CSi,
                                            const bf16* __restrict__ V,
                                            float* __restrict__ H, int nz) {
  __shared__ __align__(16) bf16 sA[2][256 * 64];  // V tiles (double-buffered)
  __shared__ __align__(16) bf16 sB[2][32 * 64];   // PT tiles (double-buffered)
  __shared__ float rsLds[8][32];
  __shared__ float Sv[32];
  const int z = blockIdx.x % nz;
  const int m0 = (blockIdx.x / nz) * 32;
  const int tid = threadIdx.x;
  const int lane = tid & 63, wv = tid >> 6;
  const int mloc = tid & 31, seg = tid >> 5;
  const bf16* Vz = V + (long)z * STRD;
  const bf16* Fr = F + (long)z * NN + (long)(m0 + mloc) * NPT + seg * 8;
  const float* CMz = CM + (long)z * NPT + seg * 8;
  const float* CSz = CSi + (long)z * NPT + seg * 8;
  f32x4 acc[4][2] = {};
  float rs = 0.f;

  // EXPW(buf, n0, FREG): exp of F chunk -> sB[buf]; accumulate rs
#define EXPW(BUF, N0, FREG)                                                    \
  {                                                                            \
    float mv[8], cv[8];                                                        \
    *(float4*)&mv[0] = *(const float4*)(CMz + (N0));                           \
    *(float4*)&mv[4] = *(const float4*)(CMz + (N0) + 4);                       \
    *(float4*)&cv[0] = *(const float4*)(CSz + (N0));                           \
    *(float4*)&cv[4] = *(const float4*)(CSz + (N0) + 4);                       \
    bf16 tb[8];                                                                \
    _Pragma("unroll") for (int i = 0; i < 8; ++i) {                            \
      float fvi = __uint_as_float((unsigned)(unsigned short)FREG[i] << 16);    \
      float pv = __expf(fvi - mv[i]) * cv[i];                                  \
      rs += pv;                                                                \
      tb[i] = __float2bfloat16(pv);                                            \
    }                                                                          \
    *(bf16x8v*)&sB[BUF][mloc * 64 + ((seg ^ (mloc & 7)) * 8)] = *(bf16x8v*)tb; \
  }

  // STAGEV(buf, n0): issue 8 global_load_lds of V column-chunk into sA[buf]
#define STAGEV(BUF, N0)                                                        \
  _Pragma("unroll") for (int i = 0; i < 8; ++i) {                              \
    int c = i * 256 + tid;                                                     \
    int row = c >> 3, g = c & 7;                                               \
    gload16(Vz + (long)row * NPT + (N0) + ((g ^ (row & 7)) * 8),               \
            &sA[BUF][c * 8]);                                                  \
  }

  // prologue: step 0 staged into buf 0; F(1) prefetched
  bf16x8v fvA = *(const bf16x8v*)(Fr);        // F step 0
  EXPW(0, 0, fvA)
  STAGEV(0, 0)
  bf16x8v fvB = *(const bf16x8v*)(Fr + 64);   // F step 1
  __syncthreads();

  // body: one barrier per step; stage/exp for step+1 before MFMA on step
#define VP_BODY(CUR, FCUR, FNXT, STEPI)                                        \
  {                                                                            \
    const int sn = (STEPI);                                                    \
    const int nn0 = sn * 64;                                                   \
    if (sn + 1 < 32) {                                                         \
      STAGEV(CUR ^ 1, nn0 + 64)                                                \
      EXPW(CUR ^ 1, nn0 + 64, FCUR)                                            \
      if (sn + 2 < 32) FNXT = *(const bf16x8v*)(Fr + nn0 + 128);               \
    }                                                                          \
    bf16x8v bfr[2][2];                                                         \
    _Pragma("unroll") for (int ni = 0; ni < 2; ++ni)                           \
      _Pragma("unroll") for (int ks = 0; ks < 2; ++ks) {                       \
        int rB = ni * 16 + (lane & 15);                                        \
        int g = ks * 4 + (lane >> 4);                                          \
        bfr[ni][ks] = *(const bf16x8v*)&sB[CUR][rB * 64 + ((g ^ (rB & 7)) * 8)]; \
      }                                                                        \
    _Pragma("unroll") for (int mi = 0; mi < 4; ++mi)                           \
      _Pragma("unroll") for (int ks = 0; ks < 2; ++ks) {                       \
        int rA = (wv * 4 + mi) * 16 + (lane & 15);                             \
        int g = ks * 4 + (lane >> 4);                                          \
        bf16x8v af = *(const bf16x8v*)&sA[CUR][rA * 64 + ((g ^ (rA & 7)) * 8)]; \
        _Pragma("unroll") for (int ni = 0; ni < 2; ++ni)                       \
          acc[mi][ni] = MFMA16(af, bfr[ni][ks], acc[mi][ni]);                  \
      }                                                                        \
    __syncthreads();                                                           \
  }

  for (int it = 0; it < 16; ++it) {
    VP_BODY(0, fvB, fvA, 2 * it)
    VP_BODY(1, fvA, fvB, 2 * it + 1)
  }
#undef VP_BODY
#undef STAGEV
#undef EXPW

  rsLds[seg][mloc] = rs;
  __syncthreads();
  if (tid < 32) {
    float R = 0.f;
#pragma unroll
    for (int s = 0; s < 8; ++s) R += rsLds[s][tid];
    Sv[tid] = 1.0f / (1e-9f + R);
  }
  __syncthreads();

  float* Hz = H + (long)z * STRD;
  const int rb = (lane >> 4) * 4, cb = lane & 15;
#pragma unroll
  for (int mi = 0; mi < 4; ++mi) {
    int e0 = (wv * 4 + mi) * 16 + rb;
#pragma unroll
    for (int ni = 0; ni < 2; ++ni) {
      int c = ni * 16 + cb;
      float scl = Sv[c];
#pragma unroll
      for (int k = 0; k < 4; ++k)
        Hz[(long)(e0 + k) * NPT + m0 + c] += acc[mi][ni][k] * scl;
    }
  }
}

// ---- pooled[b,n] = mean over e of H[b,e,n] ----
__global__ void k_pool(const float* __restrict__ H, float* __restrict__ pooled) {
  int i = blockIdx.x * 256 + threadIdx.x;
  if (i >= BATCH * NPT) return;
  int b = i >> 11, n = i & (NPT - 1);
  const float* p = H + (long)b * STRD + n;
  float s = 0.f;
  for (int e = 0; e < DEMB; ++e) s += p[(long)e * NPT];
  pooled[i] = s * (1.0f / DEMB);
}

// ---- fc1 ----
__global__ __launch_bounds__(256) void k_fc1(const float* __restrict__ pooled,
                                             const float* __restrict__ w, const float* __restrict__ bias,
                                             float* __restrict__ f) {
  int j = blockIdx.x, b = blockIdx.y;
  const float* pp = pooled + (long)b * NPT;
  const float* wr = w + (long)j * NPT;
  float s = 0.f;
  for (int n = threadIdx.x; n < NPT; n += 256) s += pp[n] * wr[n];
  s = blockReduceSum(s);
  if (threadIdx.x == 0) {
    s += bias[j];
    f[(long)b * NPT + j] = s > 0.f ? s : 0.f;
  }
}

// ---- fc2 ----
__global__ __launch_bounds__(256) void k_fc2(const float* __restrict__ f,
                                             const float* __restrict__ w, const float* __restrict__ bias,
                                             float* __restrict__ out) {
  int b = blockIdx.x;
  float s = 0.f;
  for (int j = threadIdx.x; j < NPT; j += 256) s += f[(long)b * NPT + j] * w[j];
  s = blockReduceSum(s);
  if (threadIdx.x == 0) out[b] = s + bias[0];
}

extern "C" void kernel_launch(void* const* d_in, const int* in_sizes, int n_in,
                              void* d_out, int out_size, void* d_ws, size_t ws_size,
                              hipStream_t stream) {
  const float* X    = (const float*)d_in[0];
  const float* W1   = (const float*)d_in[1];
  const float* B1   = (const float*)d_in[2];
  const float* G1   = (const float*)d_in[3];
  const float* BE1  = (const float*)d_in[4];
  const float* W2   = (const float*)d_in[5];
  const float* B2   = (const float*)d_in[6];
  const float* G2   = (const float*)d_in[7];
  const float* BE2  = (const float*)d_in[8];
  const float* WQ   = (const float*)d_in[9];
  const float* WK   = (const float*)d_in[10];
  const float* WV   = (const float*)d_in[11];
  const float* FC1W = (const float*)d_in[12];
  const float* FC1B = (const float*)d_in[13];
  const float* FC2W = (const float*)d_in[14];
  const float* FC2B = (const float*)d_in[15];
  float* OUT = (float*)d_out;

  // ---- workspace carve-out ----
  char* p = (char*)d_ws;
  auto alloc = [&](size_t bytes) -> char* {
    char* r = p;
    p += (bytes + 255) & ~(size_t)255;
    return r;
  };
  float* H1t  = (float*)alloc((size_t)BATCH * NPT * DMID * 4);
  bf16*  H1tb = (bf16*)alloc((size_t)BATCH * NPT * DMID * 2);
  float* H    = (float*)alloc((size_t)BATCH * STRD * 4);
  bf16*  Ht   = (bf16*)alloc((size_t)BATCH * STRD * 2);
  bf16*  QKt  = (bf16*)alloc((size_t)BATCH * QKS * 2);   // [b][n][512] = Q(0..255) | K(256..511)
  bf16*  Vb   = (bf16*)alloc((size_t)BATCH * STRD * 2);
  bf16*  W2b  = (bf16*)alloc((size_t)DEMB * DMID * 2);
  bf16*  WQKb = (bf16*)alloc((size_t)NSA * 512 * DEMB * 2);
  bf16*  WVb  = (bf16*)alloc((size_t)NSA * DEMB * DEMB * 2);
  float* pS   = (float*)alloc(128 * 64 * 4);
  float* pS2  = (float*)alloc(128 * 64 * 4);
  float* sa1  = (float*)alloc(64 * 4);
  float* sb1  = (float*)alloc(64 * 4);
  float* sa2  = (float*)alloc(256 * 4);
  float* sb2  = (float*)alloc(256 * 4);
  float* CM   = (float*)alloc((size_t)BATCH * NPT * 4);
  float* CSi  = (float*)alloc((size_t)BATCH * NPT * 4);
  float* PM   = (float*)alloc((size_t)BATCH * 16 * NPT * 4);
  float* PSm  = (float*)alloc((size_t)BATCH * 16 * NPT * 4);
  float* POOL = (float*)alloc((size_t)BATCH * NPT * 4);
  float* FH   = (float*)alloc((size_t)BATCH * NPT * 4);
  size_t used = (size_t)(p - (char*)d_ws);
  const size_t per_g = (size_t)NN * 2;  // F bf16 (8MB per batch)
  int G = 8;
  while (G > 1 && used + (size_t)G * per_g + 1024 > ws_size) G >>= 1;
  bf16* F = (bf16*)alloc((size_t)G * NN * 2);

  // ---- weight converts ----
  k_cvt<<<(DEMB * DMID + 255) / 256, 256, 0, stream>>>(W2, W2b, DEMB * DMID);
  int nqk = NSA * 512 * DEMB;
  k_cvtqk<<<nqk / 256, 256, 0, stream>>>(WQ, WK, WQKb);
  int nw = NSA * DEMB * DEMB;
  k_cvt<<<(nw + 255) / 256, 256, 0, stream>>>(WV, WVb, nw);

  // ---- conv1 + BN1 + ReLU (-> H1tb bf16 [b][n][64]) ----
  long szh1 = (long)BATCH * NPT * DMID;
  k_conv1t<<<(int)(szh1 / 256), 256, 0, stream>>>(X, W1, B1, H1t);
  k_bn1a<<<128, 256, 0, stream>>>(H1t, pS, pS2);
  k_bn1b<<<1, 64, 0, stream>>>(pS, pS2, G1, BE1, sa1, sb1);
  k_bn1apply<<<(int)(szh1 / 256), 256, 0, stream>>>(H1t, sa1, sb1, H1tb);

  // ---- conv2 (MFMA) + BN2 + ReLU -> H fp32 [b][256][2048] ----
  k_mgemm<2><<<dim3(16, 2, 8), 256, 0, stream>>>(W2b, 0, DMID, H1tb, (long)NPT * DMID, DMID,
                                                 H, STRD, NPT, DMID, B2, nullptr, nullptr);
  k_bnstats<<<DEMB, 256, 0, stream>>>(H, DEMB, G2, BE2, sa2, sb2);
  k_bnapply<<<(int)(BATCH * STRD / 256), 256, 0, stream>>>(H, sa2, sb2, DEMB, (int)(BATCH * STRD));

  // ---- SA layers ----
  for (int l = 0; l < NSA; ++l) {
    k_tcvt<<<dim3(32, 4, 8), 256, 0, stream>>>(H, Ht);
    // QKt[n][0..511] = Ht . [Wq;Wk]^T  : A=Ht (M=2048), B=WQK (N=512)
    k_mgemm<1><<<dim3(4, 16, 8), 256, 0, stream>>>(Ht, STRD, DEMB, WQKb + (long)l * 512 * DEMB, 0, DEMB,
                                                   QKt, QKS, 512, DEMB, nullptr, nullptr, nullptr);
    // V[e][n] : A=Wv (M=256), B=Ht (N=2048)
    k_mgemm<1><<<dim3(16, 2, 8), 256, 0, stream>>>(WVb + (long)l * DEMB * DEMB, 0, DEMB, Ht, STRD, DEMB,
                                                   Vb, STRD, NPT, DEMB, nullptr, nullptr, nullptr);
    for (int b0 = 0; b0 < BATCH; b0 += G) {
      // F[m][n] = sum_a Kt[m][a] Qt[n][a] (= E^T), bf16 + fused exact column stats
      k_mgemm<0><<<dim3(16, 16, G), 256, 0, stream>>>(QKt + 256 + b0 * QKS, QKS, 512,
                                                      QKt + b0 * QKS, QKS, 512,
                                                      F, NN, NPT, DEMB, nullptr, PM, PSm);
      k_cms_fin<<<G * NPT / 256, 256, 0, stream>>>(PM, PSm, CM, CSi);
      // H[e][m] += S[m] * sum_n V[e][n] PT[m][n]  (PT from bf16 F on the fly)
      k_vp<<<dim3(64 * G), 256, 0, stream>>>(F, CM, CSi, Vb + b0 * STRD, H + b0 * STRD, G);
    }
  }

  // ---- head ----
  k_pool<<<(BATCH * NPT) / 256, 256, 0, stream>>>(H, POOL);
  k_fc1<<<dim3(NPT, BATCH), 256, 0, stream>>>(POOL, FC1W, FC1B, FH);
  k_fc2<<<BATCH, 256, 0, stream>>>(FH, FC2W, FC2B, OUT);
}

// Round 9
// 514.964 us; speedup vs baseline: 11.4255x; 1.0396x over previous
//
#include <hip/hip_runtime.h>
#include <hip/hip_bf16.h>

typedef __hip_bfloat16 bf16;
#define DEVI __device__ __forceinline__

// Problem constants
static constexpr int BATCH = 8;
static constexpr int NPT   = 2048;
static constexpr int DMID  = 64;
static constexpr int DEMB  = 256;
static constexpr int NSA   = 4;
static constexpr long STRD = (long)DEMB * NPT;  // 524288
static constexpr long QKS  = (long)NPT * 512;   // per-batch stride of QKt
static constexpr long NN   = (long)NPT * NPT;   // 4194304

typedef __attribute__((ext_vector_type(4))) float f32x4;
typedef __attribute__((ext_vector_type(8))) short bf16x8v;

DEVI f32x4 MFMA16(bf16x8v a, bf16x8v b, f32x4 c) {
  return __builtin_amdgcn_mfma_f32_16x16x32_bf16(a, b, c, 0, 0, 0);
}

DEVI void gload16(const bf16* g, bf16* l) {
  __builtin_amdgcn_global_load_lds(
      (const __attribute__((address_space(1))) void*)g,
      (__attribute__((address_space(3))) void*)l, 16, 0, 0);
}

DEVI float waveReduceSum(float v) {
#pragma unroll
  for (int o = 32; o > 0; o >>= 1) v += __shfl_down(v, o, 64);
  return v;
}
DEVI float blockReduceSum(float v) {
  __shared__ float sm[4];
  int lane = threadIdx.x & 63, wid = threadIdx.x >> 6;
  __syncthreads();
  v = waveReduceSum(v);
  if (lane == 0) sm[wid] = v;
  __syncthreads();
  return sm[0] + sm[1] + sm[2] + sm[3];
}

// ---- fp32 -> bf16 convert ----
__global__ void k_cvt(const float* __restrict__ in, bf16* __restrict__ out, int n) {
  int i = blockIdx.x * 256 + threadIdx.x;
  if (i < n) out[i] = __float2bfloat16(in[i]);
}

// ---- concat-convert Wq,Wk -> WQKb [l][512][256] bf16 ----
__global__ void k_cvtqk(const float* __restrict__ wq, const float* __restrict__ wk,
                        bf16* __restrict__ o) {
  int idx = blockIdx.x * 256 + threadIdx.x;  // NSA*512*256
  int c = idx & 255;
  int r = (idx >> 8) & 511;
  int l = idx >> 17;
  float v = (r < 256) ? wq[((l << 8) + r) * 256 + c] : wk[((l << 8) + (r - 256)) * 256 + c];
  o[idx] = __float2bfloat16(v);
}

// ---- conv1: H1t[b][n][o] = sum_c x[b,n,c]*w1[o,c] + b1[o] ----
__global__ void k_conv1t(const float* __restrict__ x, const float* __restrict__ w1,
                         const float* __restrict__ b1, float* __restrict__ h1t) {
  long idx = (long)blockIdx.x * 256 + threadIdx.x;  // [b*n][o]
  int o = idx & 63;
  long bn = idx >> 6;
  const float* xp = x + bn * 3;
  h1t[idx] = b1[o] + xp[0] * w1[o * 3] + xp[1] * w1[o * 3 + 1] + xp[2] * w1[o * 3 + 2];
}

// ---- BN1 stats on H1t [16384][64] ----
__global__ __launch_bounds__(256) void k_bn1a(const float* __restrict__ h, float* __restrict__ pS,
                                              float* __restrict__ pS2) {
  int c = threadIdx.x & 63, rg = threadIdx.x >> 6;
  long r0 = (long)blockIdx.x * 128 + rg * 32;
  float s = 0.f, s2 = 0.f;
  for (int i = 0; i < 32; ++i) {
    float v = h[(r0 + i) * 64 + c];
    s += v; s2 += v * v;
  }
  __shared__ float smS[256], smS2[256];
  smS[threadIdx.x] = s; smS2[threadIdx.x] = s2;
  __syncthreads();
  if (threadIdx.x < 64) {
    float a = 0.f, b = 0.f;
#pragma unroll
    for (int g = 0; g < 4; ++g) { a += smS[g * 64 + c]; b += smS2[g * 64 + c]; }
    pS[blockIdx.x * 64 + c] = a;
    pS2[blockIdx.x * 64 + c] = b;
  }
}
__global__ void k_bn1b(const float* __restrict__ pS, const float* __restrict__ pS2,
                       const float* __restrict__ g, const float* __restrict__ be,
                       float* __restrict__ sa, float* __restrict__ sb) {
  int c = threadIdx.x;
  if (c >= 64) return;
  float s = 0.f, s2 = 0.f;
  for (int i = 0; i < 128; ++i) { s += pS[i * 64 + c]; s2 += pS2[i * 64 + c]; }
  const float inv = 1.0f / (BATCH * NPT);
  float m = s * inv, var = s2 * inv - m * m;
  float A = rsqrtf(var + 1e-5f) * g[c];
  sa[c] = A; sb[c] = be[c] - m * A;
}
__global__ void k_bn1apply(const float* __restrict__ h, const float* __restrict__ sa,
                           const float* __restrict__ sb, bf16* __restrict__ o) {
  long idx = (long)blockIdx.x * 256 + threadIdx.x;
  int c = idx & 63;
  float v = fmaf(h[idx], sa[c], sb[c]);
  o[idx] = __float2bfloat16(v > 0.f ? v : 0.f);
}

// ---- BN2 stats/apply on H [b][256][2048] fp32 ----
__global__ __launch_bounds__(256) void k_bnstats(const float* __restrict__ h, int Cc,
                                                 const float* __restrict__ g, const float* __restrict__ be,
                                                 float* __restrict__ sa, float* __restrict__ sb) {
  int c = blockIdx.x;
  float s = 0.f, s2 = 0.f;
  for (int b = 0; b < BATCH; ++b) {
    const float* p = h + ((long)(b * Cc + c)) * NPT;
    for (int n = threadIdx.x; n < NPT; n += 256) {
      float v = p[n];
      s += v; s2 += v * v;
    }
  }
  s = blockReduceSum(s);
  s2 = blockReduceSum(s2);
  if (threadIdx.x == 0) {
    const float inv = 1.0f / (BATCH * NPT);
    float m = s * inv, var = s2 * inv - m * m;
    float A = rsqrtf(var + 1e-5f) * g[c];
    sa[c] = A; sb[c] = be[c] - m * A;
  }
}
__global__ void k_bnapply(float* __restrict__ h, const float* __restrict__ sa,
                          const float* __restrict__ sb, int Cc, int total) {
  int i = blockIdx.x * 256 + threadIdx.x;
  if (i >= total) return;
  int c = (i >> 11) & (Cc - 1);
  float v = fmaf(h[i], sa[c], sb[c]);
  h[i] = v > 0.f ? v : 0.f;
}

// ---- tiled transpose+convert: H [b][256][2048] f32 -> Ht [b][2048][256] bf16 ----
__global__ __launch_bounds__(256) void k_tcvt(const float* __restrict__ H, bf16* __restrict__ Ht) {
  __shared__ float t[64][65];
  const float* h = H + (long)blockIdx.z * STRD;
  bf16* o = Ht + (long)blockIdx.z * STRD;
  int n0 = blockIdx.x * 64, c0 = blockIdx.y * 64;
#pragma unroll
  for (int ii = 0; ii < 16; ++ii) {
    int idx = ii * 256 + threadIdx.x;
    int i = idx >> 6, j = idx & 63;
    t[i][j] = h[(long)(c0 + i) * NPT + n0 + j];
  }
  __syncthreads();
#pragma unroll
  for (int ii = 0; ii < 16; ++ii) {
    int idx = ii * 256 + threadIdx.x;
    int i = idx >> 6, j = idx & 63;
    o[(long)(n0 + i) * DEMB + c0 + j] = __float2bfloat16(t[j][i]);
  }
}

// ---- MFMA GEMM, B^T form: C[M][N] = A[M][K] . B[N][K]^T ; 128x128 tile, BK=64 ----
// XOR-swizzled LDS (granule ^= row&7) on both staging-source and read.
// MODE 0: C bf16 = acc, PLUS column-softmax partial stats from fp32 acc (PM/PS)
// MODE 1: C bf16 = acc
// MODE 2: C f32 = acc + bias[r]
template <int MODE>
__global__ __launch_bounds__(256) void k_mgemm(
    const bf16* __restrict__ A, long aStr, int ldA,
    const bf16* __restrict__ B, long bStr, int ldB,
    void* __restrict__ Cv, long cStr, int ldC,
    int K,
    const float* __restrict__ bias,
    float* __restrict__ PMo, float* __restrict__ PSo) {
  __shared__ __align__(16) bf16 sA[128 * 64];
  __shared__ __align__(16) bf16 sB[128 * 64];
  __shared__ float smx[4][64], ssx[4][64];
  const int z = blockIdx.z;
  A += aStr * z;
  B += bStr * z;
  const int bm = blockIdx.y * 128, bn = blockIdx.x * 128;
  const int tid = threadIdx.x;
  const int lane = tid & 63, wv = tid >> 6;
  const int wr = (wv >> 1) * 64, wc = (wv & 1) * 64;
  f32x4 acc[4][4] = {};

  for (int k0 = 0; k0 < K; k0 += 64) {
#pragma unroll
    for (int i = 0; i < 4; ++i) {
      int c = i * 256 + tid;
      int row = c >> 3, g = c & 7;
      int gs = (g ^ (row & 7)) * 8;
      gload16(A + (long)(bm + row) * ldA + k0 + gs, sA + c * 8);
      gload16(B + (long)(bn + row) * ldB + k0 + gs, sB + c * 8);
    }
    __syncthreads();
    bf16x8v af[4][2], bfr[4][2];
#pragma unroll
    for (int mi = 0; mi < 4; ++mi)
#pragma unroll
      for (int ks = 0; ks < 2; ++ks) {
        int rA = wr + mi * 16 + (lane & 15);
        int rB = wc + mi * 16 + (lane & 15);
        int g = ks * 4 + (lane >> 4);
        af[mi][ks]  = *(const bf16x8v*)&sA[rA * 64 + ((g ^ (rA & 7)) * 8)];
        bfr[mi][ks] = *(const bf16x8v*)&sB[rB * 64 + ((g ^ (rB & 7)) * 8)];
      }
#pragma unroll
    for (int ks = 0; ks < 2; ++ks)
#pragma unroll
      for (int mi = 0; mi < 4; ++mi)
#pragma unroll
        for (int ni = 0; ni < 4; ++ni)
          acc[mi][ni] = MFMA16(af[mi][ks], bfr[ni][ks], acc[mi][ni]);
    __syncthreads();
  }

  const int rb = (lane >> 4) * 4, cb = lane & 15;
  if constexpr (MODE == 0 || MODE == 1) {
    bf16* C = (bf16*)Cv + cStr * z;
#pragma unroll
    for (int mi = 0; mi < 4; ++mi)
#pragma unroll
      for (int ni = 0; ni < 4; ++ni) {
        int r0 = bm + wr + mi * 16 + rb, c0 = bn + wc + ni * 16 + cb;
#pragma unroll
        for (int k = 0; k < 4; ++k)
          C[(long)(r0 + k) * ldC + c0] = __float2bfloat16(acc[mi][ni][k]);
      }
  } else {
    float* C = (float*)Cv + cStr * z;
#pragma unroll
    for (int mi = 0; mi < 4; ++mi)
#pragma unroll
      for (int ni = 0; ni < 4; ++ni) {
        int r0 = bm + wr + mi * 16 + rb, c0 = bn + wc + ni * 16 + cb;
#pragma unroll
        for (int k = 0; k < 4; ++k) {
          int r = r0 + k;
          C[(long)r * ldC + c0] = acc[mi][ni][k] + bias[r];
        }
      }
  }

  if constexpr (MODE == 0) {
    // per-column (over this block's 128 rows) online-softmax partials (exact fp32)
    float cm[4], cs[4];
#pragma unroll
    for (int ni = 0; ni < 4; ++ni) {
      float m = -3.0e38f;
#pragma unroll
      for (int mi = 0; mi < 4; ++mi)
#pragma unroll
        for (int k = 0; k < 4; ++k) m = fmaxf(m, acc[mi][ni][k]);
      float s = 0.f;
#pragma unroll
      for (int mi = 0; mi < 4; ++mi)
#pragma unroll
        for (int k = 0; k < 4; ++k) s += __expf(acc[mi][ni][k] - m);
#pragma unroll
      for (int off = 16; off <= 32; off <<= 1) {
        float mo = __shfl_xor(m, off, 64);
        float so = __shfl_xor(s, off, 64);
        float M = fmaxf(m, mo);
        s = s * __expf(m - M) + so * __expf(mo - M);
        m = M;
      }
      cm[ni] = m; cs[ni] = s;
    }
    __syncthreads();  // LDS reads of K-loop complete; reuse smx/ssx safely
    if (lane < 16) {
#pragma unroll
      for (int ni = 0; ni < 4; ++ni) {
        smx[wv][ni * 16 + lane] = cm[ni];
        ssx[wv][ni * 16 + lane] = cs[ni];
      }
    }
    __syncthreads();
    if (tid < 128) {
      int half = tid >> 6, c64 = tid & 63;
      float m1 = smx[half][c64], s1 = ssx[half][c64];
      float m2 = smx[half + 2][c64], s2 = ssx[half + 2][c64];
      float M = fmaxf(m1, m2);
      float S = s1 * __expf(m1 - M) + s2 * __expf(m2 - M);
      long o = ((long)z * 16 + blockIdx.y) * NPT + bn + half * 64 + c64;
      PMo[o] = M;
      PSo[o] = S;
    }
  }
}

// ---- combine 16 partials per column -> CM, CSi ----
__global__ void k_cms_fin(const float* __restrict__ PM, const float* __restrict__ PS,
                          float* __restrict__ CM, float* __restrict__ CSi) {
  long idx = (long)blockIdx.x * 256 + threadIdx.x;  // [G*NPT]
  long z = idx >> 11;
  int n = idx & (NPT - 1);
  const float* pm = PM + z * 16 * NPT + n;
  const float* ps = PS + z * 16 * NPT + n;
  float m = -3.0e38f;
#pragma unroll
  for (int y = 0; y < 16; ++y) m = fmaxf(m, pm[(long)y * NPT]);
  float s = 0.f;
#pragma unroll
  for (int y = 0; y < 16; ++y) s += ps[(long)y * NPT] * __expf(pm[(long)y * NPT] - m);
  CM[idx] = m;
  CSi[idx] = 1.0f / s;
}

// ---- fused normalize + rowsum + V.P GEMM (F bf16, 2-phase dbuf, coalesced F) ----
// Per block: e = 0..255 (M), m in [m0, m0+32) (N), K = n = 0..2047.
// 1-D grid 64*nz; z = bid % nz pins each batch's V to one XCD's L2.
// F read layout: row fr = tid>>3, chunk fq = tid&7 (8 lanes -> 128B contiguous).
// F and CM/CSi both register-prefetched one step ahead.
__global__ __launch_bounds__(256) void k_vp(const bf16* __restrict__ F,
                                            const float* __restrict__ CM,
                                            const float* __restrict__ CSi,
                                            const bf16* __restrict__ V,
                                            float* __restrict__ H, int nz) {
  __shared__ __align__(16) bf16 sA[2][256 * 64];  // V tiles (double-buffered)
  __shared__ __align__(16) bf16 sB[2][32 * 64];   // PT tiles (double-buffered)
  __shared__ float rsLds[32][8];
  __shared__ float Sv[32];
  const int z = blockIdx.x % nz;
  const int m0 = (blockIdx.x / nz) * 32;
  const int tid = threadIdx.x;
  const int lane = tid & 63, wv = tid >> 6;
  const int fr = tid >> 3;   // F row 0..31
  const int fq = tid & 7;    // F col chunk 0..7
  const bf16* Vz = V + (long)z * STRD;
  const bf16* Frp = F + (long)z * NN + (long)(m0 + fr) * NPT + fq * 8;
  const float* CMz = CM + (long)z * NPT + fq * 8;
  const float* CSz = CSi + (long)z * NPT + fq * 8;
  f32x4 acc[4][2] = {};
  float rs = 0.f;
  bf16x8v fvA, fvB;
  float mvA[8], cvA[8], mvB[8], cvB[8];

  // LOADF: prefetch F chunk + its CM/CSi into registers
#define LOADF(FREG, MV, CV, N0)                                                \
  {                                                                            \
    FREG = *(const bf16x8v*)(Frp + (N0));                                      \
    *(float4*)&MV[0] = *(const float4*)(CMz + (N0));                           \
    *(float4*)&MV[4] = *(const float4*)(CMz + (N0) + 4);                       \
    *(float4*)&CV[0] = *(const float4*)(CSz + (N0));                           \
    *(float4*)&CV[4] = *(const float4*)(CSz + (N0) + 4);                       \
  }

  // EXPW: exp of register F chunk -> sB[buf]; accumulate rs
#define EXPW(BUF, FREG, MV, CV)                                                \
  {                                                                            \
    bf16 tb[8];                                                                \
    _Pragma("unroll") for (int i = 0; i < 8; ++i) {                            \
      float fvi = __uint_as_float((unsigned)(unsigned short)FREG[i] << 16);    \
      float pv = __expf(fvi - MV[i]) * CV[i];                                  \
      rs += pv;                                                                \
      tb[i] = __float2bfloat16(pv);                                            \
    }                                                                          \
    *(bf16x8v*)&sB[BUF][fr * 64 + ((fq ^ (fr & 7)) * 8)] = *(bf16x8v*)tb;      \
  }

  // STAGEV: issue 8 global_load_lds of V column-chunk into sA[buf]
#define STAGEV(BUF, N0)                                                        \
  _Pragma("unroll") for (int i = 0; i < 8; ++i) {                              \
    int c = i * 256 + tid;                                                     \
    int row = c >> 3, g = c & 7;                                               \
    gload16(Vz + (long)row * NPT + (N0) + ((g ^ (row & 7)) * 8),               \
            &sA[BUF][c * 8]);                                                  \
  }

  // prologue: step 0 staged into buf 0; step-1 operands prefetched
  LOADF(fvA, mvA, cvA, 0)
  EXPW(0, fvA, mvA, cvA)
  STAGEV(0, 0)
  LOADF(fvB, mvB, cvB, 64)
  __syncthreads();

  // body: one barrier per step; stage/exp for step+1 before MFMA on step
#define VP_BODY(CUR, FN, MVN, CVN, FN2, MVN2, CVN2, STEPI)                     \
  {                                                                            \
    const int sn = (STEPI);                                                    \
    const int nn0 = sn * 64;                                                   \
    if (sn + 1 < 32) {                                                         \
      STAGEV(CUR ^ 1, nn0 + 64)                                                \
      EXPW(CUR ^ 1, FN, MVN, CVN)                                              \
      if (sn + 2 < 32) LOADF(FN2, MVN2, CVN2, nn0 + 128)                       \
    }                                                                          \
    bf16x8v bfr[2][2];                                                         \
    _Pragma("unroll") for (int ni = 0; ni < 2; ++ni)                           \
      _Pragma("unroll") for (int ks = 0; ks < 2; ++ks) {                       \
        int rB = ni * 16 + (lane & 15);                                        \
        int g = ks * 4 + (lane >> 4);                                          \
        bfr[ni][ks] = *(const bf16x8v*)&sB[CUR][rB * 64 + ((g ^ (rB & 7)) * 8)]; \
      }                                                                        \
    _Pragma("unroll") for (int mi = 0; mi < 4; ++mi)                           \
      _Pragma("unroll") for (int ks = 0; ks < 2; ++ks) {                       \
        int rA = (wv * 4 + mi) * 16 + (lane & 15);                             \
        int g = ks * 4 + (lane >> 4);                                          \
        bf16x8v af = *(const bf16x8v*)&sA[CUR][rA * 64 + ((g ^ (rA & 7)) * 8)]; \
        _Pragma("unroll") for (int ni = 0; ni < 2; ++ni)                       \
          acc[mi][ni] = MFMA16(af, bfr[ni][ks], acc[mi][ni]);                  \
      }                                                                        \
    __syncthreads();                                                           \
  }

  for (int it = 0; it < 16; ++it) {
    VP_BODY(0, fvB, mvB, cvB, fvA, mvA, cvA, 2 * it)
    VP_BODY(1, fvA, mvA, cvA, fvB, mvB, cvB, 2 * it + 1)
  }
#undef VP_BODY
#undef STAGEV
#undef EXPW
#undef LOADF

  rsLds[fr][fq] = rs;
  __syncthreads();
  if (tid < 32) {
    float R = 0.f;
#pragma unroll
    for (int q = 0; q < 8; ++q) R += rsLds[tid][q];
    Sv[tid] = 1.0f / (1e-9f + R);
  }
  __syncthreads();

  float* Hz = H + (long)z * STRD;
  const int rb = (lane >> 4) * 4, cb = lane & 15;
#pragma unroll
  for (int mi = 0; mi < 4; ++mi) {
    int e0 = (wv * 4 + mi) * 16 + rb;
#pragma unroll
    for (int ni = 0; ni < 2; ++ni) {
      int c = ni * 16 + cb;
      float scl = Sv[c];
#pragma unroll
      for (int k = 0; k < 4; ++k)
        Hz[(long)(e0 + k) * NPT + m0 + c] += acc[mi][ni][k] * scl;
    }
  }
}

// ---- pooled[b,n] = mean over e of H[b,e,n] ----
__global__ void k_pool(const float* __restrict__ H, float* __restrict__ pooled) {
  int i = blockIdx.x * 256 + threadIdx.x;
  if (i >= BATCH * NPT) return;
  int b = i >> 11, n = i & (NPT - 1);
  const float* p = H + (long)b * STRD + n;
  float s = 0.f;
  for (int e = 0; e < DEMB; ++e) s += p[(long)e * NPT];
  pooled[i] = s * (1.0f / DEMB);
}

// ---- fc1 ----
__global__ __launch_bounds__(256) void k_fc1(const float* __restrict__ pooled,
                                             const float* __restrict__ w, const float* __restrict__ bias,
                                             float* __restrict__ f) {
  int j = blockIdx.x, b = blockIdx.y;
  const float* pp = pooled + (long)b * NPT;
  const float* wr = w + (long)j * NPT;
  float s = 0.f;
  for (int n = threadIdx.x; n < NPT; n += 256) s += pp[n] * wr[n];
  s = blockReduceSum(s);
  if (threadIdx.x == 0) {
    s += bias[j];
    f[(long)b * NPT + j] = s > 0.f ? s : 0.f;
  }
}

// ---- fc2 ----
__global__ __launch_bounds__(256) void k_fc2(const float* __restrict__ f,
                                             const float* __restrict__ w, const float* __restrict__ bias,
                                             float* __restrict__ out) {
  int b = blockIdx.x;
  float s = 0.f;
  for (int j = threadIdx.x; j < NPT; j += 256) s += f[(long)b * NPT + j] * w[j];
  s = blockReduceSum(s);
  if (threadIdx.x == 0) out[b] = s + bias[0];
}

extern "C" void kernel_launch(void* const* d_in, const int* in_sizes, int n_in,
                              void* d_out, int out_size, void* d_ws, size_t ws_size,
                              hipStream_t stream) {
  const float* X    = (const float*)d_in[0];
  const float* W1   = (const float*)d_in[1];
  const float* B1   = (const float*)d_in[2];
  const float* G1   = (const float*)d_in[3];
  const float* BE1  = (const float*)d_in[4];
  const float* W2   = (const float*)d_in[5];
  const float* B2   = (const float*)d_in[6];
  const float* G2   = (const float*)d_in[7];
  const float* BE2  = (const float*)d_in[8];
  const float* WQ   = (const float*)d_in[9];
  const float* WK   = (const float*)d_in[10];
  const float* WV   = (const float*)d_in[11];
  const float* FC1W = (const float*)d_in[12];
  const float* FC1B = (const float*)d_in[13];
  const float* FC2W = (const float*)d_in[14];
  const float* FC2B = (const float*)d_in[15];
  float* OUT = (float*)d_out;

  // ---- workspace carve-out ----
  char* p = (char*)d_ws;
  auto alloc = [&](size_t bytes) -> char* {
    char* r = p;
    p += (bytes + 255) & ~(size_t)255;
    return r;
  };
  float* H1t  = (float*)alloc((size_t)BATCH * NPT * DMID * 4);
  bf16*  H1tb = (bf16*)alloc((size_t)BATCH * NPT * DMID * 2);
  float* H    = (float*)alloc((size_t)BATCH * STRD * 4);
  bf16*  Ht   = (bf16*)alloc((size_t)BATCH * STRD * 2);
  bf16*  QKt  = (bf16*)alloc((size_t)BATCH * QKS * 2);   // [b][n][512] = Q(0..255) | K(256..511)
  bf16*  Vb   = (bf16*)alloc((size_t)BATCH * STRD * 2);
  bf16*  W2b  = (bf16*)alloc((size_t)DEMB * DMID * 2);
  bf16*  WQKb = (bf16*)alloc((size_t)NSA * 512 * DEMB * 2);
  bf16*  WVb  = (bf16*)alloc((size_t)NSA * DEMB * DEMB * 2);
  float* pS   = (float*)alloc(128 * 64 * 4);
  float* pS2  = (float*)alloc(128 * 64 * 4);
  float* sa1  = (float*)alloc(64 * 4);
  float* sb1  = (float*)alloc(64 * 4);
  float* sa2  = (float*)alloc(256 * 4);
  float* sb2  = (float*)alloc(256 * 4);
  float* CM   = (float*)alloc((size_t)BATCH * NPT * 4);
  float* CSi  = (float*)alloc((size_t)BATCH * NPT * 4);
  float* PM   = (float*)alloc((size_t)BATCH * 16 * NPT * 4);
  float* PSm  = (float*)alloc((size_t)BATCH * 16 * NPT * 4);
  float* POOL = (float*)alloc((size_t)BATCH * NPT * 4);
  float* FH   = (float*)alloc((size_t)BATCH * NPT * 4);
  size_t used = (size_t)(p - (char*)d_ws);
  const size_t per_g = (size_t)NN * 2;  // F bf16 (8MB per batch)
  int G = 8;
  while (G > 1 && used + (size_t)G * per_g + 1024 > ws_size) G >>= 1;
  bf16* F = (bf16*)alloc((size_t)G * NN * 2);

  // ---- weight converts ----
  k_cvt<<<(DEMB * DMID + 255) / 256, 256, 0, stream>>>(W2, W2b, DEMB * DMID);
  int nqk = NSA * 512 * DEMB;
  k_cvtqk<<<nqk / 256, 256, 0, stream>>>(WQ, WK, WQKb);
  int nw = NSA * DEMB * DEMB;
  k_cvt<<<(nw + 255) / 256, 256, 0, stream>>>(WV, WVb, nw);

  // ---- conv1 + BN1 + ReLU (-> H1tb bf16 [b][n][64]) ----
  long szh1 = (long)BATCH * NPT * DMID;
  k_conv1t<<<(int)(szh1 / 256), 256, 0, stream>>>(X, W1, B1, H1t);
  k_bn1a<<<128, 256, 0, stream>>>(H1t, pS, pS2);
  k_bn1b<<<1, 64, 0, stream>>>(pS, pS2, G1, BE1, sa1, sb1);
  k_bn1apply<<<(int)(szh1 / 256), 256, 0, stream>>>(H1t, sa1, sb1, H1tb);

  // ---- conv2 (MFMA) + BN2 + ReLU -> H fp32 [b][256][2048] ----
  k_mgemm<2><<<dim3(16, 2, 8), 256, 0, stream>>>(W2b, 0, DMID, H1tb, (long)NPT * DMID, DMID,
                                                 H, STRD, NPT, DMID, B2, nullptr, nullptr);
  k_bnstats<<<DEMB, 256, 0, stream>>>(H, DEMB, G2, BE2, sa2, sb2);
  k_bnapply<<<(int)(BATCH * STRD / 256), 256, 0, stream>>>(H, sa2, sb2, DEMB, (int)(BATCH * STRD));

  // ---- SA layers ----
  for (int l = 0; l < NSA; ++l) {
    k_tcvt<<<dim3(32, 4, 8), 256, 0, stream>>>(H, Ht);
    // QKt[n][0..511] = Ht . [Wq;Wk]^T  : A=Ht (M=2048), B=WQK (N=512)
    k_mgemm<1><<<dim3(4, 16, 8), 256, 0, stream>>>(Ht, STRD, DEMB, WQKb + (long)l * 512 * DEMB, 0, DEMB,
                                                   QKt, QKS, 512, DEMB, nullptr, nullptr, nullptr);
    // V[e][n] : A=Wv (M=256), B=Ht (N=2048)
    k_mgemm<1><<<dim3(16, 2, 8), 256, 0, stream>>>(WVb + (long)l * DEMB * DEMB, 0, DEMB, Ht, STRD, DEMB,
                                                   Vb, STRD, NPT, DEMB, nullptr, nullptr, nullptr);
    for (int b0 = 0; b0 < BATCH; b0 += G) {
      // F[m][n] = sum_a Kt[m][a] Qt[n][a] (= E^T), bf16 + fused exact column stats
      k_mgemm<0><<<dim3(16, 16, G), 256, 0, stream>>>(QKt + 256 + b0 * QKS, QKS, 512,
                                                      QKt + b0 * QKS, QKS, 512,
                                                      F, NN, NPT, DEMB, nullptr, PM, PSm);
      k_cms_fin<<<G * NPT / 256, 256, 0, stream>>>(PM, PSm, CM, CSi);
      // H[e][m] += S[m] * sum_n V[e][n] PT[m][n]  (PT from bf16 F on the fly)
      k_vp<<<dim3(64 * G), 256, 0, stream>>>(F, CM, CSi, Vb + b0 * STRD, H + b0 * STRD, G);
    }
  }

  // ---- head ----
  k_pool<<<(BATCH * NPT) / 256, 256, 0, stream>>>(H, POOL);
  k_fc1<<<dim3(NPT, BATCH), 256, 0, stream>>>(POOL, FC1W, FC1B, FH);
  k_fc2<<<BATCH, 256, 0, stream>>>(FH, FC2W, FC2B, OUT);
}

// Round 10
// 488.196 us; speedup vs baseline: 12.0520x; 1.0548x over previous
//
#include <hip/hip_runtime.h>
#include <hip/hip_bf16.h>

typedef __hip_bfloat16 bf16;
#define DEVI __device__ __forceinline__

// Problem constants
static constexpr int BATCH = 8;
static constexpr int NPT   = 2048;
static constexpr int DMID  = 64;
static constexpr int DEMB  = 256;
static constexpr int NSA   = 4;
static constexpr long STRD = (long)DEMB * NPT;  // 524288
static constexpr long QKS  = (long)NPT * 512;   // per-batch stride of QKt
static constexpr long NN   = (long)NPT * NPT;   // 4194304

typedef __attribute__((ext_vector_type(4))) float f32x4;
typedef __attribute__((ext_vector_type(8))) short bf16x8v;

DEVI f32x4 MFMA16(bf16x8v a, bf16x8v b, f32x4 c) {
  return __builtin_amdgcn_mfma_f32_16x16x32_bf16(a, b, c, 0, 0, 0);
}

DEVI void gload16(const bf16* g, bf16* l) {
  __builtin_amdgcn_global_load_lds(
      (const __attribute__((address_space(1))) void*)g,
      (__attribute__((address_space(3))) void*)l, 16, 0, 0);
}

DEVI float waveReduceSum(float v) {
#pragma unroll
  for (int o = 32; o > 0; o >>= 1) v += __shfl_down(v, o, 64);
  return v;
}
DEVI float blockReduceSum(float v) {
  __shared__ float sm[4];
  int lane = threadIdx.x & 63, wid = threadIdx.x >> 6;
  __syncthreads();
  v = waveReduceSum(v);
  if (lane == 0) sm[wid] = v;
  __syncthreads();
  return sm[0] + sm[1] + sm[2] + sm[3];
}

// ---- fp32 -> bf16 convert ----
__global__ void k_cvt(const float* __restrict__ in, bf16* __restrict__ out, int n) {
  int i = blockIdx.x * 256 + threadIdx.x;
  if (i < n) out[i] = __float2bfloat16(in[i]);
}

// ---- concat-convert Wq,Wk -> WQKb [l][512][256] bf16 ----
__global__ void k_cvtqk(const float* __restrict__ wq, const float* __restrict__ wk,
                        bf16* __restrict__ o) {
  int idx = blockIdx.x * 256 + threadIdx.x;  // NSA*512*256
  int c = idx & 255;
  int r = (idx >> 8) & 511;
  int l = idx >> 17;
  float v = (r < 256) ? wq[((l << 8) + r) * 256 + c] : wk[((l << 8) + (r - 256)) * 256 + c];
  o[idx] = __float2bfloat16(v);
}

// ---- conv1: H1t[b][n][o] = sum_c x[b,n,c]*w1[o,c] + b1[o] ----
__global__ void k_conv1t(const float* __restrict__ x, const float* __restrict__ w1,
                         const float* __restrict__ b1, float* __restrict__ h1t) {
  long idx = (long)blockIdx.x * 256 + threadIdx.x;  // [b*n][o]
  int o = idx & 63;
  long bn = idx >> 6;
  const float* xp = x + bn * 3;
  h1t[idx] = b1[o] + xp[0] * w1[o * 3] + xp[1] * w1[o * 3 + 1] + xp[2] * w1[o * 3 + 2];
}

// ---- BN1 stats on H1t [16384][64] ----
__global__ __launch_bounds__(256) void k_bn1a(const float* __restrict__ h, float* __restrict__ pS,
                                              float* __restrict__ pS2) {
  int c = threadIdx.x & 63, rg = threadIdx.x >> 6;
  long r0 = (long)blockIdx.x * 128 + rg * 32;
  float s = 0.f, s2 = 0.f;
  for (int i = 0; i < 32; ++i) {
    float v = h[(r0 + i) * 64 + c];
    s += v; s2 += v * v;
  }
  __shared__ float smS[256], smS2[256];
  smS[threadIdx.x] = s; smS2[threadIdx.x] = s2;
  __syncthreads();
  if (threadIdx.x < 64) {
    float a = 0.f, b = 0.f;
#pragma unroll
    for (int g = 0; g < 4; ++g) { a += smS[g * 64 + c]; b += smS2[g * 64 + c]; }
    pS[blockIdx.x * 64 + c] = a;
    pS2[blockIdx.x * 64 + c] = b;
  }
}
__global__ void k_bn1b(const float* __restrict__ pS, const float* __restrict__ pS2,
                       const float* __restrict__ g, const float* __restrict__ be,
                       float* __restrict__ sa, float* __restrict__ sb) {
  int c = threadIdx.x;
  if (c >= 64) return;
  float s = 0.f, s2 = 0.f;
  for (int i = 0; i < 128; ++i) { s += pS[i * 64 + c]; s2 += pS2[i * 64 + c]; }
  const float inv = 1.0f / (BATCH * NPT);
  float m = s * inv, var = s2 * inv - m * m;
  float A = rsqrtf(var + 1e-5f) * g[c];
  sa[c] = A; sb[c] = be[c] - m * A;
}
__global__ void k_bn1apply(const float* __restrict__ h, const float* __restrict__ sa,
                           const float* __restrict__ sb, bf16* __restrict__ o) {
  long idx = (long)blockIdx.x * 256 + threadIdx.x;
  int c = idx & 63;
  float v = fmaf(h[idx], sa[c], sb[c]);
  o[idx] = __float2bfloat16(v > 0.f ? v : 0.f);
}

// ---- BN2 stats/apply on H [b][256][2048] fp32 ----
__global__ __launch_bounds__(256) void k_bnstats(const float* __restrict__ h, int Cc,
                                                 const float* __restrict__ g, const float* __restrict__ be,
                                                 float* __restrict__ sa, float* __restrict__ sb) {
  int c = blockIdx.x;
  float s = 0.f, s2 = 0.f;
  for (int b = 0; b < BATCH; ++b) {
    const float* p = h + ((long)(b * Cc + c)) * NPT;
    for (int n = threadIdx.x; n < NPT; n += 256) {
      float v = p[n];
      s += v; s2 += v * v;
    }
  }
  s = blockReduceSum(s);
  s2 = blockReduceSum(s2);
  if (threadIdx.x == 0) {
    const float inv = 1.0f / (BATCH * NPT);
    float m = s * inv, var = s2 * inv - m * m;
    float A = rsqrtf(var + 1e-5f) * g[c];
    sa[c] = A; sb[c] = be[c] - m * A;
  }
}
__global__ void k_bnapply(float* __restrict__ h, const float* __restrict__ sa,
                          const float* __restrict__ sb, int Cc, int total) {
  int i = blockIdx.x * 256 + threadIdx.x;
  if (i >= total) return;
  int c = (i >> 11) & (Cc - 1);
  float v = fmaf(h[i], sa[c], sb[c]);
  h[i] = v > 0.f ? v : 0.f;
}

// ---- tiled transpose+convert: H [b][256][2048] f32 -> Ht [b][2048][256] bf16 ----
__global__ __launch_bounds__(256) void k_tcvt(const float* __restrict__ H, bf16* __restrict__ Ht) {
  __shared__ float t[64][65];
  const float* h = H + (long)blockIdx.z * STRD;
  bf16* o = Ht + (long)blockIdx.z * STRD;
  int n0 = blockIdx.x * 64, c0 = blockIdx.y * 64;
#pragma unroll
  for (int ii = 0; ii < 16; ++ii) {
    int idx = ii * 256 + threadIdx.x;
    int i = idx >> 6, j = idx & 63;
    t[i][j] = h[(long)(c0 + i) * NPT + n0 + j];
  }
  __syncthreads();
#pragma unroll
  for (int ii = 0; ii < 16; ++ii) {
    int idx = ii * 256 + threadIdx.x;
    int i = idx >> 6, j = idx & 63;
    o[(long)(n0 + i) * DEMB + c0 + j] = __float2bfloat16(t[j][i]);
  }
}

// ---- MFMA GEMM, B^T form: C[M][N] = A[M][K] . B[N][K]^T ; 128x128 tile, BK=64 ----
// XOR-swizzled LDS (granule ^= row&7) on both staging-source and read.
// MODE 0: C bf16 = acc, PLUS column-softmax partial stats from fp32 acc (PM/PS)
// MODE 1: C bf16 = acc
// MODE 2: C f32 = acc + bias[r]
template <int MODE>
__global__ __launch_bounds__(256) void k_mgemm(
    const bf16* __restrict__ A, long aStr, int ldA,
    const bf16* __restrict__ B, long bStr, int ldB,
    void* __restrict__ Cv, long cStr, int ldC,
    int K,
    const float* __restrict__ bias,
    float* __restrict__ PMo, float* __restrict__ PSo) {
  __shared__ __align__(16) bf16 sA[128 * 64];
  __shared__ __align__(16) bf16 sB[128 * 64];
  __shared__ float smx[4][64], ssx[4][64];
  const int z = blockIdx.z;
  A += aStr * z;
  B += bStr * z;
  const int bm = blockIdx.y * 128, bn = blockIdx.x * 128;
  const int tid = threadIdx.x;
  const int lane = tid & 63, wv = tid >> 6;
  const int wr = (wv >> 1) * 64, wc = (wv & 1) * 64;
  f32x4 acc[4][4] = {};

  for (int k0 = 0; k0 < K; k0 += 64) {
#pragma unroll
    for (int i = 0; i < 4; ++i) {
      int c = i * 256 + tid;
      int row = c >> 3, g = c & 7;
      int gs = (g ^ (row & 7)) * 8;
      gload16(A + (long)(bm + row) * ldA + k0 + gs, sA + c * 8);
      gload16(B + (long)(bn + row) * ldB + k0 + gs, sB + c * 8);
    }
    __syncthreads();
    bf16x8v af[4][2], bfr[4][2];
#pragma unroll
    for (int mi = 0; mi < 4; ++mi)
#pragma unroll
      for (int ks = 0; ks < 2; ++ks) {
        int rA = wr + mi * 16 + (lane & 15);
        int rB = wc + mi * 16 + (lane & 15);
        int g = ks * 4 + (lane >> 4);
        af[mi][ks]  = *(const bf16x8v*)&sA[rA * 64 + ((g ^ (rA & 7)) * 8)];
        bfr[mi][ks] = *(const bf16x8v*)&sB[rB * 64 + ((g ^ (rB & 7)) * 8)];
      }
#pragma unroll
    for (int ks = 0; ks < 2; ++ks)
#pragma unroll
      for (int mi = 0; mi < 4; ++mi)
#pragma unroll
        for (int ni = 0; ni < 4; ++ni)
          acc[mi][ni] = MFMA16(af[mi][ks], bfr[ni][ks], acc[mi][ni]);
    __syncthreads();
  }

  const int rb = (lane >> 4) * 4, cb = lane & 15;
  if constexpr (MODE == 0 || MODE == 1) {
    bf16* C = (bf16*)Cv + cStr * z;
#pragma unroll
    for (int mi = 0; mi < 4; ++mi)
#pragma unroll
      for (int ni = 0; ni < 4; ++ni) {
        int r0 = bm + wr + mi * 16 + rb, c0 = bn + wc + ni * 16 + cb;
#pragma unroll
        for (int k = 0; k < 4; ++k)
          C[(long)(r0 + k) * ldC + c0] = __float2bfloat16(acc[mi][ni][k]);
      }
  } else {
    float* C = (float*)Cv + cStr * z;
#pragma unroll
    for (int mi = 0; mi < 4; ++mi)
#pragma unroll
      for (int ni = 0; ni < 4; ++ni) {
        int r0 = bm + wr + mi * 16 + rb, c0 = bn + wc + ni * 16 + cb;
#pragma unroll
        for (int k = 0; k < 4; ++k) {
          int r = r0 + k;
          C[(long)r * ldC + c0] = acc[mi][ni][k] + bias[r];
        }
      }
  }

  if constexpr (MODE == 0) {
    // per-column (over this block's 128 rows) online-softmax partials (exact fp32)
    float cm[4], cs[4];
#pragma unroll
    for (int ni = 0; ni < 4; ++ni) {
      float m = -3.0e38f;
#pragma unroll
      for (int mi = 0; mi < 4; ++mi)
#pragma unroll
        for (int k = 0; k < 4; ++k) m = fmaxf(m, acc[mi][ni][k]);
      float s = 0.f;
#pragma unroll
      for (int mi = 0; mi < 4; ++mi)
#pragma unroll
        for (int k = 0; k < 4; ++k) s += __expf(acc[mi][ni][k] - m);
#pragma unroll
      for (int off = 16; off <= 32; off <<= 1) {
        float mo = __shfl_xor(m, off, 64);
        float so = __shfl_xor(s, off, 64);
        float M = fmaxf(m, mo);
        s = s * __expf(m - M) + so * __expf(mo - M);
        m = M;
      }
      cm[ni] = m; cs[ni] = s;
    }
    __syncthreads();  // LDS reads of K-loop complete; reuse smx/ssx safely
    if (lane < 16) {
#pragma unroll
      for (int ni = 0; ni < 4; ++ni) {
        smx[wv][ni * 16 + lane] = cm[ni];
        ssx[wv][ni * 16 + lane] = cs[ni];
      }
    }
    __syncthreads();
    if (tid < 128) {
      int half = tid >> 6, c64 = tid & 63;
      float m1 = smx[half][c64], s1 = ssx[half][c64];
      float m2 = smx[half + 2][c64], s2 = ssx[half + 2][c64];
      float M = fmaxf(m1, m2);
      float S = s1 * __expf(m1 - M) + s2 * __expf(m2 - M);
      long o = ((long)z * 16 + blockIdx.y) * NPT + bn + half * 64 + c64;
      PMo[o] = M;
      PSo[o] = S;
    }
  }
}

// ---- combine 16 partials per column -> CM, CSi ----
__global__ void k_cms_fin(const float* __restrict__ PM, const float* __restrict__ PS,
                          float* __restrict__ CM, float* __restrict__ CSi) {
  long idx = (long)blockIdx.x * 256 + threadIdx.x;  // [G*NPT]
  long z = idx >> 11;
  int n = idx & (NPT - 1);
  const float* pm = PM + z * 16 * NPT + n;
  const float* ps = PS + z * 16 * NPT + n;
  float m = -3.0e38f;
#pragma unroll
  for (int y = 0; y < 16; ++y) m = fmaxf(m, pm[(long)y * NPT]);
  float s = 0.f;
#pragma unroll
  for (int y = 0; y < 16; ++y) s += ps[(long)y * NPT] * __expf(pm[(long)y * NPT] - m);
  CM[idx] = m;
  CSi[idx] = 1.0f / s;
}

// ---- fused normalize + rowsum + V.P GEMM (F bf16, 2-phase dbuf, 8 waves) ----
// Per block: e = 0..255 (M), m in [m0, m0+64) (N), K = n = 0..2047.
// 512 threads = 8 waves arranged 4(e) x 2(m); tile 256e x 64m.
// 1-D grid 32*nz; z = bid % nz pins each batch's V to one XCD's L2.
// F read: row fr = tid>>3 (0..63), chunk fq = tid&7 -> fully coalesced 128B.
__global__ __launch_bounds__(512) void k_vp(const bf16* __restrict__ F,
                                            const float* __restrict__ CM,
                                            const float* __restrict__ CSi,
                                            const bf16* __restrict__ V,
                                            float* __restrict__ H, int nz) {
  __shared__ __align__(16) bf16 sA[2][256 * 64];  // V tiles (double-buffered)
  __shared__ __align__(16) bf16 sB[2][64 * 64];   // PT tiles (double-buffered)
  __shared__ float rsLds[64][8];
  __shared__ float Sv[64];
  const int z = blockIdx.x % nz;
  const int m0 = (blockIdx.x / nz) * 64;
  const int tid = threadIdx.x;
  const int lane = tid & 63, wv = tid >> 6;
  const int we = wv & 3;   // e-quarter 0..3 (64 rows)
  const int wm = wv >> 2;  // m-half 0..1 (32 cols)
  const int fr = tid >> 3; // F row 0..63
  const int fq = tid & 7;  // F col chunk 0..7
  const bf16* Vz = V + (long)z * STRD;
  const bf16* Frp = F + (long)z * NN + (long)(m0 + fr) * NPT + fq * 8;
  const float* CMz = CM + (long)z * NPT + fq * 8;
  const float* CSz = CSi + (long)z * NPT + fq * 8;
  f32x4 acc[4][2] = {};
  float rs = 0.f;
  bf16x8v fvA, fvB;
  float mvA[8], cvA[8], mvB[8], cvB[8];

  // LOADF: prefetch F chunk + its CM/CSi into registers
#define LOADF(FREG, MV, CV, N0)                                                \
  {                                                                            \
    FREG = *(const bf16x8v*)(Frp + (N0));                                      \
    *(float4*)&MV[0] = *(const float4*)(CMz + (N0));                           \
    *(float4*)&MV[4] = *(const float4*)(CMz + (N0) + 4);                       \
    *(float4*)&CV[0] = *(const float4*)(CSz + (N0));                           \
    *(float4*)&CV[4] = *(const float4*)(CSz + (N0) + 4);                       \
  }

  // EXPW: exp of register F chunk -> sB[buf]; accumulate rs
#define EXPW(BUF, FREG, MV, CV)                                                \
  {                                                                            \
    bf16 tb[8];                                                                \
    _Pragma("unroll") for (int i = 0; i < 8; ++i) {                            \
      float fvi = __uint_as_float((unsigned)(unsigned short)FREG[i] << 16);    \
      float pv = __expf(fvi - MV[i]) * CV[i];                                  \
      rs += pv;                                                                \
      tb[i] = __float2bfloat16(pv);                                            \
    }                                                                          \
    *(bf16x8v*)&sB[BUF][fr * 64 + ((fq ^ (fr & 7)) * 8)] = *(bf16x8v*)tb;      \
  }

  // STAGEV: issue 4 global_load_lds of V column-chunk into sA[buf] (512 thr)
#define STAGEV(BUF, N0)                                                        \
  _Pragma("unroll") for (int i = 0; i < 4; ++i) {                              \
    int c = i * 512 + tid;                                                     \
    int row = c >> 3, g = c & 7;                                               \
    gload16(Vz + (long)row * NPT + (N0) + ((g ^ (row & 7)) * 8),               \
            &sA[BUF][c * 8]);                                                  \
  }

  // prologue
  LOADF(fvA, mvA, cvA, 0)
  EXPW(0, fvA, mvA, cvA)
  STAGEV(0, 0)
  LOADF(fvB, mvB, cvB, 64)
  __syncthreads();

  // body: one barrier per step; stage/exp for step+1 before MFMA on step
#define VP_BODY(CUR, FN, MVN, CVN, FN2, MVN2, CVN2, STEPI)                     \
  {                                                                            \
    const int sn = (STEPI);                                                    \
    const int nn0 = sn * 64;                                                   \
    if (sn + 1 < 32) {                                                         \
      STAGEV(CUR ^ 1, nn0 + 64)                                                \
      EXPW(CUR ^ 1, FN, MVN, CVN)                                              \
      if (sn + 2 < 32) LOADF(FN2, MVN2, CVN2, nn0 + 128)                       \
    }                                                                          \
    bf16x8v bfr[2][2];                                                         \
    _Pragma("unroll") for (int ni = 0; ni < 2; ++ni)                           \
      _Pragma("unroll") for (int ks = 0; ks < 2; ++ks) {                       \
        int rB = wm * 32 + ni * 16 + (lane & 15);                              \
        int g = ks * 4 + (lane >> 4);                                          \
        bfr[ni][ks] = *(const bf16x8v*)&sB[CUR][rB * 64 + ((g ^ (rB & 7)) * 8)]; \
      }                                                                        \
    _Pragma("unroll") for (int mi = 0; mi < 4; ++mi)                           \
      _Pragma("unroll") for (int ks = 0; ks < 2; ++ks) {                       \
        int rA = we * 64 + mi * 16 + (lane & 15);                              \
        int g = ks * 4 + (lane >> 4);                                          \
        bf16x8v af = *(const bf16x8v*)&sA[CUR][rA * 64 + ((g ^ (rA & 7)) * 8)]; \
        _Pragma("unroll") for (int ni = 0; ni < 2; ++ni)                       \
          acc[mi][ni] = MFMA16(af, bfr[ni][ks], acc[mi][ni]);                  \
      }                                                                        \
    __syncthreads();                                                           \
  }

  for (int it = 0; it < 16; ++it) {
    VP_BODY(0, fvB, mvB, cvB, fvA, mvA, cvA, 2 * it)
    VP_BODY(1, fvA, mvA, cvA, fvB, mvB, cvB, 2 * it + 1)
  }
#undef VP_BODY
#undef STAGEV
#undef EXPW
#undef LOADF

  rsLds[fr][fq] = rs;
  __syncthreads();
  if (tid < 64) {
    float R = 0.f;
#pragma unroll
    for (int q = 0; q < 8; ++q) R += rsLds[tid][q];
    Sv[tid] = 1.0f / (1e-9f + R);
  }
  __syncthreads();

  float* Hz = H + (long)z * STRD;
  const int rb = (lane >> 4) * 4, cb = lane & 15;
#pragma unroll
  for (int mi = 0; mi < 4; ++mi) {
    int e0 = we * 64 + mi * 16 + rb;
#pragma unroll
    for (int ni = 0; ni < 2; ++ni) {
      int c = wm * 32 + ni * 16 + cb;
      float scl = Sv[c];
#pragma unroll
      for (int k = 0; k < 4; ++k)
        Hz[(long)(e0 + k) * NPT + m0 + c] += acc[mi][ni][k] * scl;
    }
  }
}

// ---- pooled[b,n] = mean over e of H[b,e,n] ----
__global__ void k_pool(const float* __restrict__ H, float* __restrict__ pooled) {
  int i = blockIdx.x * 256 + threadIdx.x;
  if (i >= BATCH * NPT) return;
  int b = i >> 11, n = i & (NPT - 1);
  const float* p = H + (long)b * STRD + n;
  float s = 0.f;
  for (int e = 0; e < DEMB; ++e) s += p[(long)e * NPT];
  pooled[i] = s * (1.0f / DEMB);
}

// ---- fc1 ----
__global__ __launch_bounds__(256) void k_fc1(const float* __restrict__ pooled,
                                             const float* __restrict__ w, const float* __restrict__ bias,
                                             float* __restrict__ f) {
  int j = blockIdx.x, b = blockIdx.y;
  const float* pp = pooled + (long)b * NPT;
  const float* wr = w + (long)j * NPT;
  float s = 0.f;
  for (int n = threadIdx.x; n < NPT; n += 256) s += pp[n] * wr[n];
  s = blockReduceSum(s);
  if (threadIdx.x == 0) {
    s += bias[j];
    f[(long)b * NPT + j] = s > 0.f ? s : 0.f;
  }
}

// ---- fc2 ----
__global__ __launch_bounds__(256) void k_fc2(const float* __restrict__ f,
                                             const float* __restrict__ w, const float* __restrict__ bias,
                                             float* __restrict__ out) {
  int b = blockIdx.x;
  float s = 0.f;
  for (int j = threadIdx.x; j < NPT; j += 256) s += f[(long)b * NPT + j] * w[j];
  s = blockReduceSum(s);
  if (threadIdx.x == 0) out[b] = s + bias[0];
}

extern "C" void kernel_launch(void* const* d_in, const int* in_sizes, int n_in,
                              void* d_out, int out_size, void* d_ws, size_t ws_size,
                              hipStream_t stream) {
  const float* X    = (const float*)d_in[0];
  const float* W1   = (const float*)d_in[1];
  const float* B1   = (const float*)d_in[2];
  const float* G1   = (const float*)d_in[3];
  const float* BE1  = (const float*)d_in[4];
  const float* W2   = (const float*)d_in[5];
  const float* B2   = (const float*)d_in[6];
  const float* G2   = (const float*)d_in[7];
  const float* BE2  = (const float*)d_in[8];
  const float* WQ   = (const float*)d_in[9];
  const float* WK   = (const float*)d_in[10];
  const float* WV   = (const float*)d_in[11];
  const float* FC1W = (const float*)d_in[12];
  const float* FC1B = (const float*)d_in[13];
  const float* FC2W = (const float*)d_in[14];
  const float* FC2B = (const float*)d_in[15];
  float* OUT = (float*)d_out;

  // ---- workspace carve-out ----
  char* p = (char*)d_ws;
  auto alloc = [&](size_t bytes) -> char* {
    char* r = p;
    p += (bytes + 255) & ~(size_t)255;
    return r;
  };
  float* H1t  = (float*)alloc((size_t)BATCH * NPT * DMID * 4);
  bf16*  H1tb = (bf16*)alloc((size_t)BATCH * NPT * DMID * 2);
  float* H    = (float*)alloc((size_t)BATCH * STRD * 4);
  bf16*  Ht   = (bf16*)alloc((size_t)BATCH * STRD * 2);
  bf16*  QKt  = (bf16*)alloc((size_t)BATCH * QKS * 2);   // [b][n][512] = Q(0..255) | K(256..511)
  bf16*  Vb   = (bf16*)alloc((size_t)BATCH * STRD * 2);
  bf16*  W2b  = (bf16*)alloc((size_t)DEMB * DMID * 2);
  bf16*  WQKb = (bf16*)alloc((size_t)NSA * 512 * DEMB * 2);
  bf16*  WVb  = (bf16*)alloc((size_t)NSA * DEMB * DEMB * 2);
  float* pS   = (float*)alloc(128 * 64 * 4);
  float* pS2  = (float*)alloc(128 * 64 * 4);
  float* sa1  = (float*)alloc(64 * 4);
  float* sb1  = (float*)alloc(64 * 4);
  float* sa2  = (float*)alloc(256 * 4);
  float* sb2  = (float*)alloc(256 * 4);
  float* CM   = (float*)alloc((size_t)BATCH * NPT * 4);
  float* CSi  = (float*)alloc((size_t)BATCH * NPT * 4);
  float* PM   = (float*)alloc((size_t)BATCH * 16 * NPT * 4);
  float* PSm  = (float*)alloc((size_t)BATCH * 16 * NPT * 4);
  float* POOL = (float*)alloc((size_t)BATCH * NPT * 4);
  float* FH   = (float*)alloc((size_t)BATCH * NPT * 4);
  size_t used = (size_t)(p - (char*)d_ws);
  const size_t per_g = (size_t)NN * 2;  // F bf16 (8MB per batch)
  int G = 8;
  while (G > 1 && used + (size_t)G * per_g + 1024 > ws_size) G >>= 1;
  bf16* F = (bf16*)alloc((size_t)G * NN * 2);

  // ---- weight converts ----
  k_cvt<<<(DEMB * DMID + 255) / 256, 256, 0, stream>>>(W2, W2b, DEMB * DMID);
  int nqk = NSA * 512 * DEMB;
  k_cvtqk<<<nqk / 256, 256, 0, stream>>>(WQ, WK, WQKb);
  int nw = NSA * DEMB * DEMB;
  k_cvt<<<(nw + 255) / 256, 256, 0, stream>>>(WV, WVb, nw);

  // ---- conv1 + BN1 + ReLU (-> H1tb bf16 [b][n][64]) ----
  long szh1 = (long)BATCH * NPT * DMID;
  k_conv1t<<<(int)(szh1 / 256), 256, 0, stream>>>(X, W1, B1, H1t);
  k_bn1a<<<128, 256, 0, stream>>>(H1t, pS, pS2);
  k_bn1b<<<1, 64, 0, stream>>>(pS, pS2, G1, BE1, sa1, sb1);
  k_bn1apply<<<(int)(szh1 / 256), 256, 0, stream>>>(H1t, sa1, sb1, H1tb);

  // ---- conv2 (MFMA) + BN2 + ReLU -> H fp32 [b][256][2048] ----
  k_mgemm<2><<<dim3(16, 2, 8), 256, 0, stream>>>(W2b, 0, DMID, H1tb, (long)NPT * DMID, DMID,
                                                 H, STRD, NPT, DMID, B2, nullptr, nullptr);
  k_bnstats<<<DEMB, 256, 0, stream>>>(H, DEMB, G2, BE2, sa2, sb2);
  k_bnapply<<<(int)(BATCH * STRD / 256), 256, 0, stream>>>(H, sa2, sb2, DEMB, (int)(BATCH * STRD));

  // ---- SA layers ----
  for (int l = 0; l < NSA; ++l) {
    k_tcvt<<<dim3(32, 4, 8), 256, 0, stream>>>(H, Ht);
    // QKt[n][0..511] = Ht . [Wq;Wk]^T  : A=Ht (M=2048), B=WQK (N=512)
    k_mgemm<1><<<dim3(4, 16, 8), 256, 0, stream>>>(Ht, STRD, DEMB, WQKb + (long)l * 512 * DEMB, 0, DEMB,
                                                   QKt, QKS, 512, DEMB, nullptr, nullptr, nullptr);
    // V[e][n] : A=Wv (M=256), B=Ht (N=2048)
    k_mgemm<1><<<dim3(16, 2, 8), 256, 0, stream>>>(WVb + (long)l * DEMB * DEMB, 0, DEMB, Ht, STRD, DEMB,
                                                   Vb, STRD, NPT, DEMB, nullptr, nullptr, nullptr);
    for (int b0 = 0; b0 < BATCH; b0 += G) {
      // F[m][n] = sum_a Kt[m][a] Qt[n][a] (= E^T), bf16 + fused exact column stats
      k_mgemm<0><<<dim3(16, 16, G), 256, 0, stream>>>(QKt + 256 + b0 * QKS, QKS, 512,
                                                      QKt + b0 * QKS, QKS, 512,
                                                      F, NN, NPT, DEMB, nullptr, PM, PSm);
      k_cms_fin<<<G * NPT / 256, 256, 0, stream>>>(PM, PSm, CM, CSi);
      // H[e][m] += S[m] * sum_n V[e][n] PT[m][n]  (PT from bf16 F on the fly)
      k_vp<<<dim3(32 * G), 512, 0, stream>>>(F, CM, CSi, Vb + b0 * STRD, H + b0 * STRD, G);
    }
  }

  // ---- head ----
  k_pool<<<(BATCH * NPT) / 256, 256, 0, stream>>>(H, POOL);
  k_fc1<<<dim3(NPT, BATCH), 256, 0, stream>>>(POOL, FC1W, FC1B, FH);
  k_fc2<<<BATCH, 256, 0, stream>>>(FH, FC2W, FC2B, OUT);
}

// Round 11
// 472.949 us; speedup vs baseline: 12.4405x; 1.0322x over previous
//
#include <hip/hip_runtime.h>
#include <hip/hip_bf16.h>

typedef __hip_bfloat16 bf16;
#define DEVI __device__ __forceinline__

// Problem constants
static constexpr int BATCH = 8;
static constexpr int NPT   = 2048;
static constexpr int DMID  = 64;
static constexpr int DEMB  = 256;
static constexpr int NSA   = 4;
static constexpr long STRD = (long)DEMB * NPT;  // 524288
static constexpr long QKS  = (long)NPT * 512;   // per-batch stride of QKt
static constexpr long NN   = (long)NPT * NPT;   // 4194304

typedef __attribute__((ext_vector_type(4))) float f32x4;
typedef __attribute__((ext_vector_type(8))) short bf16x8v;

DEVI f32x4 MFMA16(bf16x8v a, bf16x8v b, f32x4 c) {
  return __builtin_amdgcn_mfma_f32_16x16x32_bf16(a, b, c, 0, 0, 0);
}

DEVI void gload16(const bf16* g, bf16* l) {
  __builtin_amdgcn_global_load_lds(
      (const __attribute__((address_space(1))) void*)g,
      (__attribute__((address_space(3))) void*)l, 16, 0, 0);
}

DEVI float waveReduceSum(float v) {
#pragma unroll
  for (int o = 32; o > 0; o >>= 1) v += __shfl_down(v, o, 64);
  return v;
}
DEVI float blockReduceSum(float v) {
  __shared__ float sm[4];
  int lane = threadIdx.x & 63, wid = threadIdx.x >> 6;
  __syncthreads();
  v = waveReduceSum(v);
  if (lane == 0) sm[wid] = v;
  __syncthreads();
  return sm[0] + sm[1] + sm[2] + sm[3];
}

// ---- fp32 -> bf16 convert ----
__global__ void k_cvt(const float* __restrict__ in, bf16* __restrict__ out, int n) {
  int i = blockIdx.x * 256 + threadIdx.x;
  if (i < n) out[i] = __float2bfloat16(in[i]);
}

// ---- concat-convert Wq,Wk -> WQKb [l][512][256] bf16 ----
__global__ void k_cvtqk(const float* __restrict__ wq, const float* __restrict__ wk,
                        bf16* __restrict__ o) {
  int idx = blockIdx.x * 256 + threadIdx.x;  // NSA*512*256
  int c = idx & 255;
  int r = (idx >> 8) & 511;
  int l = idx >> 17;
  float v = (r < 256) ? wq[((l << 8) + r) * 256 + c] : wk[((l << 8) + (r - 256)) * 256 + c];
  o[idx] = __float2bfloat16(v);
}

// ---- conv1: H1t[b][n][o] = sum_c x[b,n,c]*w1[o,c] + b1[o] ----
__global__ void k_conv1t(const float* __restrict__ x, const float* __restrict__ w1,
                         const float* __restrict__ b1, float* __restrict__ h1t) {
  long idx = (long)blockIdx.x * 256 + threadIdx.x;  // [b*n][o]
  int o = idx & 63;
  long bn = idx >> 6;
  const float* xp = x + bn * 3;
  h1t[idx] = b1[o] + xp[0] * w1[o * 3] + xp[1] * w1[o * 3 + 1] + xp[2] * w1[o * 3 + 2];
}

// ---- BN1 stats on H1t [16384][64] ----
__global__ __launch_bounds__(256) void k_bn1a(const float* __restrict__ h, float* __restrict__ pS,
                                              float* __restrict__ pS2) {
  int c = threadIdx.x & 63, rg = threadIdx.x >> 6;
  long r0 = (long)blockIdx.x * 128 + rg * 32;
  float s = 0.f, s2 = 0.f;
  for (int i = 0; i < 32; ++i) {
    float v = h[(r0 + i) * 64 + c];
    s += v; s2 += v * v;
  }
  __shared__ float smS[256], smS2[256];
  smS[threadIdx.x] = s; smS2[threadIdx.x] = s2;
  __syncthreads();
  if (threadIdx.x < 64) {
    float a = 0.f, b = 0.f;
#pragma unroll
    for (int g = 0; g < 4; ++g) { a += smS[g * 64 + c]; b += smS2[g * 64 + c]; }
    pS[blockIdx.x * 64 + c] = a;
    pS2[blockIdx.x * 64 + c] = b;
  }
}
__global__ void k_bn1b(const float* __restrict__ pS, const float* __restrict__ pS2,
                       const float* __restrict__ g, const float* __restrict__ be,
                       float* __restrict__ sa, float* __restrict__ sb) {
  int c = threadIdx.x;
  if (c >= 64) return;
  float s = 0.f, s2 = 0.f;
  for (int i = 0; i < 128; ++i) { s += pS[i * 64 + c]; s2 += pS2[i * 64 + c]; }
  const float inv = 1.0f / (BATCH * NPT);
  float m = s * inv, var = s2 * inv - m * m;
  float A = rsqrtf(var + 1e-5f) * g[c];
  sa[c] = A; sb[c] = be[c] - m * A;
}
__global__ void k_bn1apply(const float* __restrict__ h, const float* __restrict__ sa,
                           const float* __restrict__ sb, bf16* __restrict__ o) {
  long idx = (long)blockIdx.x * 256 + threadIdx.x;
  int c = idx & 63;
  float v = fmaf(h[idx], sa[c], sb[c]);
  o[idx] = __float2bfloat16(v > 0.f ? v : 0.f);
}

// ---- BN2 stats/apply on H [b][256][2048] fp32 ----
__global__ __launch_bounds__(256) void k_bnstats(const float* __restrict__ h, int Cc,
                                                 const float* __restrict__ g, const float* __restrict__ be,
                                                 float* __restrict__ sa, float* __restrict__ sb) {
  int c = blockIdx.x;
  float s = 0.f, s2 = 0.f;
  for (int b = 0; b < BATCH; ++b) {
    const float* p = h + ((long)(b * Cc + c)) * NPT;
    for (int n = threadIdx.x; n < NPT; n += 256) {
      float v = p[n];
      s += v; s2 += v * v;
    }
  }
  s = blockReduceSum(s);
  s2 = blockReduceSum(s2);
  if (threadIdx.x == 0) {
    const float inv = 1.0f / (BATCH * NPT);
    float m = s * inv, var = s2 * inv - m * m;
    float A = rsqrtf(var + 1e-5f) * g[c];
    sa[c] = A; sb[c] = be[c] - m * A;
  }
}
__global__ void k_bnapply(float* __restrict__ h, const float* __restrict__ sa,
                          const float* __restrict__ sb, int Cc, int total) {
  int i = blockIdx.x * 256 + threadIdx.x;
  if (i >= total) return;
  int c = (i >> 11) & (Cc - 1);
  float v = fmaf(h[i], sa[c], sb[c]);
  h[i] = v > 0.f ? v : 0.f;
}

// ---- tiled transpose+convert: H [b][256][2048] f32 -> Ht [b][2048][256] bf16 ----
__global__ __launch_bounds__(256) void k_tcvt(const float* __restrict__ H, bf16* __restrict__ Ht) {
  __shared__ float t[64][65];
  const float* h = H + (long)blockIdx.z * STRD;
  bf16* o = Ht + (long)blockIdx.z * STRD;
  int n0 = blockIdx.x * 64, c0 = blockIdx.y * 64;
#pragma unroll
  for (int ii = 0; ii < 16; ++ii) {
    int idx = ii * 256 + threadIdx.x;
    int i = idx >> 6, j = idx & 63;
    t[i][j] = h[(long)(c0 + i) * NPT + n0 + j];
  }
  __syncthreads();
#pragma unroll
  for (int ii = 0; ii < 16; ++ii) {
    int idx = ii * 256 + threadIdx.x;
    int i = idx >> 6, j = idx & 63;
    o[(long)(n0 + i) * DEMB + c0 + j] = __float2bfloat16(t[j][i]);
  }
}

// ---- MFMA GEMM, B^T form: C[M][N] = A[M][K] . B[N][K]^T ; 128x128 tile, BK=64 ----
// XOR-swizzled LDS (granule ^= row&7) on both staging-source and read.
// MODE 0: C bf16 = acc + fused column-softmax partials; 1-D grid, z = bid % nz (XCD-pin)
// MODE 1: C bf16 = acc
// MODE 2: C f32 = acc + bias[r]
template <int MODE>
__global__ __launch_bounds__(256) void k_mgemm(
    const bf16* __restrict__ A, long aStr, int ldA,
    const bf16* __restrict__ B, long bStr, int ldB,
    void* __restrict__ Cv, long cStr, int ldC,
    int K,
    const float* __restrict__ bias,
    float* __restrict__ PMo, float* __restrict__ PSo, int nz) {
  __shared__ __align__(16) bf16 sA[128 * 64];
  __shared__ __align__(16) bf16 sB[128 * 64];
  __shared__ float smx[4][64], ssx[4][64];
  int bx, by, bz;
  if constexpr (MODE == 0) {
    bz = blockIdx.x % nz;
    int t = blockIdx.x / nz;
    bx = t & 15;
    by = t >> 4;
  } else {
    bx = blockIdx.x; by = blockIdx.y; bz = blockIdx.z;
  }
  A += aStr * bz;
  B += bStr * bz;
  const int bm = by * 128, bn = bx * 128;
  const int tid = threadIdx.x;
  const int lane = tid & 63, wv = tid >> 6;
  const int wr = (wv >> 1) * 64, wc = (wv & 1) * 64;
  f32x4 acc[4][4] = {};

  for (int k0 = 0; k0 < K; k0 += 64) {
#pragma unroll
    for (int i = 0; i < 4; ++i) {
      int c = i * 256 + tid;
      int row = c >> 3, g = c & 7;
      int gs = (g ^ (row & 7)) * 8;
      gload16(A + (long)(bm + row) * ldA + k0 + gs, sA + c * 8);
      gload16(B + (long)(bn + row) * ldB + k0 + gs, sB + c * 8);
    }
    __syncthreads();
    bf16x8v af[4][2], bfr[4][2];
#pragma unroll
    for (int mi = 0; mi < 4; ++mi)
#pragma unroll
      for (int ks = 0; ks < 2; ++ks) {
        int rA = wr + mi * 16 + (lane & 15);
        int rB = wc + mi * 16 + (lane & 15);
        int g = ks * 4 + (lane >> 4);
        af[mi][ks]  = *(const bf16x8v*)&sA[rA * 64 + ((g ^ (rA & 7)) * 8)];
        bfr[mi][ks] = *(const bf16x8v*)&sB[rB * 64 + ((g ^ (rB & 7)) * 8)];
      }
#pragma unroll
    for (int ks = 0; ks < 2; ++ks)
#pragma unroll
      for (int mi = 0; mi < 4; ++mi)
#pragma unroll
        for (int ni = 0; ni < 4; ++ni)
          acc[mi][ni] = MFMA16(af[mi][ks], bfr[ni][ks], acc[mi][ni]);
    __syncthreads();
  }

  const int rb = (lane >> 4) * 4, cb = lane & 15;
  if constexpr (MODE == 0 || MODE == 1) {
    bf16* C = (bf16*)Cv + cStr * bz;
#pragma unroll
    for (int mi = 0; mi < 4; ++mi)
#pragma unroll
      for (int ni = 0; ni < 4; ++ni) {
        int r0 = bm + wr + mi * 16 + rb, c0 = bn + wc + ni * 16 + cb;
#pragma unroll
        for (int k = 0; k < 4; ++k)
          C[(long)(r0 + k) * ldC + c0] = __float2bfloat16(acc[mi][ni][k]);
      }
  } else {
    float* C = (float*)Cv + cStr * bz;
#pragma unroll
    for (int mi = 0; mi < 4; ++mi)
#pragma unroll
      for (int ni = 0; ni < 4; ++ni) {
        int r0 = bm + wr + mi * 16 + rb, c0 = bn + wc + ni * 16 + cb;
#pragma unroll
        for (int k = 0; k < 4; ++k) {
          int r = r0 + k;
          C[(long)r * ldC + c0] = acc[mi][ni][k] + bias[r];
        }
      }
  }

  if constexpr (MODE == 0) {
    // per-column (over this block's 128 rows) online-softmax partials (exact fp32)
    float cm[4], cs[4];
#pragma unroll
    for (int ni = 0; ni < 4; ++ni) {
      float m = -3.0e38f;
#pragma unroll
      for (int mi = 0; mi < 4; ++mi)
#pragma unroll
        for (int k = 0; k < 4; ++k) m = fmaxf(m, acc[mi][ni][k]);
      float s = 0.f;
#pragma unroll
      for (int mi = 0; mi < 4; ++mi)
#pragma unroll
        for (int k = 0; k < 4; ++k) s += __expf(acc[mi][ni][k] - m);
#pragma unroll
      for (int off = 16; off <= 32; off <<= 1) {
        float mo = __shfl_xor(m, off, 64);
        float so = __shfl_xor(s, off, 64);
        float M = fmaxf(m, mo);
        s = s * __expf(m - M) + so * __expf(mo - M);
        m = M;
      }
      cm[ni] = m; cs[ni] = s;
    }
    __syncthreads();  // LDS reads of K-loop complete; reuse smx/ssx safely
    if (lane < 16) {
#pragma unroll
      for (int ni = 0; ni < 4; ++ni) {
        smx[wv][ni * 16 + lane] = cm[ni];
        ssx[wv][ni * 16 + lane] = cs[ni];
      }
    }
    __syncthreads();
    if (tid < 128) {
      int half = tid >> 6, c64 = tid & 63;
      float m1 = smx[half][c64], s1 = ssx[half][c64];
      float m2 = smx[half + 2][c64], s2 = ssx[half + 2][c64];
      float M = fmaxf(m1, m2);
      float S = s1 * __expf(m1 - M) + s2 * __expf(m2 - M);
      long o = ((long)bz * 16 + by) * NPT + bn + half * 64 + c64;
      PMo[o] = M;
      PSo[o] = S;
    }
  }
}

// ---- combine 16 partials per column -> CM, CSi ----
__global__ void k_cms_fin(const float* __restrict__ PM, const float* __restrict__ PS,
                          float* __restrict__ CM, float* __restrict__ CSi) {
  long idx = (long)blockIdx.x * 256 + threadIdx.x;  // [G*NPT]
  long z = idx >> 11;
  int n = idx & (NPT - 1);
  const float* pm = PM + z * 16 * NPT + n;
  const float* ps = PS + z * 16 * NPT + n;
  float m = -3.0e38f;
#pragma unroll
  for (int y = 0; y < 16; ++y) m = fmaxf(m, pm[(long)y * NPT]);
  float s = 0.f;
#pragma unroll
  for (int y = 0; y < 16; ++y) s += ps[(long)y * NPT] * __expf(pm[(long)y * NPT] - m);
  CM[idx] = m;
  CSi[idx] = 1.0f / s;
}

// ---- fused normalize + rowsum + V.P GEMM (F bf16, 2-phase dbuf, 8 waves) ----
// Per block: e = 0..255 (M), m in [m0, m0+64) (N), K = n = 0..2047.
// 512 threads = 8 waves arranged 4(e) x 2(m); tile 256e x 64m.
// 1-D grid 32*nz; z = bid % nz pins each batch's V to one XCD's L2.
// CM/CSi staged once in LDS (no per-step scale loads); F prefetch hoisted to
// the top of the step body so its HBM latency overlaps the whole step.
__global__ __launch_bounds__(512) void k_vp(const bf16* __restrict__ F,
                                            const float* __restrict__ CM,
                                            const float* __restrict__ CSi,
                                            const bf16* __restrict__ V,
                                            float* __restrict__ H, int nz) {
  __shared__ __align__(16) bf16 sA[2][256 * 64];  // V tiles (double-buffered)
  __shared__ __align__(16) bf16 sB[2][64 * 64];   // PT tiles (double-buffered)
  __shared__ float rsLds[64][8];
  __shared__ float Sv[64];
  __shared__ float smCM[NPT], smCS[NPT];
  const int z = blockIdx.x % nz;
  const int m0 = (blockIdx.x / nz) * 64;
  const int tid = threadIdx.x;
  const int lane = tid & 63, wv = tid >> 6;
  const int we = wv & 3;   // e-quarter 0..3 (64 rows)
  const int wm = wv >> 2;  // m-half 0..1 (32 cols)
  const int fr = tid >> 3; // F row 0..63
  const int fq = tid & 7;  // F col chunk 0..7
  const bf16* Vz = V + (long)z * STRD;
  const bf16* Frp = F + (long)z * NN + (long)(m0 + fr) * NPT + fq * 8;
  f32x4 acc[4][2] = {};
  float rs = 0.f;
  bf16x8v fvA, fvB;

  // one-time: stage CM/CSi for this batch into LDS (16 KB)
  {
    const float* cmz = CM + (long)z * NPT;
    const float* csz = CSi + (long)z * NPT;
#pragma unroll
    for (int i = 0; i < 4; ++i) {
      int idx = i * 512 + tid;
      smCM[idx] = cmz[idx];
      smCS[idx] = csz[idx];
    }
  }

#define LOADF(FREG, N0) FREG = *(const bf16x8v*)(Frp + (N0));

  // EXPW: exp of register F chunk (scales from LDS) -> sB[buf]; accumulate rs
#define EXPW(BUF, FREG, N0)                                                    \
  {                                                                            \
    float mv[8], cv[8];                                                        \
    *(float4*)&mv[0] = *(const float4*)&smCM[(N0) + fq * 8];                   \
    *(float4*)&mv[4] = *(const float4*)&smCM[(N0) + fq * 8 + 4];               \
    *(float4*)&cv[0] = *(const float4*)&smCS[(N0) + fq * 8];                   \
    *(float4*)&cv[4] = *(const float4*)&smCS[(N0) + fq * 8 + 4];               \
    bf16 tb[8];                                                                \
    _Pragma("unroll") for (int i = 0; i < 8; ++i) {                            \
      float fvi = __uint_as_float((unsigned)(unsigned short)FREG[i] << 16);    \
      float pv = __expf(fvi - mv[i]) * cv[i];                                  \
      rs += pv;                                                                \
      tb[i] = __float2bfloat16(pv);                                            \
    }                                                                          \
    *(bf16x8v*)&sB[BUF][fr * 64 + ((fq ^ (fr & 7)) * 8)] = *(bf16x8v*)tb;      \
  }

  // STAGEV: issue 4 global_load_lds of V column-chunk into sA[buf] (512 thr)
#define STAGEV(BUF, N0)                                                        \
  _Pragma("unroll") for (int i = 0; i < 4; ++i) {                              \
    int c = i * 512 + tid;                                                     \
    int row = c >> 3, g = c & 7;                                               \
    gload16(Vz + (long)row * NPT + (N0) + ((g ^ (row & 7)) * 8),               \
            &sA[BUF][c * 8]);                                                  \
  }

  // prologue
  LOADF(fvA, 0)
  STAGEV(0, 0)
  __syncthreads();  // scales in LDS visible (also covers staging of step 0)
  EXPW(0, fvA, 0)
  LOADF(fvB, 64)
  __syncthreads();

  // body: F prefetch at top (full-step latency cover); stage/exp for step+1;
  // MFMA on current buffers; single barrier per step.
#define VP_BODY(CUR, FN, FN2, STEPI)                                           \
  {                                                                            \
    const int sn = (STEPI);                                                    \
    const int nn0 = sn * 64;                                                   \
    if (sn + 2 < 32) LOADF(FN2, nn0 + 128)                                     \
    if (sn + 1 < 32) {                                                         \
      STAGEV(CUR ^ 1, nn0 + 64)                                                \
      EXPW(CUR ^ 1, FN, nn0 + 64)                                              \
    }                                                                          \
    bf16x8v bfr[2][2];                                                         \
    _Pragma("unroll") for (int ni = 0; ni < 2; ++ni)                           \
      _Pragma("unroll") for (int ks = 0; ks < 2; ++ks) {                       \
        int rB = wm * 32 + ni * 16 + (lane & 15);                              \
        int g = ks * 4 + (lane >> 4);                                          \
        bfr[ni][ks] = *(const bf16x8v*)&sB[CUR][rB * 64 + ((g ^ (rB & 7)) * 8)]; \
      }                                                                        \
    _Pragma("unroll") for (int mi = 0; mi < 4; ++mi)                           \
      _Pragma("unroll") for (int ks = 0; ks < 2; ++ks) {                       \
        int rA = we * 64 + mi * 16 + (lane & 15);                              \
        int g = ks * 4 + (lane >> 4);                                          \
        bf16x8v af = *(const bf16x8v*)&sA[CUR][rA * 64 + ((g ^ (rA & 7)) * 8)]; \
        _Pragma("unroll") for (int ni = 0; ni < 2; ++ni)                       \
          acc[mi][ni] = MFMA16(af, bfr[ni][ks], acc[mi][ni]);                  \
      }                                                                        \
    __syncthreads();                                                           \
  }

  for (int it = 0; it < 16; ++it) {
    VP_BODY(0, fvB, fvA, 2 * it)
    VP_BODY(1, fvA, fvB, 2 * it + 1)
  }
#undef VP_BODY
#undef STAGEV
#undef EXPW
#undef LOADF

  rsLds[fr][fq] = rs;
  __syncthreads();
  if (tid < 64) {
    float R = 0.f;
#pragma unroll
    for (int q = 0; q < 8; ++q) R += rsLds[tid][q];
    Sv[tid] = 1.0f / (1e-9f + R);
  }
  __syncthreads();

  float* Hz = H + (long)z * STRD;
  const int rb = (lane >> 4) * 4, cb = lane & 15;
#pragma unroll
  for (int mi = 0; mi < 4; ++mi) {
    int e0 = we * 64 + mi * 16 + rb;
#pragma unroll
    for (int ni = 0; ni < 2; ++ni) {
      int c = wm * 32 + ni * 16 + cb;
      float scl = Sv[c];
#pragma unroll
      for (int k = 0; k < 4; ++k)
        Hz[(long)(e0 + k) * NPT + m0 + c] += acc[mi][ni][k] * scl;
    }
  }
}

// ---- pooled[b,n] = mean over e of H[b,e,n] ----
__global__ void k_pool(const float* __restrict__ H, float* __restrict__ pooled) {
  int i = blockIdx.x * 256 + threadIdx.x;
  if (i >= BATCH * NPT) return;
  int b = i >> 11, n = i & (NPT - 1);
  const float* p = H + (long)b * STRD + n;
  float s = 0.f;
  for (int e = 0; e < DEMB; ++e) s += p[(long)e * NPT];
  pooled[i] = s * (1.0f / DEMB);
}

// ---- fc1 ----
__global__ __launch_bounds__(256) void k_fc1(const float* __restrict__ pooled,
                                             const float* __restrict__ w, const float* __restrict__ bias,
                                             float* __restrict__ f) {
  int j = blockIdx.x, b = blockIdx.y;
  const float* pp = pooled + (long)b * NPT;
  const float* wr = w + (long)j * NPT;
  float s = 0.f;
  for (int n = threadIdx.x; n < NPT; n += 256) s += pp[n] * wr[n];
  s = blockReduceSum(s);
  if (threadIdx.x == 0) {
    s += bias[j];
    f[(long)b * NPT + j] = s > 0.f ? s : 0.f;
  }
}

// ---- fc2 ----
__global__ __launch_bounds__(256) void k_fc2(const float* __restrict__ f,
                                             const float* __restrict__ w, const float* __restrict__ bias,
                                             float* __restrict__ out) {
  int b = blockIdx.x;
  float s = 0.f;
  for (int j = threadIdx.x; j < NPT; j += 256) s += f[(long)b * NPT + j] * w[j];
  s = blockReduceSum(s);
  if (threadIdx.x == 0) out[b] = s + bias[0];
}

extern "C" void kernel_launch(void* const* d_in, const int* in_sizes, int n_in,
                              void* d_out, int out_size, void* d_ws, size_t ws_size,
                              hipStream_t stream) {
  const float* X    = (const float*)d_in[0];
  const float* W1   = (const float*)d_in[1];
  const float* B1   = (const float*)d_in[2];
  const float* G1   = (const float*)d_in[3];
  const float* BE1  = (const float*)d_in[4];
  const float* W2   = (const float*)d_in[5];
  const float* B2   = (const float*)d_in[6];
  const float* G2   = (const float*)d_in[7];
  const float* BE2  = (const float*)d_in[8];
  const float* WQ   = (const float*)d_in[9];
  const float* WK   = (const float*)d_in[10];
  const float* WV   = (const float*)d_in[11];
  const float* FC1W = (const float*)d_in[12];
  const float* FC1B = (const float*)d_in[13];
  const float* FC2W = (const float*)d_in[14];
  const float* FC2B = (const float*)d_in[15];
  float* OUT = (float*)d_out;

  // ---- workspace carve-out ----
  char* p = (char*)d_ws;
  auto alloc = [&](size_t bytes) -> char* {
    char* r = p;
    p += (bytes + 255) & ~(size_t)255;
    return r;
  };
  float* H1t  = (float*)alloc((size_t)BATCH * NPT * DMID * 4);
  bf16*  H1tb = (bf16*)alloc((size_t)BATCH * NPT * DMID * 2);
  float* H    = (float*)alloc((size_t)BATCH * STRD * 4);
  bf16*  Ht   = (bf16*)alloc((size_t)BATCH * STRD * 2);
  bf16*  QKt  = (bf16*)alloc((size_t)BATCH * QKS * 2);   // [b][n][512] = Q(0..255) | K(256..511)
  bf16*  Vb   = (bf16*)alloc((size_t)BATCH * STRD * 2);
  bf16*  W2b  = (bf16*)alloc((size_t)DEMB * DMID * 2);
  bf16*  WQKb = (bf16*)alloc((size_t)NSA * 512 * DEMB * 2);
  bf16*  WVb  = (bf16*)alloc((size_t)NSA * DEMB * DEMB * 2);
  float* pS   = (float*)alloc(128 * 64 * 4);
  float* pS2  = (float*)alloc(128 * 64 * 4);
  float* sa1  = (float*)alloc(64 * 4);
  float* sb1  = (float*)alloc(64 * 4);
  float* sa2  = (float*)alloc(256 * 4);
  float* sb2  = (float*)alloc(256 * 4);
  float* CM   = (float*)alloc((size_t)BATCH * NPT * 4);
  float* CSi  = (float*)alloc((size_t)BATCH * NPT * 4);
  float* PM   = (float*)alloc((size_t)BATCH * 16 * NPT * 4);
  float* PSm  = (float*)alloc((size_t)BATCH * 16 * NPT * 4);
  float* POOL = (float*)alloc((size_t)BATCH * NPT * 4);
  float* FH   = (float*)alloc((size_t)BATCH * NPT * 4);
  size_t used = (size_t)(p - (char*)d_ws);
  const size_t per_g = (size_t)NN * 2;  // F bf16 (8MB per batch)
  int G = 8;
  while (G > 1 && used + (size_t)G * per_g + 1024 > ws_size) G >>= 1;
  bf16* F = (bf16*)alloc((size_t)G * NN * 2);

  // ---- weight converts ----
  k_cvt<<<(DEMB * DMID + 255) / 256, 256, 0, stream>>>(W2, W2b, DEMB * DMID);
  int nqk = NSA * 512 * DEMB;
  k_cvtqk<<<nqk / 256, 256, 0, stream>>>(WQ, WK, WQKb);
  int nw = NSA * DEMB * DEMB;
  k_cvt<<<(nw + 255) / 256, 256, 0, stream>>>(WV, WVb, nw);

  // ---- conv1 + BN1 + ReLU (-> H1tb bf16 [b][n][64]) ----
  long szh1 = (long)BATCH * NPT * DMID;
  k_conv1t<<<(int)(szh1 / 256), 256, 0, stream>>>(X, W1, B1, H1t);
  k_bn1a<<<128, 256, 0, stream>>>(H1t, pS, pS2);
  k_bn1b<<<1, 64, 0, stream>>>(pS, pS2, G1, BE1, sa1, sb1);
  k_bn1apply<<<(int)(szh1 / 256), 256, 0, stream>>>(H1t, sa1, sb1, H1tb);

  // ---- conv2 (MFMA) + BN2 + ReLU -> H fp32 [b][256][2048] ----
  k_mgemm<2><<<dim3(16, 2, 8), 256, 0, stream>>>(W2b, 0, DMID, H1tb, (long)NPT * DMID, DMID,
                                                 H, STRD, NPT, DMID, B2, nullptr, nullptr, 0);
  k_bnstats<<<DEMB, 256, 0, stream>>>(H, DEMB, G2, BE2, sa2, sb2);
  k_bnapply<<<(int)(BATCH * STRD / 256), 256, 0, stream>>>(H, sa2, sb2, DEMB, (int)(BATCH * STRD));

  // ---- SA layers ----
  for (int l = 0; l < NSA; ++l) {
    k_tcvt<<<dim3(32, 4, 8), 256, 0, stream>>>(H, Ht);
    // QKt[n][0..511] = Ht . [Wq;Wk]^T  : A=Ht (M=2048), B=WQK (N=512)
    k_mgemm<1><<<dim3(4, 16, 8), 256, 0, stream>>>(Ht, STRD, DEMB, WQKb + (long)l * 512 * DEMB, 0, DEMB,
                                                   QKt, QKS, 512, DEMB, nullptr, nullptr, nullptr, 0);
    // V[e][n] : A=Wv (M=256), B=Ht (N=2048)
    k_mgemm<1><<<dim3(16, 2, 8), 256, 0, stream>>>(WVb + (long)l * DEMB * DEMB, 0, DEMB, Ht, STRD, DEMB,
                                                   Vb, STRD, NPT, DEMB, nullptr, nullptr, nullptr, 0);
    for (int b0 = 0; b0 < BATCH; b0 += G) {
      // F[m][n] = sum_a Kt[m][a] Qt[n][a] (= E^T), bf16 + fused exact column stats
      // 1-D grid, z = bid % G pins each batch's QKt panels to one XCD's L2
      k_mgemm<0><<<dim3(256 * G), 256, 0, stream>>>(QKt + 256 + b0 * QKS, QKS, 512,
                                                    QKt + b0 * QKS, QKS, 512,
                                                    F, NN, NPT, DEMB, nullptr, PM, PSm, G);
      k_cms_fin<<<G * NPT / 256, 256, 0, stream>>>(PM, PSm, CM, CSi);
      // H[e][m] += S[m] * sum_n V[e][n] PT[m][n]  (PT from bf16 F on the fly)
      k_vp<<<dim3(32 * G), 512, 0, stream>>>(F, CM, CSi, Vb + b0 * STRD, H + b0 * STRD, G);
    }
  }

  // ---- head ----
  k_pool<<<(BATCH * NPT) / 256, 256, 0, stream>>>(H, POOL);
  k_fc1<<<dim3(NPT, BATCH), 256, 0, stream>>>(POOL, FC1W, FC1B, FH);
  k_fc2<<<BATCH, 256, 0, stream>>>(FH, FC2W, FC2B, OUT);
}

// Round 12
// 471.756 us; speedup vs baseline: 12.4720x; 1.0025x over previous
//
#include <hip/hip_runtime.h>
#include <hip/hip_bf16.h>

typedef __hip_bfloat16 bf16;
#define DEVI __device__ __forceinline__

// Problem constants
static constexpr int BATCH = 8;
static constexpr int NPT   = 2048;
static constexpr int DMID  = 64;
static constexpr int DEMB  = 256;
static constexpr int NSA   = 4;
static constexpr long STRD = (long)DEMB * NPT;  // 524288
static constexpr long QKS  = (long)NPT * 512;   // per-batch stride of QKt
static constexpr long NN   = (long)NPT * NPT;   // 4194304

typedef __attribute__((ext_vector_type(4))) float f32x4;
typedef __attribute__((ext_vector_type(8))) short bf16x8v;

DEVI f32x4 MFMA16(bf16x8v a, bf16x8v b, f32x4 c) {
  return __builtin_amdgcn_mfma_f32_16x16x32_bf16(a, b, c, 0, 0, 0);
}

DEVI void gload16(const bf16* g, bf16* l) {
  __builtin_amdgcn_global_load_lds(
      (const __attribute__((address_space(1))) void*)g,
      (__attribute__((address_space(3))) void*)l, 16, 0, 0);
}

DEVI float waveReduceSum(float v) {
#pragma unroll
  for (int o = 32; o > 0; o >>= 1) v += __shfl_down(v, o, 64);
  return v;
}
DEVI float blockReduceSum(float v) {
  __shared__ float sm[4];
  int lane = threadIdx.x & 63, wid = threadIdx.x >> 6;
  __syncthreads();
  v = waveReduceSum(v);
  if (lane == 0) sm[wid] = v;
  __syncthreads();
  return sm[0] + sm[1] + sm[2] + sm[3];
}

// ---- fp32 -> bf16 convert ----
__global__ void k_cvt(const float* __restrict__ in, bf16* __restrict__ out, int n) {
  int i = blockIdx.x * 256 + threadIdx.x;
  if (i < n) out[i] = __float2bfloat16(in[i]);
}

// ---- concat-convert Wq,Wk -> WQKb [l][512][256] bf16 ----
__global__ void k_cvtqk(const float* __restrict__ wq, const float* __restrict__ wk,
                        bf16* __restrict__ o) {
  int idx = blockIdx.x * 256 + threadIdx.x;  // NSA*512*256
  int c = idx & 255;
  int r = (idx >> 8) & 511;
  int l = idx >> 17;
  float v = (r < 256) ? wq[((l << 8) + r) * 256 + c] : wk[((l << 8) + (r - 256)) * 256 + c];
  o[idx] = __float2bfloat16(v);
}

// ---- conv1: H1t[b][n][o] = sum_c x[b,n,c]*w1[o,c] + b1[o] ----
__global__ void k_conv1t(const float* __restrict__ x, const float* __restrict__ w1,
                         const float* __restrict__ b1, float* __restrict__ h1t) {
  long idx = (long)blockIdx.x * 256 + threadIdx.x;  // [b*n][o]
  int o = idx & 63;
  long bn = idx >> 6;
  const float* xp = x + bn * 3;
  h1t[idx] = b1[o] + xp[0] * w1[o * 3] + xp[1] * w1[o * 3 + 1] + xp[2] * w1[o * 3 + 2];
}

// ---- BN1 stats on H1t [16384][64] ----
__global__ __launch_bounds__(256) void k_bn1a(const float* __restrict__ h, float* __restrict__ pS,
                                              float* __restrict__ pS2) {
  int c = threadIdx.x & 63, rg = threadIdx.x >> 6;
  long r0 = (long)blockIdx.x * 128 + rg * 32;
  float s = 0.f, s2 = 0.f;
  for (int i = 0; i < 32; ++i) {
    float v = h[(r0 + i) * 64 + c];
    s += v; s2 += v * v;
  }
  __shared__ float smS[256], smS2[256];
  smS[threadIdx.x] = s; smS2[threadIdx.x] = s2;
  __syncthreads();
  if (threadIdx.x < 64) {
    float a = 0.f, b = 0.f;
#pragma unroll
    for (int g = 0; g < 4; ++g) { a += smS[g * 64 + c]; b += smS2[g * 64 + c]; }
    pS[blockIdx.x * 64 + c] = a;
    pS2[blockIdx.x * 64 + c] = b;
  }
}
__global__ void k_bn1b(const float* __restrict__ pS, const float* __restrict__ pS2,
                       const float* __restrict__ g, const float* __restrict__ be,
                       float* __restrict__ sa, float* __restrict__ sb) {
  int c = threadIdx.x;
  if (c >= 64) return;
  float s = 0.f, s2 = 0.f;
  for (int i = 0; i < 128; ++i) { s += pS[i * 64 + c]; s2 += pS2[i * 64 + c]; }
  const float inv = 1.0f / (BATCH * NPT);
  float m = s * inv, var = s2 * inv - m * m;
  float A = rsqrtf(var + 1e-5f) * g[c];
  sa[c] = A; sb[c] = be[c] - m * A;
}
__global__ void k_bn1apply(const float* __restrict__ h, const float* __restrict__ sa,
                           const float* __restrict__ sb, bf16* __restrict__ o) {
  long idx = (long)blockIdx.x * 256 + threadIdx.x;
  int c = idx & 63;
  float v = fmaf(h[idx], sa[c], sb[c]);
  o[idx] = __float2bfloat16(v > 0.f ? v : 0.f);
}

// ---- BN2 stats/apply on H [b][256][2048] fp32 ----
__global__ __launch_bounds__(256) void k_bnstats(const float* __restrict__ h, int Cc,
                                                 const float* __restrict__ g, const float* __restrict__ be,
                                                 float* __restrict__ sa, float* __restrict__ sb) {
  int c = blockIdx.x;
  float s = 0.f, s2 = 0.f;
  for (int b = 0; b < BATCH; ++b) {
    const float* p = h + ((long)(b * Cc + c)) * NPT;
    for (int n = threadIdx.x; n < NPT; n += 256) {
      float v = p[n];
      s += v; s2 += v * v;
    }
  }
  s = blockReduceSum(s);
  s2 = blockReduceSum(s2);
  if (threadIdx.x == 0) {
    const float inv = 1.0f / (BATCH * NPT);
    float m = s * inv, var = s2 * inv - m * m;
    float A = rsqrtf(var + 1e-5f) * g[c];
    sa[c] = A; sb[c] = be[c] - m * A;
  }
}
__global__ void k_bnapply(float* __restrict__ h, const float* __restrict__ sa,
                          const float* __restrict__ sb, int Cc, int total) {
  int i = blockIdx.x * 256 + threadIdx.x;
  if (i >= total) return;
  int c = (i >> 11) & (Cc - 1);
  float v = fmaf(h[i], sa[c], sb[c]);
  h[i] = v > 0.f ? v : 0.f;
}

// ---- tiled transpose+convert: H [b][256][2048] f32 -> Ht [b][2048][256] bf16 ----
__global__ __launch_bounds__(256) void k_tcvt(const float* __restrict__ H, bf16* __restrict__ Ht) {
  __shared__ float t[64][65];
  const float* h = H + (long)blockIdx.z * STRD;
  bf16* o = Ht + (long)blockIdx.z * STRD;
  int n0 = blockIdx.x * 64, c0 = blockIdx.y * 64;
#pragma unroll
  for (int ii = 0; ii < 16; ++ii) {
    int idx = ii * 256 + threadIdx.x;
    int i = idx >> 6, j = idx & 63;
    t[i][j] = h[(long)(c0 + i) * NPT + n0 + j];
  }
  __syncthreads();
#pragma unroll
  for (int ii = 0; ii < 16; ++ii) {
    int idx = ii * 256 + threadIdx.x;
    int i = idx >> 6, j = idx & 63;
    o[(long)(n0 + i) * DEMB + c0 + j] = __float2bfloat16(t[j][i]);
  }
}

// ---- MFMA GEMM, B^T form: C[M][N] = A[M][K] . B[N][K]^T ; 128x128 tile, BK=64 ----
// XOR-swizzled LDS (granule ^= row&7) on both staging-source and read.
// MODE 0: C bf16 = acc + fused column-softmax partials; 1-D grid, z = bid % nz (XCD-pin)
// MODE 1: C bf16 = acc
// MODE 2: C f32 = acc + bias[r]
template <int MODE>
__global__ __launch_bounds__(256) void k_mgemm(
    const bf16* __restrict__ A, long aStr, int ldA,
    const bf16* __restrict__ B, long bStr, int ldB,
    void* __restrict__ Cv, long cStr, int ldC,
    int K,
    const float* __restrict__ bias,
    float* __restrict__ PMo, float* __restrict__ PSo, int nz) {
  __shared__ __align__(16) bf16 sA[128 * 64];
  __shared__ __align__(16) bf16 sB[128 * 64];
  __shared__ float smx[4][64], ssx[4][64];
  int bx, by, bz;
  if constexpr (MODE == 0) {
    bz = blockIdx.x % nz;
    int t = blockIdx.x / nz;
    bx = t & 15;
    by = t >> 4;
  } else {
    bx = blockIdx.x; by = blockIdx.y; bz = blockIdx.z;
  }
  A += aStr * bz;
  B += bStr * bz;
  const int bm = by * 128, bn = bx * 128;
  const int tid = threadIdx.x;
  const int lane = tid & 63, wv = tid >> 6;
  const int wr = (wv >> 1) * 64, wc = (wv & 1) * 64;
  f32x4 acc[4][4] = {};

  for (int k0 = 0; k0 < K; k0 += 64) {
#pragma unroll
    for (int i = 0; i < 4; ++i) {
      int c = i * 256 + tid;
      int row = c >> 3, g = c & 7;
      int gs = (g ^ (row & 7)) * 8;
      gload16(A + (long)(bm + row) * ldA + k0 + gs, sA + c * 8);
      gload16(B + (long)(bn + row) * ldB + k0 + gs, sB + c * 8);
    }
    __syncthreads();
    bf16x8v af[4][2], bfr[4][2];
#pragma unroll
    for (int mi = 0; mi < 4; ++mi)
#pragma unroll
      for (int ks = 0; ks < 2; ++ks) {
        int rA = wr + mi * 16 + (lane & 15);
        int rB = wc + mi * 16 + (lane & 15);
        int g = ks * 4 + (lane >> 4);
        af[mi][ks]  = *(const bf16x8v*)&sA[rA * 64 + ((g ^ (rA & 7)) * 8)];
        bfr[mi][ks] = *(const bf16x8v*)&sB[rB * 64 + ((g ^ (rB & 7)) * 8)];
      }
#pragma unroll
    for (int ks = 0; ks < 2; ++ks)
#pragma unroll
      for (int mi = 0; mi < 4; ++mi)
#pragma unroll
        for (int ni = 0; ni < 4; ++ni)
          acc[mi][ni] = MFMA16(af[mi][ks], bfr[ni][ks], acc[mi][ni]);
    __syncthreads();
  }

  const int rb = (lane >> 4) * 4, cb = lane & 15;
  if constexpr (MODE == 0 || MODE == 1) {
    bf16* C = (bf16*)Cv + cStr * bz;
#pragma unroll
    for (int mi = 0; mi < 4; ++mi)
#pragma unroll
      for (int ni = 0; ni < 4; ++ni) {
        int r0 = bm + wr + mi * 16 + rb, c0 = bn + wc + ni * 16 + cb;
#pragma unroll
        for (int k = 0; k < 4; ++k)
          C[(long)(r0 + k) * ldC + c0] = __float2bfloat16(acc[mi][ni][k]);
      }
  } else {
    float* C = (float*)Cv + cStr * bz;
#pragma unroll
    for (int mi = 0; mi < 4; ++mi)
#pragma unroll
      for (int ni = 0; ni < 4; ++ni) {
        int r0 = bm + wr + mi * 16 + rb, c0 = bn + wc + ni * 16 + cb;
#pragma unroll
        for (int k = 0; k < 4; ++k) {
          int r = r0 + k;
          C[(long)r * ldC + c0] = acc[mi][ni][k] + bias[r];
        }
      }
  }

  if constexpr (MODE == 0) {
    // per-column (over this block's 128 rows) online-softmax partials (exact fp32)
    float cm[4], cs[4];
#pragma unroll
    for (int ni = 0; ni < 4; ++ni) {
      float m = -3.0e38f;
#pragma unroll
      for (int mi = 0; mi < 4; ++mi)
#pragma unroll
        for (int k = 0; k < 4; ++k) m = fmaxf(m, acc[mi][ni][k]);
      float s = 0.f;
#pragma unroll
      for (int mi = 0; mi < 4; ++mi)
#pragma unroll
        for (int k = 0; k < 4; ++k) s += __expf(acc[mi][ni][k] - m);
#pragma unroll
      for (int off = 16; off <= 32; off <<= 1) {
        float mo = __shfl_xor(m, off, 64);
        float so = __shfl_xor(s, off, 64);
        float M = fmaxf(m, mo);
        s = s * __expf(m - M) + so * __expf(mo - M);
        m = M;
      }
      cm[ni] = m; cs[ni] = s;
    }
    __syncthreads();  // LDS reads of K-loop complete; reuse smx/ssx safely
    if (lane < 16) {
#pragma unroll
      for (int ni = 0; ni < 4; ++ni) {
        smx[wv][ni * 16 + lane] = cm[ni];
        ssx[wv][ni * 16 + lane] = cs[ni];
      }
    }
    __syncthreads();
    if (tid < 128) {
      int half = tid >> 6, c64 = tid & 63;
      float m1 = smx[half][c64], s1 = ssx[half][c64];
      float m2 = smx[half + 2][c64], s2 = ssx[half + 2][c64];
      float M = fmaxf(m1, m2);
      float S = s1 * __expf(m1 - M) + s2 * __expf(m2 - M);
      long o = ((long)bz * 16 + by) * NPT + bn + half * 64 + c64;
      PMo[o] = M;
      PSo[o] = S;
    }
  }
}

// ---- combine 16 partials per column -> CM, CSi ----
__global__ void k_cms_fin(const float* __restrict__ PM, const float* __restrict__ PS,
                          float* __restrict__ CM, float* __restrict__ CSi) {
  long idx = (long)blockIdx.x * 256 + threadIdx.x;  // [G*NPT]
  long z = idx >> 11;
  int n = idx & (NPT - 1);
  const float* pm = PM + z * 16 * NPT + n;
  const float* ps = PS + z * 16 * NPT + n;
  float m = -3.0e38f;
#pragma unroll
  for (int y = 0; y < 16; ++y) m = fmaxf(m, pm[(long)y * NPT]);
  float s = 0.f;
#pragma unroll
  for (int y = 0; y < 16; ++y) s += ps[(long)y * NPT] * __expf(pm[(long)y * NPT] - m);
  CM[idx] = m;
  CSi[idx] = 1.0f / s;
}

// ---- fused normalize + rowsum + V.P GEMM (F bf16, 2-phase dbuf) ----
// Block: 256 threads = 4 waves (2e x 2m); tile 128e x 64m; e-halves split
// across blocks so 2 independent blocks share a CU (decoupled barriers).
// 1-D grid 64*nz; z = bid % nz pins each batch's V to one XCD's L2.
// Each thread handles F rows fr and fr+32 (fully coalesced 128B groups).
__global__ __launch_bounds__(256) void k_vp(const bf16* __restrict__ F,
                                            const float* __restrict__ CM,
                                            const float* __restrict__ CSi,
                                            const bf16* __restrict__ V,
                                            float* __restrict__ H, int nz) {
  __shared__ __align__(16) bf16 sA[2][128 * 64];  // V half-tiles (double-buffered)
  __shared__ __align__(16) bf16 sB[2][64 * 64];   // PT tiles (double-buffered)
  __shared__ float rsLds[64][8];
  __shared__ float Sv[64];
  __shared__ float smCM[NPT], smCS[NPT];
  const int z = blockIdx.x % nz;
  const int t = blockIdx.x / nz;
  const int eh = t & 1;            // e-half 0..1 (128 rows each)
  const int m0 = (t >> 1) * 64;    // m-tile 0..31
  const int tid = threadIdx.x;
  const int lane = tid & 63, wv = tid >> 6;
  const int we = wv & 1;   // e 64-range within the 128
  const int wm = wv >> 1;  // m 32-half
  const int fr = tid >> 3; // F row 0..31 (also handles fr+32)
  const int fq = tid & 7;  // F col chunk 0..7
  const bf16* Vz = V + (long)z * STRD + (long)eh * 128 * NPT;
  const bf16* Frp0 = F + (long)z * NN + (long)(m0 + fr) * NPT + fq * 8;
  const bf16* Frp1 = Frp0 + (long)32 * NPT;
  f32x4 acc[4][2] = {};
  float rs0 = 0.f, rs1 = 0.f;
  bf16x8v fvA0, fvA1, fvB0, fvB1;

  // one-time: stage CM/CSi for this batch into LDS (16 KB)
  {
    const float* cmz = CM + (long)z * NPT;
    const float* csz = CSi + (long)z * NPT;
#pragma unroll
    for (int i = 0; i < 8; ++i) {
      int idx = i * 256 + tid;
      smCM[idx] = cmz[idx];
      smCS[idx] = csz[idx];
    }
  }

#define LOADF(A0, A1, N0)                                                      \
  {                                                                            \
    A0 = *(const bf16x8v*)(Frp0 + (N0));                                       \
    A1 = *(const bf16x8v*)(Frp1 + (N0));                                       \
  }

  // EXPW: exp of 2 register F rows (scales from LDS) -> sB[buf]; accumulate rs
#define EXPW(BUF, A0, A1, N0)                                                  \
  {                                                                            \
    float mv[8], cv[8];                                                        \
    *(float4*)&mv[0] = *(const float4*)&smCM[(N0) + fq * 8];                   \
    *(float4*)&mv[4] = *(const float4*)&smCM[(N0) + fq * 8 + 4];               \
    *(float4*)&cv[0] = *(const float4*)&smCS[(N0) + fq * 8];                   \
    *(float4*)&cv[4] = *(const float4*)&smCS[(N0) + fq * 8 + 4];               \
    bf16 tb0[8], tb1[8];                                                       \
    _Pragma("unroll") for (int i = 0; i < 8; ++i) {                            \
      float f0 = __uint_as_float((unsigned)(unsigned short)A0[i] << 16);       \
      float f1 = __uint_as_float((unsigned)(unsigned short)A1[i] << 16);       \
      float p0 = __expf(f0 - mv[i]) * cv[i];                                   \
      float p1 = __expf(f1 - mv[i]) * cv[i];                                   \
      rs0 += p0; rs1 += p1;                                                    \
      tb0[i] = __float2bfloat16(p0);                                           \
      tb1[i] = __float2bfloat16(p1);                                           \
    }                                                                          \
    *(bf16x8v*)&sB[BUF][fr * 64 + ((fq ^ (fr & 7)) * 8)] = *(bf16x8v*)tb0;     \
    *(bf16x8v*)&sB[BUF][(fr + 32) * 64 + ((fq ^ (fr & 7)) * 8)] = *(bf16x8v*)tb1; \
  }

  // STAGEV: issue 4 global_load_lds of V half-tile column-chunk into sA[buf]
#define STAGEV(BUF, N0)                                                        \
  _Pragma("unroll") for (int i = 0; i < 4; ++i) {                              \
    int c = i * 256 + tid;                                                     \
    int row = c >> 3, g = c & 7;                                               \
    gload16(Vz + (long)row * NPT + (N0) + ((g ^ (row & 7)) * 8),               \
            &sA[BUF][c * 8]);                                                  \
  }

  // prologue
  LOADF(fvA0, fvA1, 0)
  STAGEV(0, 0)
  __syncthreads();  // scales in LDS visible; staging of step 0 drained
  EXPW(0, fvA0, fvA1, 0)
  LOADF(fvB0, fvB1, 64)
  __syncthreads();

  // body: F prefetch at top; stage/exp for step+1; MFMA on step; one barrier.
#define VP_BODY(CUR, FA0, FA1, FB0, FB1, STEPI)                                \
  {                                                                            \
    const int sn = (STEPI);                                                    \
    const int nn0 = sn * 64;                                                   \
    if (sn + 2 < 32) LOADF(FB0, FB1, nn0 + 128)                                \
    if (sn + 1 < 32) {                                                         \
      STAGEV(CUR ^ 1, nn0 + 64)                                                \
      EXPW(CUR ^ 1, FA0, FA1, nn0 + 64)                                        \
    }                                                                          \
    bf16x8v bfr[2][2];                                                         \
    _Pragma("unroll") for (int ni = 0; ni < 2; ++ni)                           \
      _Pragma("unroll") for (int ks = 0; ks < 2; ++ks) {                       \
        int rB = wm * 32 + ni * 16 + (lane & 15);                              \
        int g = ks * 4 + (lane >> 4);                                          \
        bfr[ni][ks] = *(const bf16x8v*)&sB[CUR][rB * 64 + ((g ^ (rB & 7)) * 8)]; \
      }                                                                        \
    _Pragma("unroll") for (int mi = 0; mi < 4; ++mi)                           \
      _Pragma("unroll") for (int ks = 0; ks < 2; ++ks) {                       \
        int rA = we * 64 + mi * 16 + (lane & 15);                              \
        int g = ks * 4 + (lane >> 4);                                          \
        bf16x8v af = *(const bf16x8v*)&sA[CUR][rA * 64 + ((g ^ (rA & 7)) * 8)]; \
        _Pragma("unroll") for (int ni = 0; ni < 2; ++ni)                       \
          acc[mi][ni] = MFMA16(af, bfr[ni][ks], acc[mi][ni]);                  \
      }                                                                        \
    __syncthreads();                                                           \
  }

  for (int it = 0; it < 16; ++it) {
    VP_BODY(0, fvB0, fvB1, fvA0, fvA1, 2 * it)
    VP_BODY(1, fvA0, fvA1, fvB0, fvB1, 2 * it + 1)
  }
#undef VP_BODY
#undef STAGEV
#undef EXPW
#undef LOADF

  rsLds[fr][fq] = rs0;
  rsLds[fr + 32][fq] = rs1;
  __syncthreads();
  if (tid < 64) {
    float R = 0.f;
#pragma unroll
    for (int q = 0; q < 8; ++q) R += rsLds[tid][q];
    Sv[tid] = 1.0f / (1e-9f + R);
  }
  __syncthreads();

  float* Hz = H + (long)z * STRD;
  const int rb = (lane >> 4) * 4, cb = lane & 15;
#pragma unroll
  for (int mi = 0; mi < 4; ++mi) {
    int e0 = eh * 128 + we * 64 + mi * 16 + rb;
#pragma unroll
    for (int ni = 0; ni < 2; ++ni) {
      int c = wm * 32 + ni * 16 + cb;
      float scl = Sv[c];
#pragma unroll
      for (int k = 0; k < 4; ++k)
        Hz[(long)(e0 + k) * NPT + m0 + c] += acc[mi][ni][k] * scl;
    }
  }
}

// ---- pooled[b,n] = mean over e of H[b,e,n] ----
__global__ void k_pool(const float* __restrict__ H, float* __restrict__ pooled) {
  int i = blockIdx.x * 256 + threadIdx.x;
  if (i >= BATCH * NPT) return;
  int b = i >> 11, n = i & (NPT - 1);
  const float* p = H + (long)b * STRD + n;
  float s = 0.f;
  for (int e = 0; e < DEMB; ++e) s += p[(long)e * NPT];
  pooled[i] = s * (1.0f / DEMB);
}

// ---- fc1: one block per output row j; w row read ONCE, all 8 batches ----
__global__ __launch_bounds__(256) void k_fc1(const float* __restrict__ pooled,
                                             const float* __restrict__ w, const float* __restrict__ bias,
                                             float* __restrict__ f) {
  int j = blockIdx.x;
  const float* wr = w + (long)j * NPT;
  int n0 = threadIdx.x * 8;
  float wl[8];
  *(float4*)&wl[0] = *(const float4*)(wr + n0);
  *(float4*)&wl[4] = *(const float4*)(wr + n0 + 4);
  float part[8];
#pragma unroll
  for (int b = 0; b < 8; ++b) {
    const float* pp = pooled + (long)b * NPT + n0;
    float4 p0 = *(const float4*)pp, p1 = *(const float4*)(pp + 4);
    part[b] = wl[0] * p0.x + wl[1] * p0.y + wl[2] * p0.z + wl[3] * p0.w +
              wl[4] * p1.x + wl[5] * p1.y + wl[6] * p1.z + wl[7] * p1.w;
  }
#pragma unroll
  for (int b = 0; b < 8; ++b) {
    float s = blockReduceSum(part[b]);
    if (threadIdx.x == 0) {
      s += bias[j];
      f[(long)b * NPT + j] = s > 0.f ? s : 0.f;
    }
  }
}

// ---- fc2 ----
__global__ __launch_bounds__(256) void k_fc2(const float* __restrict__ f,
                                             const float* __restrict__ w, const float* __restrict__ bias,
                                             float* __restrict__ out) {
  int b = blockIdx.x;
  float s = 0.f;
  for (int j = threadIdx.x; j < NPT; j += 256) s += f[(long)b * NPT + j] * w[j];
  s = blockReduceSum(s);
  if (threadIdx.x == 0) out[b] = s + bias[0];
}

extern "C" void kernel_launch(void* const* d_in, const int* in_sizes, int n_in,
                              void* d_out, int out_size, void* d_ws, size_t ws_size,
                              hipStream_t stream) {
  const float* X    = (const float*)d_in[0];
  const float* W1   = (const float*)d_in[1];
  const float* B1   = (const float*)d_in[2];
  const float* G1   = (const float*)d_in[3];
  const float* BE1  = (const float*)d_in[4];
  const float* W2   = (const float*)d_in[5];
  const float* B2   = (const float*)d_in[6];
  const float* G2   = (const float*)d_in[7];
  const float* BE2  = (const float*)d_in[8];
  const float* WQ   = (const float*)d_in[9];
  const float* WK   = (const float*)d_in[10];
  const float* WV   = (const float*)d_in[11];
  const float* FC1W = (const float*)d_in[12];
  const float* FC1B = (const float*)d_in[13];
  const float* FC2W = (const float*)d_in[14];
  const float* FC2B = (const float*)d_in[15];
  float* OUT = (float*)d_out;

  // ---- workspace carve-out ----
  char* p = (char*)d_ws;
  auto alloc = [&](size_t bytes) -> char* {
    char* r = p;
    p += (bytes + 255) & ~(size_t)255;
    return r;
  };
  float* H1t  = (float*)alloc((size_t)BATCH * NPT * DMID * 4);
  bf16*  H1tb = (bf16*)alloc((size_t)BATCH * NPT * DMID * 2);
  float* H    = (float*)alloc((size_t)BATCH * STRD * 4);
  bf16*  Ht   = (bf16*)alloc((size_t)BATCH * STRD * 2);
  bf16*  QKt  = (bf16*)alloc((size_t)BATCH * QKS * 2);   // [b][n][512] = Q(0..255) | K(256..511)
  bf16*  Vb   = (bf16*)alloc((size_t)BATCH * STRD * 2);
  bf16*  W2b  = (bf16*)alloc((size_t)DEMB * DMID * 2);
  bf16*  WQKb = (bf16*)alloc((size_t)NSA * 512 * DEMB * 2);
  bf16*  WVb  = (bf16*)alloc((size_t)NSA * DEMB * DEMB * 2);
  float* pS   = (float*)alloc(128 * 64 * 4);
  float* pS2  = (float*)alloc(128 * 64 * 4);
  float* sa1  = (float*)alloc(64 * 4);
  float* sb1  = (float*)alloc(64 * 4);
  float* sa2  = (float*)alloc(256 * 4);
  float* sb2  = (float*)alloc(256 * 4);
  float* CM   = (float*)alloc((size_t)BATCH * NPT * 4);
  float* CSi  = (float*)alloc((size_t)BATCH * NPT * 4);
  float* PM   = (float*)alloc((size_t)BATCH * 16 * NPT * 4);
  float* PSm  = (float*)alloc((size_t)BATCH * 16 * NPT * 4);
  float* POOL = (float*)alloc((size_t)BATCH * NPT * 4);
  float* FH   = (float*)alloc((size_t)BATCH * NPT * 4);
  size_t used = (size_t)(p - (char*)d_ws);
  const size_t per_g = (size_t)NN * 2;  // F bf16 (8MB per batch)
  int G = 8;
  while (G > 1 && used + (size_t)G * per_g + 1024 > ws_size) G >>= 1;
  bf16* F = (bf16*)alloc((size_t)G * NN * 2);

  // ---- weight converts ----
  k_cvt<<<(DEMB * DMID + 255) / 256, 256, 0, stream>>>(W2, W2b, DEMB * DMID);
  int nqk = NSA * 512 * DEMB;
  k_cvtqk<<<nqk / 256, 256, 0, stream>>>(WQ, WK, WQKb);
  int nw = NSA * DEMB * DEMB;
  k_cvt<<<(nw + 255) / 256, 256, 0, stream>>>(WV, WVb, nw);

  // ---- conv1 + BN1 + ReLU (-> H1tb bf16 [b][n][64]) ----
  long szh1 = (long)BATCH * NPT * DMID;
  k_conv1t<<<(int)(szh1 / 256), 256, 0, stream>>>(X, W1, B1, H1t);
  k_bn1a<<<128, 256, 0, stream>>>(H1t, pS, pS2);
  k_bn1b<<<1, 64, 0, stream>>>(pS, pS2, G1, BE1, sa1, sb1);
  k_bn1apply<<<(int)(szh1 / 256), 256, 0, stream>>>(H1t, sa1, sb1, H1tb);

  // ---- conv2 (MFMA) + BN2 + ReLU -> H fp32 [b][256][2048] ----
  k_mgemm<2><<<dim3(16, 2, 8), 256, 0, stream>>>(W2b, 0, DMID, H1tb, (long)NPT * DMID, DMID,
                                                 H, STRD, NPT, DMID, B2, nullptr, nullptr, 0);
  k_bnstats<<<DEMB, 256, 0, stream>>>(H, DEMB, G2, BE2, sa2, sb2);
  k_bnapply<<<(int)(BATCH * STRD / 256), 256, 0, stream>>>(H, sa2, sb2, DEMB, (int)(BATCH * STRD));

  // ---- SA layers ----
  for (int l = 0; l < NSA; ++l) {
    k_tcvt<<<dim3(32, 4, 8), 256, 0, stream>>>(H, Ht);
    // QKt[n][0..511] = Ht . [Wq;Wk]^T  : A=Ht (M=2048), B=WQK (N=512)
    k_mgemm<1><<<dim3(4, 16, 8), 256, 0, stream>>>(Ht, STRD, DEMB, WQKb + (long)l * 512 * DEMB, 0, DEMB,
                                                   QKt, QKS, 512, DEMB, nullptr, nullptr, nullptr, 0);
    // V[e][n] : A=Wv (M=256), B=Ht (N=2048)
    k_mgemm<1><<<dim3(16, 2, 8), 256, 0, stream>>>(WVb + (long)l * DEMB * DEMB, 0, DEMB, Ht, STRD, DEMB,
                                                   Vb, STRD, NPT, DEMB, nullptr, nullptr, nullptr, 0);
    for (int b0 = 0; b0 < BATCH; b0 += G) {
      // F[m][n] = sum_a Kt[m][a] Qt[n][a] (= E^T), bf16 + fused exact column stats
      // 1-D grid, z = bid % G pins each batch's QKt panels to one XCD's L2
      k_mgemm<0><<<dim3(256 * G), 256, 0, stream>>>(QKt + 256 + b0 * QKS, QKS, 512,
                                                    QKt + b0 * QKS, QKS, 512,
                                                    F, NN, NPT, DEMB, nullptr, PM, PSm, G);
      k_cms_fin<<<G * NPT / 256, 256, 0, stream>>>(PM, PSm, CM, CSi);
      // H[e][m] += S[m] * sum_n V[e][n] PT[m][n]  (PT from bf16 F on the fly)
      k_vp<<<dim3(64 * G), 256, 0, stream>>>(F, CM, CSi, Vb + b0 * STRD, H + b0 * STRD, G);
    }
  }

  // ---- head ----
  k_pool<<<(BATCH * NPT) / 256, 256, 0, stream>>>(H, POOL);
  k_fc1<<<NPT, 256, 0, stream>>>(POOL, FC1W, FC1B, FH);
  k_fc2<<<BATCH, 256, 0, stream>>>(FH, FC2W, FC2B, OUT);
}